// Round 1
// baseline (194.287 us; speedup 1.0000x reference)
//
#include <hip/hip_runtime.h>
#include <hip/hip_bf16.h>
#include <stdint.h>

typedef __attribute__((ext_vector_type(8))) short short8;
typedef __attribute__((ext_vector_type(4))) float f32x4;

#define NB 128
#define NL 256
#define NROWS 32768        // B*L
#define IN_DIM 360
#define KP1 384            // padded K for layer-1 GEMM
#define MEM 200
#define NP 256             // padded N
#define OUT_X (NROWS * MEM)

__device__ __forceinline__ unsigned short f2b(float f) {
    unsigned u = __builtin_bit_cast(unsigned, f);
    unsigned r = (u + 0x7FFFu + ((u >> 16) & 1u)) >> 16;
    return (unsigned short)r;
}

// ---------------- weight prep: W0p[256][384], W1p[256][256] (bf16, [n][k], zero-padded)
__global__ void prep_weights(const float* __restrict__ W0, const float* __restrict__ W1,
                             short* __restrict__ W0p, short* __restrict__ W1p) {
    int idx = blockIdx.x * 256 + threadIdx.x;
    if (idx < NP * KP1) {
        int n = idx / KP1, k = idx - n * KP1;
        float v = (n < MEM && k < IN_DIM) ? W0[n * IN_DIM + k] : 0.f;
        W0p[idx] = (short)f2b(v);
    } else {
        int i2 = idx - NP * KP1;
        if (i2 < NP * NP) {
            int n = i2 >> 8, k = i2 & 255;
            float v = (n < MEM && k < MEM) ? W1[n * MEM + k] : 0.f;
            W1p[i2] = (short)f2b(v);
        }
    }
}

// ---------------- embedding concat -> x0 bf16 [32768][384]
__global__ void embed_kernel(const int* __restrict__ words, const int* __restrict__ pos,
                             const int* __restrict__ ner,
                             const float* __restrict__ embW, const float* __restrict__ posW,
                             const float* __restrict__ nerW, short* __restrict__ x0b) {
    int row = blockIdx.x;
    int k = threadIdx.x;              // blockDim = 384
    float v = 0.f;
    if (k < 300)      v = embW[(size_t)words[row] * 300 + k];
    else if (k < 330) v = posW[pos[row] * 30 + (k - 300)];
    else if (k < 360) v = nerW[ner[row] * 30 + (k - 330)];
    x0b[(size_t)row * KP1 + k] = (short)f2b(v);
}

// ---------------- adj row pass: rowsum, denom_inv, CSR neighbor lists (uint8)
__global__ void adjrow_kernel(const float* __restrict__ adj, float* __restrict__ dinv,
                              float* __restrict__ rsum, uint8_t* __restrict__ nbr,
                              int* __restrict__ cnt) {
    int row = blockIdx.x * 4 + (threadIdx.x >> 6);
    int lane = threadIdx.x & 63;
    const float4* ar = (const float4*)(adj + (size_t)row * NL);
    float4 v = ar[lane];
    float s = v.x + v.y + v.z + v.w;
    #pragma unroll
    for (int off = 32; off >= 1; off >>= 1) s += __shfl_xor(s, off);
    if (lane == 0) { rsum[row] = s; dinv[row] = 1.0f / (s + 1.0f); }
    unsigned long long m0 = __ballot(v.x != 0.f);
    unsigned long long m1 = __ballot(v.y != 0.f);
    unsigned long long m2 = __ballot(v.z != 0.f);
    unsigned long long m3 = __ballot(v.w != 0.f);
    unsigned long long lt = ((unsigned long long)1 << lane) - 1;
    int c0 = __popcll(m0), c1 = c0 + __popcll(m1), c2 = c1 + __popcll(m2);
    int total = c2 + __popcll(m3);
    int p0 = __popcll(m0 & lt);
    int p1 = c0 + __popcll(m1 & lt);
    int p2 = c1 + __popcll(m2 & lt);
    int p3 = c2 + __popcll(m3 & lt);
    uint8_t* nb = nbr + (size_t)row * NL;
    if (v.x != 0.f) nb[p0] = (uint8_t)(lane * 4 + 0);
    if (v.y != 0.f) nb[p1] = (uint8_t)(lane * 4 + 1);
    if (v.z != 0.f) nb[p2] = (uint8_t)(lane * 4 + 2);
    if (v.w != 0.f) nb[p3] = (uint8_t)(lane * 4 + 3);
    if (lane == 0) cnt[row] = total;
}

// ---------------- colsum nonzero flags (for mask only; order-independent)
__global__ void adjcol_kernel(const float* __restrict__ adj, unsigned* __restrict__ colnz) {
    int b = blockIdx.x >> 2, ic = blockIdx.x & 3;
    int t = threadIdx.x;
    unsigned acc = 0;
    for (int i = ic * 64; i < ic * 64 + 64; ++i)
        acc |= (adj[((size_t)(b * NL + i)) * NL + t] != 0.f) ? 1u : 0u;
    if (acc) atomicOr(&colnz[b * NL + t], 1u);
}

__global__ void mask_kernel(const float* __restrict__ rsum, const unsigned* __restrict__ colnz,
                            float* __restrict__ outm) {
    int r = blockIdx.x * 256 + threadIdx.x;
    outm[r] = (rsum[r] == 0.f && colnz[r] == 0u) ? 1.0f : 0.0f;
}

// ---------------- bf16 MFMA GEMM: out[M][256] f32 = A[M][lda] * Bp[n][k]^T
// tile 128x64, BK=32, 4 waves (2x2), each wave 64x32 = 4x2 frags of 16x16x32
__global__ __launch_bounds__(256) void gemm_kernel(const short* __restrict__ A, int lda, int nkt,
                                                   const short* __restrict__ Bp, int ldb,
                                                   float* __restrict__ out) {
    __shared__ short At[128][32];
    __shared__ short Bt[64][32];
    int mt = blockIdx.x >> 2, nt = blockIdx.x & 3;
    int tid = threadIdx.x;
    int lane = tid & 63, wid = tid >> 6;
    int wr = wid >> 1, wc = wid & 1;
    int lr = lane & 15, lc = lane >> 4;
    f32x4 acc[4][2] = {};
    const short* Ab = A + (size_t)mt * 128 * lda;
    const short* Bb = Bp + (size_t)nt * 64 * ldb;
    for (int kt = 0; kt < nkt; ++kt) {
        int k0 = kt * 32;
        __syncthreads();
        #pragma unroll
        for (int it = 0; it < 2; ++it) {
            int idx = tid + it * 256;
            int row = idx >> 2, c = idx & 3;
            short8 v = *(const short8*)(Ab + (size_t)row * lda + k0 + c * 8);
            int cs = c ^ ((row >> 1) & 3);
            *(short8*)&At[row][cs * 8] = v;
        }
        {
            int n = tid >> 2, c = tid & 3;
            short8 v = *(const short8*)(Bb + (size_t)n * ldb + k0 + c * 8);
            int cs = c ^ ((n >> 1) & 3);
            *(short8*)&Bt[n][cs * 8] = v;
        }
        __syncthreads();
        short8 af[4], bf[2];
        #pragma unroll
        for (int mi = 0; mi < 4; ++mi) {
            int row = wr * 64 + mi * 16 + lr;
            int cs = lc ^ ((row >> 1) & 3);
            af[mi] = *(const short8*)&At[row][cs * 8];
        }
        #pragma unroll
        for (int ni = 0; ni < 2; ++ni) {
            int row = wc * 32 + ni * 16 + lr;
            int cs = lc ^ ((row >> 1) & 3);
            bf[ni] = *(const short8*)&Bt[row][cs * 8];
        }
        #pragma unroll
        for (int mi = 0; mi < 4; ++mi)
            #pragma unroll
            for (int ni = 0; ni < 2; ++ni)
                acc[mi][ni] = __builtin_amdgcn_mfma_f32_16x16x32_bf16(af[mi], bf[ni], acc[mi][ni], 0, 0, 0);
    }
    int orow0 = mt * 128 + wr * 64;
    int ocol0 = nt * 64 + wc * 32;
    #pragma unroll
    for (int mi = 0; mi < 4; ++mi)
        #pragma unroll
        for (int ni = 0; ni < 2; ++ni)
            #pragma unroll
            for (int r = 0; r < 4; ++r)
                out[(size_t)(orow0 + mi * 16 + lc * 4 + r) * NP + ocol0 + ni * 16 + lr] = acc[mi][ni][r];
}

// ---------------- sparse adj gather + epilogue. FINAL=0: write x1 bf16 [32768][256]; FINAL=1: f32 out [32768][200]
template <int FINAL>
__global__ void spmm_kernel(const float* __restrict__ Y, const uint8_t* __restrict__ nbr,
                            const int* __restrict__ cnt, const float* __restrict__ dinv,
                            const float* __restrict__ bias, short* __restrict__ x1b,
                            float* __restrict__ outx) {
    int row = blockIdx.x * 4 + (threadIdx.x >> 6);
    int lane = threadIdx.x & 63;
    const float* Yb = Y + (size_t)(row & ~255) * NP;   // batch base
    float ax = 0.f, ay = 0.f, az = 0.f, aw = 0.f;
    int n = cnt[row];
    const uint8_t* nb = nbr + (size_t)row * NL;
    for (int t = 0; t < n; ++t) {
        int j = nb[t];
        float4 v = ((const float4*)(Yb + (size_t)j * NP))[lane];
        ax += v.x; ay += v.y; az += v.z; aw += v.w;
    }
    float4 sv = ((const float4*)(Y + (size_t)row * NP))[lane];
    float di = dinv[row];
    int col = lane * 4;
    float bx = 0.f, by = 0.f, bz = 0.f, bw = 0.f;
    if (col < MEM) { float4 bv = *(const float4*)(bias + col); bx = bv.x; by = bv.y; bz = bv.z; bw = bv.w; }
    float h0 = fmaxf((ax + sv.x + 2.f * bx) * di, 0.f);
    float h1 = fmaxf((ay + sv.y + 2.f * by) * di, 0.f);
    float h2 = fmaxf((az + sv.z + 2.f * bz) * di, 0.f);
    float h3 = fmaxf((aw + sv.w + 2.f * bw) * di, 0.f);
    if (FINAL == 0) {
        ushort4 st;
        if (col < MEM) { st.x = f2b(h0); st.y = f2b(h1); st.z = f2b(h2); st.w = f2b(h3); }
        else           { st.x = 0; st.y = 0; st.z = 0; st.w = 0; }
        *(ushort4*)((unsigned short*)x1b + (size_t)row * NP + col) = st;
    } else {
        if (col < MEM) {
            float4 o; o.x = h0; o.y = h1; o.z = h2; o.w = h3;
            *(float4*)(outx + (size_t)row * MEM + col) = o;
        }
    }
}

extern "C" void kernel_launch(void* const* d_in, const int* in_sizes, int n_in,
                              void* d_out, int out_size, void* d_ws, size_t ws_size,
                              hipStream_t stream) {
    const int*   words = (const int*)d_in[0];
    const int*   pos   = (const int*)d_in[1];
    const int*   ner   = (const int*)d_in[2];
    const float* adj   = (const float*)d_in[3];
    const float* embW  = (const float*)d_in[4];
    const float* posW  = (const float*)d_in[5];
    const float* nerW  = (const float*)d_in[6];
    const float* W0    = (const float*)d_in[7];
    const float* b0    = (const float*)d_in[8];
    const float* W1    = (const float*)d_in[9];
    const float* b1    = (const float*)d_in[10];
    float* out = (float*)d_out;

    char* ws = (char*)d_ws;
    size_t off = 0;
    short* x0b = (short*)(ws + off);        off += (size_t)NROWS * KP1 * 2;       // 25.2 MB
    short* W0p = (short*)(ws + off);        off += (size_t)NP * KP1 * 2;          // 196 KB
    short* W1p = (short*)(ws + off);        off += (size_t)NP * NP * 2;           // 131 KB
    float* Y   = (float*)(ws + off);        off += (size_t)NROWS * NP * 4;        // 33.5 MB (y0 then y1)
    short* X1b = (short*)(ws + off);        off += (size_t)NROWS * NP * 2;        // 16.8 MB
    float* dinv = (float*)(ws + off);       off += (size_t)NROWS * 4;
    float* rsum = (float*)(ws + off);       off += (size_t)NROWS * 4;
    unsigned* colnz = (unsigned*)(ws + off); size_t colnz_off = off; off += (size_t)NROWS * 4;
    int*  cnt  = (int*)(ws + off);          off += (size_t)NROWS * 4;
    uint8_t* nbr = (uint8_t*)(ws + off);    off += (size_t)NROWS * NL;            // 8.4 MB

    hipMemsetAsync(ws + colnz_off, 0, (size_t)NROWS * 4, stream);

    prep_weights<<<(NP * KP1 + NP * NP + 255) / 256, 256, 0, stream>>>(W0, W1, W0p, W1p);
    embed_kernel<<<NROWS, KP1, 0, stream>>>(words, pos, ner, embW, posW, nerW, x0b);
    adjrow_kernel<<<NROWS / 4, 256, 0, stream>>>(adj, dinv, rsum, nbr, cnt);
    adjcol_kernel<<<NB * 4, 256, 0, stream>>>(adj, colnz);
    mask_kernel<<<NROWS / 256, 256, 0, stream>>>(rsum, colnz, out + OUT_X);

    // layer 1: y0 = x0 @ W0^T ; x1 = relu((adj@y0 + y0 + 2 b0)/denom)
    gemm_kernel<<<(NROWS / 128) * 4, 256, 0, stream>>>(x0b, KP1, KP1 / 32, W0p, KP1, Y);
    spmm_kernel<0><<<NROWS / 4, 256, 0, stream>>>(Y, nbr, cnt, dinv, b0, X1b, nullptr);
    // layer 2: y1 = x1 @ W1^T ; out = relu((adj@y1 + y1 + 2 b1)/denom)
    gemm_kernel<<<(NROWS / 128) * 4, 256, 0, stream>>>(X1b, NP, NP / 32, W1p, NP, Y);
    spmm_kernel<1><<<NROWS / 4, 256, 0, stream>>>(Y, nbr, cnt, dinv, b1, nullptr, out);
}

// Round 3
// 177.809 us; speedup vs baseline: 1.0927x; 1.0927x over previous
//
#include <hip/hip_runtime.h>
#include <hip/hip_bf16.h>
#include <stdint.h>

typedef __attribute__((ext_vector_type(8))) short short8;
typedef __attribute__((ext_vector_type(4))) float f32x4;

#define NB 128
#define NL 256
#define NROWS 32768        // B*L
#define IN_DIM 360
#define KP1 384            // padded K for layer-1 GEMM
#define MEM 200
#define NP 256             // padded N
#define OUT_X (NROWS * MEM)

__device__ __forceinline__ unsigned short f2b(float f) {
    unsigned u = __builtin_bit_cast(unsigned, f);
    unsigned r = (u + 0x7FFFu + ((u >> 16) & 1u)) >> 16;
    return (unsigned short)r;
}

// ---------------- weight prep: W0p[256][384], W1p[256][256] (bf16, [n][k], zero-padded)
__global__ void prep_weights(const float* __restrict__ W0, const float* __restrict__ W1,
                             short* __restrict__ W0p, short* __restrict__ W1p) {
    int idx = blockIdx.x * 256 + threadIdx.x;
    if (idx < NP * KP1) {
        int n = idx / KP1, k = idx - n * KP1;
        float v = (n < MEM && k < IN_DIM) ? W0[n * IN_DIM + k] : 0.f;
        W0p[idx] = (short)f2b(v);
    } else {
        int i2 = idx - NP * KP1;
        if (i2 < NP * NP) {
            int n = i2 >> 8, k = i2 & 255;
            float v = (n < MEM && k < MEM) ? W1[n * MEM + k] : 0.f;
            W1p[i2] = (short)f2b(v);
        }
    }
}

// ---------------- embedding concat -> x0 bf16 [32768][384]
__global__ void embed_kernel(const int* __restrict__ words, const int* __restrict__ pos,
                             const int* __restrict__ ner,
                             const float* __restrict__ embW, const float* __restrict__ posW,
                             const float* __restrict__ nerW, short* __restrict__ x0b) {
    int row = blockIdx.x;
    int k = threadIdx.x;              // blockDim = 384
    float v = 0.f;
    if (k < 300)      v = embW[(size_t)words[row] * 300 + k];
    else if (k < 330) v = posW[pos[row] * 30 + (k - 300)];
    else if (k < 360) v = nerW[ner[row] * 30 + (k - 330)];
    x0b[(size_t)row * KP1 + k] = (short)f2b(v);
}

// ---------------- adj row pass: rowsum, denom_inv, 256-bit nbr masks, col-nonzero flags
// mask word w, bit l  <->  within-batch column 4*l + w   (from float4 lane layout)
__global__ void adjrow_kernel(const float* __restrict__ adj, float* __restrict__ dinv,
                              float* __restrict__ rsum, unsigned long long* __restrict__ msk,
                              unsigned* __restrict__ colnz) {
    int row = blockIdx.x * 4 + (threadIdx.x >> 6);
    int lane = threadIdx.x & 63;
    const float4* ar = (const float4*)(adj + (size_t)row * NL);
    float4 v = ar[lane];
    float s = v.x + v.y + v.z + v.w;
    #pragma unroll
    for (int off = 32; off >= 1; off >>= 1) s += __shfl_xor(s, off);
    unsigned long long m0 = __ballot(v.x != 0.f);
    unsigned long long m1 = __ballot(v.y != 0.f);
    unsigned long long m2 = __ballot(v.z != 0.f);
    unsigned long long m3 = __ballot(v.w != 0.f);
    if (lane == 0) {
        rsum[row] = s; dinv[row] = 1.0f / (s + 1.0f);
        unsigned long long* mr = msk + (size_t)row * 4;
        mr[0] = m0; mr[1] = m1; mr[2] = m2; mr[3] = m3;
    }
    unsigned* cz = colnz + ((row >> 8) << 8);   // batch base
    if (v.x != 0.f) atomicOr(&cz[lane * 4 + 0], 1u);
    if (v.y != 0.f) atomicOr(&cz[lane * 4 + 1], 1u);
    if (v.z != 0.f) atomicOr(&cz[lane * 4 + 2], 1u);
    if (v.w != 0.f) atomicOr(&cz[lane * 4 + 3], 1u);
}

__global__ void mask_kernel(const float* __restrict__ rsum, const unsigned* __restrict__ colnz,
                            float* __restrict__ outm) {
    int r = blockIdx.x * 256 + threadIdx.x;
    outm[r] = (rsum[r] == 0.f && colnz[r] == 0u) ? 1.0f : 0.0f;
}

// ---------------- bf16 MFMA GEMM: out[M][256] f32 = A[M][lda] * Bp[n][k]^T
// tile 128x64, BK=32, 4 waves (2x2), each wave 64x32 = 4x2 frags of 16x16x32
__global__ __launch_bounds__(256) void gemm_kernel(const short* __restrict__ A, int lda, int nkt,
                                                   const short* __restrict__ Bp, int ldb,
                                                   float* __restrict__ out) {
    __shared__ short At[128][32];
    __shared__ short Bt[64][32];
    int mt = blockIdx.x >> 2, nt = blockIdx.x & 3;
    int tid = threadIdx.x;
    int lane = tid & 63, wid = tid >> 6;
    int wr = wid >> 1, wc = wid & 1;
    int lr = lane & 15, lc = lane >> 4;
    f32x4 acc[4][2] = {};
    const short* Ab = A + (size_t)mt * 128 * lda;
    const short* Bb = Bp + (size_t)nt * 64 * ldb;
    for (int kt = 0; kt < nkt; ++kt) {
        int k0 = kt * 32;
        __syncthreads();
        #pragma unroll
        for (int it = 0; it < 2; ++it) {
            int idx = tid + it * 256;
            int row = idx >> 2, c = idx & 3;
            short8 v = *(const short8*)(Ab + (size_t)row * lda + k0 + c * 8);
            int cs = c ^ ((row >> 1) & 3);
            *(short8*)&At[row][cs * 8] = v;
        }
        {
            int n = tid >> 2, c = tid & 3;
            short8 v = *(const short8*)(Bb + (size_t)n * ldb + k0 + c * 8);
            int cs = c ^ ((n >> 1) & 3);
            *(short8*)&Bt[n][cs * 8] = v;
        }
        __syncthreads();
        short8 af[4], bf[2];
        #pragma unroll
        for (int mi = 0; mi < 4; ++mi) {
            int row = wr * 64 + mi * 16 + lr;
            int cs = lc ^ ((row >> 1) & 3);
            af[mi] = *(const short8*)&At[row][cs * 8];
        }
        #pragma unroll
        for (int ni = 0; ni < 2; ++ni) {
            int row = wc * 32 + ni * 16 + lr;
            int cs = lc ^ ((row >> 1) & 3);
            bf[ni] = *(const short8*)&Bt[row][cs * 8];
        }
        #pragma unroll
        for (int mi = 0; mi < 4; ++mi)
            #pragma unroll
            for (int ni = 0; ni < 2; ++ni)
                acc[mi][ni] = __builtin_amdgcn_mfma_f32_16x16x32_bf16(af[mi], bf[ni], acc[mi][ni], 0, 0, 0);
    }
    int orow0 = mt * 128 + wr * 64;
    int ocol0 = nt * 64 + wc * 32;
    #pragma unroll
    for (int mi = 0; mi < 4; ++mi)
        #pragma unroll
        for (int ni = 0; ni < 2; ++ni)
            #pragma unroll
            for (int r = 0; r < 4; ++r)
                out[(size_t)(orow0 + mi * 16 + lc * 4 + r) * NP + ocol0 + ni * 16 + lr] = acc[mi][ni][r];
}

// ---------------- LDS-staged sparse gather + epilogue.
// block = (batch, 64-col quarter). Stage Y[batch][:, q*64..q*64+64) in LDS (64 KB),
// then 16 waves x 16 rows: acc = sum_{j in nbr(row)} Ysm[j][lane] via scalar-mask ctz loop.
// FINAL=0: write x1 bf16 [32768][256]; FINAL=1: f32 out [32768][200]
template <int FINAL>
__global__ __launch_bounds__(1024) void spmm_kernel(
    const float* __restrict__ Y, const unsigned long long* __restrict__ msk,
    const float* __restrict__ dinv, const float* __restrict__ bias,
    short* __restrict__ x1b, float* __restrict__ outx) {
    __shared__ float Ysm[NL][64];
    int batch = blockIdx.x >> 2, q = blockIdx.x & 3;
    int tid = threadIdx.x;
    const float* Yb = Y + (size_t)batch * NL * NP + q * 64;
    #pragma unroll
    for (int k = 0; k < 4; ++k) {
        int f = tid + k * 1024;            // float4 index, 4096 total
        int row = f >> 4, c4 = (f & 15) << 2;
        *(float4*)&Ysm[row][c4] = *(const float4*)(Yb + (size_t)row * NP + c4);
    }
    __syncthreads();
    int wid = tid >> 6, lane = tid & 63;
    int col = q * 64 + lane;
    float bv = (col < MEM) ? bias[col] : 0.f;
    for (int r = wid * 16; r < wid * 16 + 16; ++r) {
        int rowg = batch * NL + r;
        const unsigned long long* mr = msk + (size_t)rowg * 4;
        float acc = 0.f;
        #pragma unroll
        for (int w = 0; w < 4; ++w) {
            unsigned long long m = mr[w];
            // readfirstlane returns int: zero-extend explicitly (sign-extension here
            // was round 2's correctness bug — spurious high-word neighbor bits).
            unsigned lo = (unsigned)__builtin_amdgcn_readfirstlane((unsigned)m);
            unsigned hi = (unsigned)__builtin_amdgcn_readfirstlane((unsigned)(m >> 32));
            m = ((unsigned long long)hi << 32) | (unsigned long long)lo;
            while (m) {
                int bpos = __builtin_ctzll(m); m &= m - 1;
                acc += Ysm[(bpos << 2) | w][lane];
            }
        }
        float h = fmaxf((acc + Ysm[r][lane] + 2.f * bv) * dinv[rowg], 0.f);
        if (FINAL == 0) {
            ((unsigned short*)x1b)[(size_t)rowg * NP + col] = f2b(h);
        } else if (col < MEM) {
            outx[(size_t)rowg * MEM + col] = h;
        }
    }
}

extern "C" void kernel_launch(void* const* d_in, const int* in_sizes, int n_in,
                              void* d_out, int out_size, void* d_ws, size_t ws_size,
                              hipStream_t stream) {
    const int*   words = (const int*)d_in[0];
    const int*   pos   = (const int*)d_in[1];
    const int*   ner   = (const int*)d_in[2];
    const float* adj   = (const float*)d_in[3];
    const float* embW  = (const float*)d_in[4];
    const float* posW  = (const float*)d_in[5];
    const float* nerW  = (const float*)d_in[6];
    const float* W0    = (const float*)d_in[7];
    const float* b0    = (const float*)d_in[8];
    const float* W1    = (const float*)d_in[9];
    const float* b1    = (const float*)d_in[10];
    float* out = (float*)d_out;

    char* ws = (char*)d_ws;
    size_t off = 0;
    short* x0b = (short*)(ws + off);        off += (size_t)NROWS * KP1 * 2;       // 25.2 MB
    short* W0p = (short*)(ws + off);        off += (size_t)NP * KP1 * 2;          // 196 KB
    short* W1p = (short*)(ws + off);        off += (size_t)NP * NP * 2;           // 131 KB
    float* Y   = (float*)(ws + off);        off += (size_t)NROWS * NP * 4;        // 33.5 MB
    short* X1b = (short*)(ws + off);        off += (size_t)NROWS * NP * 2;        // 16.8 MB
    float* dinv = (float*)(ws + off);       off += (size_t)NROWS * 4;
    float* rsum = (float*)(ws + off);       off += (size_t)NROWS * 4;
    unsigned* colnz = (unsigned*)(ws + off); size_t colnz_off = off; off += (size_t)NROWS * 4;
    unsigned long long* msk = (unsigned long long*)(ws + off); off += (size_t)NROWS * 32; // 1 MB

    hipMemsetAsync(ws + colnz_off, 0, (size_t)NROWS * 4, stream);

    prep_weights<<<(NP * KP1 + NP * NP + 255) / 256, 256, 0, stream>>>(W0, W1, W0p, W1p);
    embed_kernel<<<NROWS, KP1, 0, stream>>>(words, pos, ner, embW, posW, nerW, x0b);
    adjrow_kernel<<<NROWS / 4, 256, 0, stream>>>(adj, dinv, rsum, msk, colnz);
    mask_kernel<<<NROWS / 256, 256, 0, stream>>>(rsum, colnz, out + OUT_X);

    // layer 1: y0 = x0 @ W0^T ; x1 = relu((adj@y0 + y0 + 2 b0)/denom)
    gemm_kernel<<<(NROWS / 128) * 4, 256, 0, stream>>>(x0b, KP1, KP1 / 32, W0p, KP1, Y);
    spmm_kernel<0><<<NB * 4, 1024, 0, stream>>>(Y, msk, dinv, b0, X1b, nullptr);
    // layer 2: y1 = x1 @ W1^T ; out = relu((adj@y1 + y1 + 2 b1)/denom)
    gemm_kernel<<<(NROWS / 128) * 4, 256, 0, stream>>>(X1b, NP, NP / 32, W1p, NP, Y);
    spmm_kernel<1><<<NB * 4, 1024, 0, stream>>>(Y, msk, dinv, b1, nullptr, out);
}

// Round 4
// 166.335 us; speedup vs baseline: 1.1681x; 1.0690x over previous
//
#include <hip/hip_runtime.h>
#include <hip/hip_bf16.h>
#include <stdint.h>

typedef __attribute__((ext_vector_type(8))) short short8;
typedef __attribute__((ext_vector_type(4))) float f32x4;

#define NB 128
#define NL 256
#define NROWS 32768        // B*L
#define IN_DIM 360
#define KP1 384            // padded K for layer-1 GEMM (permuted layout, see embed_kernel)
#define MEM 200
#define NP 256             // padded N
#define OUT_X (NROWS * MEM)

// Permuted K layout for x0/W0p (keeps every 8-col chunk single-table):
//   kp 0..299   : emb k = kp
//   kp 304..333 : pos k = kp-304
//   kp 336..365 : ner k = kp-336
//   else        : zero pad
// GEMM1 is invariant since both A and B use the same permutation.

__device__ __forceinline__ unsigned short f2b(float f) {
    unsigned u = __builtin_bit_cast(unsigned, f);
    unsigned r = (u + 0x7FFFu + ((u >> 16) & 1u)) >> 16;
    return (unsigned short)r;
}

// ---------------- weight prep: W0p[256][384] (permuted K), W1p[256][256] (bf16, [n][k])
__global__ void prep_weights(const float* __restrict__ W0, const float* __restrict__ W1,
                             short* __restrict__ W0p, short* __restrict__ W1p) {
    int idx = blockIdx.x * 256 + threadIdx.x;
    if (idx < NP * KP1) {
        int n = idx / KP1, kp = idx - n * KP1;
        float v = 0.f;
        if (n < MEM) {
            if (kp < 300)                   v = W0[n * IN_DIM + kp];
            else if (kp >= 304 && kp < 334) v = W0[n * IN_DIM + 300 + (kp - 304)];
            else if (kp >= 336 && kp < 366) v = W0[n * IN_DIM + 330 + (kp - 336)];
        }
        W0p[idx] = (short)f2b(v);
    } else {
        int i2 = idx - NP * KP1;
        if (i2 < NP * NP) {
            int n = i2 >> 8, k = i2 & 255;
            float v = (n < MEM && k < MEM) ? W1[n * MEM + k] : 0.f;
            W1p[i2] = (short)f2b(v);
        }
    }
}

// ---------------- embedding concat -> x0 bf16 [32768][384] (permuted K layout)
// block = 384 threads = 8 rows x 48 chunks; each thread writes one short8 (8 cols).
__global__ __launch_bounds__(384) void embed_kernel(
    const int* __restrict__ words, const int* __restrict__ pos, const int* __restrict__ ner,
    const float* __restrict__ embW, const float* __restrict__ posW,
    const float* __restrict__ nerW, short* __restrict__ x0b) {
    int t = threadIdx.x;
    int r = t / 48, c = t - r * 48;
    int row = blockIdx.x * 8 + r;
    float vals[8];
    #pragma unroll
    for (int i = 0; i < 8; ++i) vals[i] = 0.f;
    if (c < 37) {                       // pure emb: cols 8c..8c+7 < 300
        const float* src = embW + (size_t)words[row] * 300 + c * 8;
        float4 a = *(const float4*)src;
        float4 b = *(const float4*)(src + 4);
        vals[0] = a.x; vals[1] = a.y; vals[2] = a.z; vals[3] = a.w;
        vals[4] = b.x; vals[5] = b.y; vals[6] = b.z; vals[7] = b.w;
    } else if (c == 37) {               // emb tail: cols 296..299 + pad
        const float* src = embW + (size_t)words[row] * 300 + 296;
        vals[0] = src[0]; vals[1] = src[1]; vals[2] = src[2]; vals[3] = src[3];
    } else if (c <= 41) {               // pos: kp 304..333
        int k0 = c * 8 - 304;           // 0,8,16,24
        const float* src = posW + (size_t)pos[row] * 30 + k0;
        #pragma unroll
        for (int i = 0; i < 8; ++i) if (k0 + i < 30) vals[i] = src[i];
    } else if (c <= 45) {               // ner: kp 336..365
        int k0 = c * 8 - 336;           // 0,8,16,24
        const float* src = nerW + (size_t)ner[row] * 30 + k0;
        #pragma unroll
        for (int i = 0; i < 8; ++i) if (k0 + i < 30) vals[i] = src[i];
    }                                   // c 46,47: zero pad
    short8 st;
    #pragma unroll
    for (int i = 0; i < 8; ++i) st[i] = (short)f2b(vals[i]);
    *(short8*)((unsigned short*)x0b + (size_t)row * KP1 + c * 8) = st;
}

// ---------------- adj row pass: rowsum, denom_inv, 256-bit nbr masks, col-nonzero flags
// mask word w, bit l  <->  within-batch column 4*l + w   (from float4 lane layout)
__global__ void adjrow_kernel(const float* __restrict__ adj, float* __restrict__ dinv,
                              float* __restrict__ rsum, unsigned long long* __restrict__ msk,
                              unsigned* __restrict__ colnz) {
    int row = blockIdx.x * 4 + (threadIdx.x >> 6);
    int lane = threadIdx.x & 63;
    const float4* ar = (const float4*)(adj + (size_t)row * NL);
    float4 v = ar[lane];
    float s = v.x + v.y + v.z + v.w;
    #pragma unroll
    for (int off = 32; off >= 1; off >>= 1) s += __shfl_xor(s, off);
    unsigned long long m0 = __ballot(v.x != 0.f);
    unsigned long long m1 = __ballot(v.y != 0.f);
    unsigned long long m2 = __ballot(v.z != 0.f);
    unsigned long long m3 = __ballot(v.w != 0.f);
    if (lane == 0) {
        rsum[row] = s; dinv[row] = 1.0f / (s + 1.0f);
        unsigned long long* mr = msk + (size_t)row * 4;
        mr[0] = m0; mr[1] = m1; mr[2] = m2; mr[3] = m3;
    }
    unsigned* cz = colnz + ((row >> 8) << 8);   // batch base
    if (v.x != 0.f) atomicOr(&cz[lane * 4 + 0], 1u);
    if (v.y != 0.f) atomicOr(&cz[lane * 4 + 1], 1u);
    if (v.z != 0.f) atomicOr(&cz[lane * 4 + 2], 1u);
    if (v.w != 0.f) atomicOr(&cz[lane * 4 + 3], 1u);
}

__global__ void mask_kernel(const float* __restrict__ rsum, const unsigned* __restrict__ colnz,
                            float* __restrict__ outm) {
    int r = blockIdx.x * 256 + threadIdx.x;
    outm[r] = (rsum[r] == 0.f && colnz[r] == 0u) ? 1.0f : 0.0f;
}

// ---------------- bf16 MFMA GEMM: out[M][256] f32 = A[M][lda] * Bp[n][k]^T
// tile 128x64, BK=32, 4 waves (2x2), each wave 64x32 = 4x2 frags of 16x16x32
__global__ __launch_bounds__(256) void gemm_kernel(const short* __restrict__ A, int lda, int nkt,
                                                   const short* __restrict__ Bp, int ldb,
                                                   float* __restrict__ out) {
    __shared__ short At[128][32];
    __shared__ short Bt[64][32];
    int mt = blockIdx.x >> 2, nt = blockIdx.x & 3;
    int tid = threadIdx.x;
    int lane = tid & 63, wid = tid >> 6;
    int wr = wid >> 1, wc = wid & 1;
    int lr = lane & 15, lc = lane >> 4;
    f32x4 acc[4][2] = {};
    const short* Ab = A + (size_t)mt * 128 * lda;
    const short* Bb = Bp + (size_t)nt * 64 * ldb;
    for (int kt = 0; kt < nkt; ++kt) {
        int k0 = kt * 32;
        __syncthreads();
        #pragma unroll
        for (int it = 0; it < 2; ++it) {
            int idx = tid + it * 256;
            int row = idx >> 2, c = idx & 3;
            short8 v = *(const short8*)(Ab + (size_t)row * lda + k0 + c * 8);
            int cs = c ^ ((row >> 1) & 3);
            *(short8*)&At[row][cs * 8] = v;
        }
        {
            int n = tid >> 2, c = tid & 3;
            short8 v = *(const short8*)(Bb + (size_t)n * ldb + k0 + c * 8);
            int cs = c ^ ((n >> 1) & 3);
            *(short8*)&Bt[n][cs * 8] = v;
        }
        __syncthreads();
        short8 af[4], bf[2];
        #pragma unroll
        for (int mi = 0; mi < 4; ++mi) {
            int row = wr * 64 + mi * 16 + lr;
            int cs = lc ^ ((row >> 1) & 3);
            af[mi] = *(const short8*)&At[row][cs * 8];
        }
        #pragma unroll
        for (int ni = 0; ni < 2; ++ni) {
            int row = wc * 32 + ni * 16 + lr;
            int cs = lc ^ ((row >> 1) & 3);
            bf[ni] = *(const short8*)&Bt[row][cs * 8];
        }
        #pragma unroll
        for (int mi = 0; mi < 4; ++mi)
            #pragma unroll
            for (int ni = 0; ni < 2; ++ni)
                acc[mi][ni] = __builtin_amdgcn_mfma_f32_16x16x32_bf16(af[mi], bf[ni], acc[mi][ni], 0, 0, 0);
    }
    int orow0 = mt * 128 + wr * 64;
    int ocol0 = nt * 64 + wc * 32;
    #pragma unroll
    for (int mi = 0; mi < 4; ++mi)
        #pragma unroll
        for (int ni = 0; ni < 2; ++ni)
            #pragma unroll
            for (int r = 0; r < 4; ++r)
                out[(size_t)(orow0 + mi * 16 + lc * 4 + r) * NP + ocol0 + ni * 16 + lr] = acc[mi][ni][r];
}

// ---------------- LDS-staged sparse gather + epilogue.
// block = (batch, 64-col quarter). Stage Y[batch][:, q*64..q*64+64) in LDS (64 KB),
// then 16 waves x 16 rows: acc = sum_{j in nbr(row)} Ysm[j][lane] via scalar-mask ctz loop.
// FINAL=0: write x1 bf16 [32768][256]; FINAL=1: f32 out [32768][200]
template <int FINAL>
__global__ __launch_bounds__(1024) void spmm_kernel(
    const float* __restrict__ Y, const unsigned long long* __restrict__ msk,
    const float* __restrict__ dinv, const float* __restrict__ bias,
    short* __restrict__ x1b, float* __restrict__ outx) {
    __shared__ float Ysm[NL][64];
    int batch = blockIdx.x >> 2, q = blockIdx.x & 3;
    int tid = threadIdx.x;
    const float* Yb = Y + (size_t)batch * NL * NP + q * 64;
    #pragma unroll
    for (int k = 0; k < 4; ++k) {
        int f = tid + k * 1024;            // float4 index, 4096 total
        int row = f >> 4, c4 = (f & 15) << 2;
        *(float4*)&Ysm[row][c4] = *(const float4*)(Yb + (size_t)row * NP + c4);
    }
    __syncthreads();
    int wid = tid >> 6, lane = tid & 63;
    int col = q * 64 + lane;
    float bv = (col < MEM) ? bias[col] : 0.f;
    for (int r = wid * 16; r < wid * 16 + 16; ++r) {
        int rowg = batch * NL + r;
        const unsigned long long* mr = msk + (size_t)rowg * 4;
        float acc = 0.f;
        #pragma unroll
        for (int w = 0; w < 4; ++w) {
            unsigned long long m = mr[w];
            // readfirstlane returns int: zero-extend explicitly (sign-extension here
            // was round 2's correctness bug — spurious high-word neighbor bits).
            unsigned lo = (unsigned)__builtin_amdgcn_readfirstlane((unsigned)m);
            unsigned hi = (unsigned)__builtin_amdgcn_readfirstlane((unsigned)(m >> 32));
            m = ((unsigned long long)hi << 32) | (unsigned long long)lo;
            while (m) {
                int bpos = __builtin_ctzll(m); m &= m - 1;
                acc += Ysm[(bpos << 2) | w][lane];
            }
        }
        float h = fmaxf((acc + Ysm[r][lane] + 2.f * bv) * dinv[rowg], 0.f);
        if (FINAL == 0) {
            ((unsigned short*)x1b)[(size_t)rowg * NP + col] = f2b(h);
        } else if (col < MEM) {
            outx[(size_t)rowg * MEM + col] = h;
        }
    }
}

extern "C" void kernel_launch(void* const* d_in, const int* in_sizes, int n_in,
                              void* d_out, int out_size, void* d_ws, size_t ws_size,
                              hipStream_t stream) {
    const int*   words = (const int*)d_in[0];
    const int*   pos   = (const int*)d_in[1];
    const int*   ner   = (const int*)d_in[2];
    const float* adj   = (const float*)d_in[3];
    const float* embW  = (const float*)d_in[4];
    const float* posW  = (const float*)d_in[5];
    const float* nerW  = (const float*)d_in[6];
    const float* W0    = (const float*)d_in[7];
    const float* b0    = (const float*)d_in[8];
    const float* W1    = (const float*)d_in[9];
    const float* b1    = (const float*)d_in[10];
    float* out = (float*)d_out;

    char* ws = (char*)d_ws;
    size_t off = 0;
    short* x0b = (short*)(ws + off);        off += (size_t)NROWS * KP1 * 2;       // 25.2 MB
    short* W0p = (short*)(ws + off);        off += (size_t)NP * KP1 * 2;          // 196 KB
    short* W1p = (short*)(ws + off);        off += (size_t)NP * NP * 2;           // 131 KB
    float* Y   = (float*)(ws + off);        off += (size_t)NROWS * NP * 4;        // 33.5 MB
    short* X1b = (short*)(ws + off);        off += (size_t)NROWS * NP * 2;        // 16.8 MB
    float* dinv = (float*)(ws + off);       off += (size_t)NROWS * 4;
    float* rsum = (float*)(ws + off);       off += (size_t)NROWS * 4;
    unsigned* colnz = (unsigned*)(ws + off); size_t colnz_off = off; off += (size_t)NROWS * 4;
    unsigned long long* msk = (unsigned long long*)(ws + off); off += (size_t)NROWS * 32; // 1 MB

    hipMemsetAsync(ws + colnz_off, 0, (size_t)NROWS * 4, stream);

    prep_weights<<<(NP * KP1 + NP * NP + 255) / 256, 256, 0, stream>>>(W0, W1, W0p, W1p);
    embed_kernel<<<NROWS / 8, 384, 0, stream>>>(words, pos, ner, embW, posW, nerW, x0b);
    adjrow_kernel<<<NROWS / 4, 256, 0, stream>>>(adj, dinv, rsum, msk, colnz);
    mask_kernel<<<NROWS / 256, 256, 0, stream>>>(rsum, colnz, out + OUT_X);

    // layer 1: y0 = x0 @ W0^T ; x1 = relu((adj@y0 + y0 + 2 b0)/denom)
    gemm_kernel<<<(NROWS / 128) * 4, 256, 0, stream>>>(x0b, KP1, KP1 / 32, W0p, KP1, Y);
    spmm_kernel<0><<<NB * 4, 1024, 0, stream>>>(Y, msk, dinv, b0, X1b, nullptr);
    // layer 2: y1 = x1 @ W1^T ; out = relu((adj@y1 + y1 + 2 b1)/denom)
    gemm_kernel<<<(NROWS / 128) * 4, 256, 0, stream>>>(X1b, NP, NP / 32, W1p, NP, Y);
    spmm_kernel<1><<<NB * 4, 1024, 0, stream>>>(Y, msk, dinv, b1, nullptr, out);
}

// Round 5
// 153.003 us; speedup vs baseline: 1.2698x; 1.0871x over previous
//
#include <hip/hip_runtime.h>
#include <hip/hip_bf16.h>
#include <stdint.h>

typedef __attribute__((ext_vector_type(8))) short short8;
typedef __attribute__((ext_vector_type(4))) float f32x4;

#define NB 128
#define NL 256
#define NROWS 32768        // B*L
#define IN_DIM 360
#define KP1 384            // padded K for layer-1 GEMM (permuted layout, see embed_kernel)
#define MEM 200
#define NP 256             // padded N
#define OUT_X (NROWS * MEM)

// Permuted K layout for x0/W0p (keeps every 8-col chunk single-table):
//   kp 0..299   : emb k = kp
//   kp 304..333 : pos k = kp-304
//   kp 336..365 : ner k = kp-336
//   else        : zero pad
// GEMM1 is invariant since both A and B use the same permutation.

__device__ __forceinline__ unsigned short f2b(float f) {
    unsigned u = __builtin_bit_cast(unsigned, f);
    unsigned r = (u + 0x7FFFu + ((u >> 16) & 1u)) >> 16;
    return (unsigned short)r;
}

// ---------------- weight prep: W0p[256][384] (permuted K), W1p[256][256] (bf16, [n][k])
__global__ void prep_weights(const float* __restrict__ W0, const float* __restrict__ W1,
                             short* __restrict__ W0p, short* __restrict__ W1p) {
    int idx = blockIdx.x * 256 + threadIdx.x;
    if (idx < NP * KP1) {
        int n = idx / KP1, kp = idx - n * KP1;
        float v = 0.f;
        if (n < MEM) {
            if (kp < 300)                   v = W0[n * IN_DIM + kp];
            else if (kp >= 304 && kp < 334) v = W0[n * IN_DIM + 300 + (kp - 304)];
            else if (kp >= 336 && kp < 366) v = W0[n * IN_DIM + 330 + (kp - 336)];
        }
        W0p[idx] = (short)f2b(v);
    } else {
        int i2 = idx - NP * KP1;
        if (i2 < NP * NP) {
            int n = i2 >> 8, k = i2 & 255;
            float v = (n < MEM && k < MEM) ? W1[n * MEM + k] : 0.f;
            W1p[i2] = (short)f2b(v);
        }
    }
}

// ---------------- embedding concat -> x0 bf16 [32768][384] (permuted K layout)
// block = 384 threads = 8 rows x 48 chunks; each thread writes one short8 (8 cols).
__global__ __launch_bounds__(384) void embed_kernel(
    const int* __restrict__ words, const int* __restrict__ pos, const int* __restrict__ ner,
    const float* __restrict__ embW, const float* __restrict__ posW,
    const float* __restrict__ nerW, short* __restrict__ x0b) {
    int t = threadIdx.x;
    int r = t / 48, c = t - r * 48;
    int row = blockIdx.x * 8 + r;
    float vals[8];
    #pragma unroll
    for (int i = 0; i < 8; ++i) vals[i] = 0.f;
    if (c < 37) {                       // pure emb: cols 8c..8c+7 < 300
        const float* src = embW + (size_t)words[row] * 300 + c * 8;
        float4 a = *(const float4*)src;
        float4 b = *(const float4*)(src + 4);
        vals[0] = a.x; vals[1] = a.y; vals[2] = a.z; vals[3] = a.w;
        vals[4] = b.x; vals[5] = b.y; vals[6] = b.z; vals[7] = b.w;
    } else if (c == 37) {               // emb tail: cols 296..299 + pad
        const float* src = embW + (size_t)words[row] * 300 + 296;
        vals[0] = src[0]; vals[1] = src[1]; vals[2] = src[2]; vals[3] = src[3];
    } else if (c <= 41) {               // pos: kp 304..333
        int k0 = c * 8 - 304;           // 0,8,16,24
        const float* src = posW + (size_t)pos[row] * 30 + k0;
        #pragma unroll
        for (int i = 0; i < 8; ++i) if (k0 + i < 30) vals[i] = src[i];
    } else if (c <= 45) {               // ner: kp 336..365
        int k0 = c * 8 - 336;           // 0,8,16,24
        const float* src = nerW + (size_t)ner[row] * 30 + k0;
        #pragma unroll
        for (int i = 0; i < 8; ++i) if (k0 + i < 30) vals[i] = src[i];
    }                                   // c 46,47: zero pad
    short8 st;
    #pragma unroll
    for (int i = 0; i < 8; ++i) st[i] = (short)f2b(vals[i]);
    *(short8*)((unsigned short*)x0b + (size_t)row * KP1 + c * 8) = st;
}

// ---------------- adj row pass: rowsum, denom_inv, padded u16 CSR lists, col-nonzero flags
// CSR entry = within-batch column index (LDS source row); list padded to x8 with 256
// (a zeroed LDS row in spmm). Order = (w, lane asc) == previous ctz order (bit-identical sums).
__global__ void adjrow_kernel(const float* __restrict__ adj, float* __restrict__ dinv,
                              float* __restrict__ rsum, unsigned short* __restrict__ nbr,
                              int* __restrict__ cntp, unsigned* __restrict__ colnz) {
    int row = blockIdx.x * 4 + (threadIdx.x >> 6);
    int lane = threadIdx.x & 63;
    const float4* ar = (const float4*)(adj + (size_t)row * NL);
    float4 v = ar[lane];
    float s = v.x + v.y + v.z + v.w;
    #pragma unroll
    for (int off = 32; off >= 1; off >>= 1) s += __shfl_xor(s, off);
    unsigned long long m0 = __ballot(v.x != 0.f);
    unsigned long long m1 = __ballot(v.y != 0.f);
    unsigned long long m2 = __ballot(v.z != 0.f);
    unsigned long long m3 = __ballot(v.w != 0.f);
    unsigned long long lt = ((unsigned long long)1 << lane) - 1;
    int c0 = __popcll(m0), c1 = c0 + __popcll(m1), c2 = c1 + __popcll(m2);
    int total = c2 + __popcll(m3);
    int p0 = __popcll(m0 & lt);
    int p1 = c0 + __popcll(m1 & lt);
    int p2 = c1 + __popcll(m2 & lt);
    int p3 = c2 + __popcll(m3 & lt);
    unsigned short* nb = nbr + (size_t)row * NL;
    if (v.x != 0.f) nb[p0] = (unsigned short)(lane * 4 + 0);
    if (v.y != 0.f) nb[p1] = (unsigned short)(lane * 4 + 1);
    if (v.z != 0.f) nb[p2] = (unsigned short)(lane * 4 + 2);
    if (v.w != 0.f) nb[p3] = (unsigned short)(lane * 4 + 3);
    int padTo = (total + 7) & ~7;
    if (lane < padTo - total) nb[total + lane] = 256;   // sentinel -> zero LDS row
    if (lane == 0) {
        rsum[row] = s; dinv[row] = 1.0f / (s + 1.0f);
        cntp[row] = padTo;
    }
    unsigned* cz = colnz + ((row >> 8) << 8);   // batch base
    if (v.x != 0.f) atomicOr(&cz[lane * 4 + 0], 1u);
    if (v.y != 0.f) atomicOr(&cz[lane * 4 + 1], 1u);
    if (v.z != 0.f) atomicOr(&cz[lane * 4 + 2], 1u);
    if (v.w != 0.f) atomicOr(&cz[lane * 4 + 3], 1u);
}

__global__ void mask_kernel(const float* __restrict__ rsum, const unsigned* __restrict__ colnz,
                            float* __restrict__ outm) {
    int r = blockIdx.x * 256 + threadIdx.x;
    outm[r] = (rsum[r] == 0.f && colnz[r] == 0u) ? 1.0f : 0.0f;
}

// ---------------- bf16 MFMA GEMM: out[M][256] f32 = A[M][lda] * Bp[n][k]^T
// tile 128x64, BK=32, 4 waves (2x2), each wave 64x32 = 4x2 frags of 16x16x32
__global__ __launch_bounds__(256) void gemm_kernel(const short* __restrict__ A, int lda, int nkt,
                                                   const short* __restrict__ Bp, int ldb,
                                                   float* __restrict__ out) {
    __shared__ short At[128][32];
    __shared__ short Bt[64][32];
    int mt = blockIdx.x >> 2, nt = blockIdx.x & 3;
    int tid = threadIdx.x;
    int lane = tid & 63, wid = tid >> 6;
    int wr = wid >> 1, wc = wid & 1;
    int lr = lane & 15, lc = lane >> 4;
    f32x4 acc[4][2] = {};
    const short* Ab = A + (size_t)mt * 128 * lda;
    const short* Bb = Bp + (size_t)nt * 64 * ldb;
    for (int kt = 0; kt < nkt; ++kt) {
        int k0 = kt * 32;
        __syncthreads();
        #pragma unroll
        for (int it = 0; it < 2; ++it) {
            int idx = tid + it * 256;
            int row = idx >> 2, c = idx & 3;
            short8 v = *(const short8*)(Ab + (size_t)row * lda + k0 + c * 8);
            int cs = c ^ ((row >> 1) & 3);
            *(short8*)&At[row][cs * 8] = v;
        }
        {
            int n = tid >> 2, c = tid & 3;
            short8 v = *(const short8*)(Bb + (size_t)n * ldb + k0 + c * 8);
            int cs = c ^ ((n >> 1) & 3);
            *(short8*)&Bt[n][cs * 8] = v;
        }
        __syncthreads();
        short8 af[4], bf[2];
        #pragma unroll
        for (int mi = 0; mi < 4; ++mi) {
            int row = wr * 64 + mi * 16 + lr;
            int cs = lc ^ ((row >> 1) & 3);
            af[mi] = *(const short8*)&At[row][cs * 8];
        }
        #pragma unroll
        for (int ni = 0; ni < 2; ++ni) {
            int row = wc * 32 + ni * 16 + lr;
            int cs = lc ^ ((row >> 1) & 3);
            bf[ni] = *(const short8*)&Bt[row][cs * 8];
        }
        #pragma unroll
        for (int mi = 0; mi < 4; ++mi)
            #pragma unroll
            for (int ni = 0; ni < 2; ++ni)
                acc[mi][ni] = __builtin_amdgcn_mfma_f32_16x16x32_bf16(af[mi], bf[ni], acc[mi][ni], 0, 0, 0);
    }
    int orow0 = mt * 128 + wr * 64;
    int ocol0 = nt * 64 + wc * 32;
    #pragma unroll
    for (int mi = 0; mi < 4; ++mi)
        #pragma unroll
        for (int ni = 0; ni < 2; ++ni)
            #pragma unroll
            for (int r = 0; r < 4; ++r)
                out[(size_t)(orow0 + mi * 16 + lc * 4 + r) * NP + ocol0 + ni * 16 + lr] = acc[mi][ni][r];
}

// ---------------- LDS-staged sparse gather + epilogue, CSR-unrolled, float2/lane.
// block = (batch, 128-col half). Stage Y[batch][:, h*128..+128) in LDS (257 rows, row 256 = zeros),
// 16 waves x 16 rows, dual-row (r, r+8) interleave for ILP; inner chunk = 8 independent ds_read_b64.
// FINAL=0: write x1 bf16 [32768][256]; FINAL=1: f32 out [32768][200]
template <int FINAL>
__global__ __launch_bounds__(1024) void spmm_kernel(
    const float* __restrict__ Y, const unsigned short* __restrict__ nbr,
    const int* __restrict__ cntp, const float* __restrict__ dinv,
    const float* __restrict__ bias, short* __restrict__ x1b, float* __restrict__ outx) {
    extern __shared__ float Ysm[];                 // [257][128]
    int batch = blockIdx.x >> 1, h = blockIdx.x & 1;
    int tid = threadIdx.x;
    const float* Yb = Y + (size_t)batch * NL * NP + h * 128;
    #pragma unroll
    for (int k = 0; k < 8; ++k) {
        int f = tid + k * 1024;                    // float4 index, 8192 total
        int row = f >> 5, c4 = (f & 31) << 2;
        *(float4*)&Ysm[row * 128 + c4] = *(const float4*)(Yb + (size_t)row * NP + c4);
    }
    if (tid < 32) {                                // zero sentinel row 256
        float4 z; z.x = 0.f; z.y = 0.f; z.z = 0.f; z.w = 0.f;
        *(float4*)&Ysm[256 * 128 + tid * 4] = z;
    }
    __syncthreads();
    int wid = tid >> 6, lane = tid & 63;
    int cc = lane * 2;                             // col within half
    int col = h * 128 + cc;                        // global col (even)
    float bv0 = 0.f, bv1 = 0.f;
    if (col < MEM) { bv0 = bias[col]; bv1 = bias[col + 1]; }   // MEM even -> pair valid together
    int r0 = wid * 16;
    for (int rr = 0; rr < 8; ++rr) {
        int rA = r0 + rr, rB = r0 + 8 + rr;
        int gA = batch * NL + rA, gB = batch * NL + rB;
        const unsigned short* nA = nbr + (size_t)gA * NL;
        const unsigned short* nB = nbr + (size_t)gB * NL;
        int npA = cntp[gA], npB = cntp[gB];
        float axA = 0.f, ayA = 0.f, axB = 0.f, ayB = 0.f;
        int nmax = npA > npB ? npA : npB;
        for (int t = 0; t < nmax; t += 8) {
            if (t < npA) {                         // wave-uniform branch
                short8 I = *(const short8*)(nA + t);
                #pragma unroll
                for (int i = 0; i < 8; ++i) {
                    int j = (int)(unsigned short)I[i];
                    float2 v = *(const float2*)&Ysm[j * 128 + cc];
                    axA += v.x; ayA += v.y;
                }
            }
            if (t < npB) {
                short8 I = *(const short8*)(nB + t);
                #pragma unroll
                for (int i = 0; i < 8; ++i) {
                    int j = (int)(unsigned short)I[i];
                    float2 v = *(const float2*)&Ysm[j * 128 + cc];
                    axB += v.x; ayB += v.y;
                }
            }
        }
        float2 sA = *(const float2*)&Ysm[rA * 128 + cc];
        float2 sB = *(const float2*)&Ysm[rB * 128 + cc];
        float dA = dinv[gA], dB = dinv[gB];
        float hA0 = fmaxf((axA + sA.x + 2.f * bv0) * dA, 0.f);
        float hA1 = fmaxf((ayA + sA.y + 2.f * bv1) * dA, 0.f);
        float hB0 = fmaxf((axB + sB.x + 2.f * bv0) * dB, 0.f);
        float hB1 = fmaxf((ayB + sB.y + 2.f * bv1) * dB, 0.f);
        if (FINAL == 0) {
            unsigned pA = (unsigned)f2b(hA0) | ((unsigned)f2b(hA1) << 16);
            unsigned pB = (unsigned)f2b(hB0) | ((unsigned)f2b(hB1) << 16);
            ((unsigned*)x1b)[((size_t)gA * NP + col) >> 1] = pA;
            ((unsigned*)x1b)[((size_t)gB * NP + col) >> 1] = pB;
        } else if (col < MEM) {
            float2 oA; oA.x = hA0; oA.y = hA1;
            float2 oB; oB.x = hB0; oB.y = hB1;
            *(float2*)(outx + (size_t)gA * MEM + col) = oA;
            *(float2*)(outx + (size_t)gB * MEM + col) = oB;
        }
    }
}

extern "C" void kernel_launch(void* const* d_in, const int* in_sizes, int n_in,
                              void* d_out, int out_size, void* d_ws, size_t ws_size,
                              hipStream_t stream) {
    const int*   words = (const int*)d_in[0];
    const int*   pos   = (const int*)d_in[1];
    const int*   ner   = (const int*)d_in[2];
    const float* adj   = (const float*)d_in[3];
    const float* embW  = (const float*)d_in[4];
    const float* posW  = (const float*)d_in[5];
    const float* nerW  = (const float*)d_in[6];
    const float* W0    = (const float*)d_in[7];
    const float* b0    = (const float*)d_in[8];
    const float* W1    = (const float*)d_in[9];
    const float* b1    = (const float*)d_in[10];
    float* out = (float*)d_out;

    char* ws = (char*)d_ws;
    size_t off = 0;
    short* x0b = (short*)(ws + off);        off += (size_t)NROWS * KP1 * 2;       // 25.2 MB
    short* W0p = (short*)(ws + off);        off += (size_t)NP * KP1 * 2;          // 196 KB
    short* W1p = (short*)(ws + off);        off += (size_t)NP * NP * 2;           // 131 KB
    float* Y   = (float*)(ws + off);        off += (size_t)NROWS * NP * 4;        // 33.5 MB
    short* X1b = (short*)(ws + off);        off += (size_t)NROWS * NP * 2;        // 16.8 MB
    float* dinv = (float*)(ws + off);       off += (size_t)NROWS * 4;
    float* rsum = (float*)(ws + off);       off += (size_t)NROWS * 4;
    unsigned* colnz = (unsigned*)(ws + off); size_t colnz_off = off; off += (size_t)NROWS * 4;
    int* cntp = (int*)(ws + off);           off += (size_t)NROWS * 4;
    unsigned short* nbr = (unsigned short*)(ws + off); off += (size_t)NROWS * NL * 2; // 16.8 MB

    hipMemsetAsync(ws + colnz_off, 0, (size_t)NROWS * 4, stream);

    prep_weights<<<(NP * KP1 + NP * NP + 255) / 256, 256, 0, stream>>>(W0, W1, W0p, W1p);
    embed_kernel<<<NROWS / 8, 384, 0, stream>>>(words, pos, ner, embW, posW, nerW, x0b);
    adjrow_kernel<<<NROWS / 4, 256, 0, stream>>>(adj, dinv, rsum, nbr, cntp, colnz);
    mask_kernel<<<NROWS / 256, 256, 0, stream>>>(rsum, colnz, out + OUT_X);

    const int ldsB = 257 * 128 * 4;   // 131584 B
    // layer 1: y0 = x0 @ W0^T ; x1 = relu((adj@y0 + y0 + 2 b0)/denom)
    gemm_kernel<<<(NROWS / 128) * 4, 256, 0, stream>>>(x0b, KP1, KP1 / 32, W0p, KP1, Y);
    spmm_kernel<0><<<NB * 2, 1024, ldsB, stream>>>(Y, nbr, cntp, dinv, b0, X1b, nullptr);
    // layer 2: y1 = x1 @ W1^T ; out = relu((adj@y1 + y1 + 2 b1)/denom)
    gemm_kernel<<<(NROWS / 128) * 4, 256, 0, stream>>>(X1b, NP, NP / 32, W1p, NP, Y);
    spmm_kernel<1><<<NB * 2, 1024, ldsB, stream>>>(Y, nbr, cntp, dinv, b1, nullptr, out);
}

// Round 6
// 150.612 us; speedup vs baseline: 1.2900x; 1.0159x over previous
//
#include <hip/hip_runtime.h>
#include <hip/hip_bf16.h>
#include <stdint.h>

typedef __attribute__((ext_vector_type(8))) short short8;
typedef __attribute__((ext_vector_type(4))) float f32x4;

#define NB 128
#define NL 256
#define NROWS 32768        // B*L
#define IN_DIM 360
#define KP1 384            // padded K for layer-1 GEMM (permuted layout, see embed_kernel)
#define MEM 200
#define NP 256             // padded N
#define OUT_X (NROWS * MEM)

// Permuted K layout for x0/W0p (keeps every 8-col chunk single-table):
//   kp 0..299   : emb k = kp
//   kp 304..333 : pos k = kp-304
//   kp 336..365 : ner k = kp-336
//   else        : zero pad
// GEMM1 is invariant since both A and B use the same permutation.

__device__ __forceinline__ unsigned short f2b(float f) {
    unsigned u = __builtin_bit_cast(unsigned, f);
    unsigned r = (u + 0x7FFFu + ((u >> 16) & 1u)) >> 16;
    return (unsigned short)r;
}

// ---------------- weight prep: W0p[256][384] (permuted K), W1p[256][256] (bf16, [n][k])
// Also zeroes colnz (instead of a hipMemsetAsync: the rocclr fill kernel cost ~39 us
// per graph replay at 8% occupancy — 26% of total runtime, round-5 profile).
__global__ void prep_weights(const float* __restrict__ W0, const float* __restrict__ W1,
                             short* __restrict__ W0p, short* __restrict__ W1p,
                             unsigned* __restrict__ colnz) {
    int idx = blockIdx.x * 256 + threadIdx.x;
    if (idx < NROWS) colnz[idx] = 0u;   // runs before adjrow in stream order
    if (idx < NP * KP1) {
        int n = idx / KP1, kp = idx - n * KP1;
        float v = 0.f;
        if (n < MEM) {
            if (kp < 300)                   v = W0[n * IN_DIM + kp];
            else if (kp >= 304 && kp < 334) v = W0[n * IN_DIM + 300 + (kp - 304)];
            else if (kp >= 336 && kp < 366) v = W0[n * IN_DIM + 330 + (kp - 336)];
        }
        W0p[idx] = (short)f2b(v);
    } else {
        int i2 = idx - NP * KP1;
        if (i2 < NP * NP) {
            int n = i2 >> 8, k = i2 & 255;
            float v = (n < MEM && k < MEM) ? W1[n * MEM + k] : 0.f;
            W1p[i2] = (short)f2b(v);
        }
    }
}

// ---------------- embedding concat -> x0 bf16 [32768][384] (permuted K layout)
// block = 384 threads = 8 rows x 48 chunks; each thread writes one short8 (8 cols).
__global__ __launch_bounds__(384) void embed_kernel(
    const int* __restrict__ words, const int* __restrict__ pos, const int* __restrict__ ner,
    const float* __restrict__ embW, const float* __restrict__ posW,
    const float* __restrict__ nerW, short* __restrict__ x0b) {
    int t = threadIdx.x;
    int r = t / 48, c = t - r * 48;
    int row = blockIdx.x * 8 + r;
    float vals[8];
    #pragma unroll
    for (int i = 0; i < 8; ++i) vals[i] = 0.f;
    if (c < 37) {                       // pure emb: cols 8c..8c+7 < 300
        const float* src = embW + (size_t)words[row] * 300 + c * 8;
        float4 a = *(const float4*)src;
        float4 b = *(const float4*)(src + 4);
        vals[0] = a.x; vals[1] = a.y; vals[2] = a.z; vals[3] = a.w;
        vals[4] = b.x; vals[5] = b.y; vals[6] = b.z; vals[7] = b.w;
    } else if (c == 37) {               // emb tail: cols 296..299 + pad
        const float* src = embW + (size_t)words[row] * 300 + 296;
        vals[0] = src[0]; vals[1] = src[1]; vals[2] = src[2]; vals[3] = src[3];
    } else if (c <= 41) {               // pos: kp 304..333
        int k0 = c * 8 - 304;           // 0,8,16,24
        const float* src = posW + (size_t)pos[row] * 30 + k0;
        #pragma unroll
        for (int i = 0; i < 8; ++i) if (k0 + i < 30) vals[i] = src[i];
    } else if (c <= 45) {               // ner: kp 336..365
        int k0 = c * 8 - 336;           // 0,8,16,24
        const float* src = nerW + (size_t)ner[row] * 30 + k0;
        #pragma unroll
        for (int i = 0; i < 8; ++i) if (k0 + i < 30) vals[i] = src[i];
    }                                   // c 46,47: zero pad
    short8 st;
    #pragma unroll
    for (int i = 0; i < 8; ++i) st[i] = (short)f2b(vals[i]);
    *(short8*)((unsigned short*)x0b + (size_t)row * KP1 + c * 8) = st;
}

// ---------------- adj row pass: rowsum, denom_inv, padded u16 CSR lists, col-nonzero flags
// CSR entry = within-batch column index (LDS source row); list padded to x8 with 256
// (a zeroed LDS row in spmm). Order = (w, lane asc) == previous ctz order (bit-identical sums).
__global__ void adjrow_kernel(const float* __restrict__ adj, float* __restrict__ dinv,
                              float* __restrict__ rsum, unsigned short* __restrict__ nbr,
                              int* __restrict__ cntp, unsigned* __restrict__ colnz) {
    int row = blockIdx.x * 4 + (threadIdx.x >> 6);
    int lane = threadIdx.x & 63;
    const float4* ar = (const float4*)(adj + (size_t)row * NL);
    float4 v = ar[lane];
    float s = v.x + v.y + v.z + v.w;
    #pragma unroll
    for (int off = 32; off >= 1; off >>= 1) s += __shfl_xor(s, off);
    unsigned long long m0 = __ballot(v.x != 0.f);
    unsigned long long m1 = __ballot(v.y != 0.f);
    unsigned long long m2 = __ballot(v.z != 0.f);
    unsigned long long m3 = __ballot(v.w != 0.f);
    unsigned long long lt = ((unsigned long long)1 << lane) - 1;
    int c0 = __popcll(m0), c1 = c0 + __popcll(m1), c2 = c1 + __popcll(m2);
    int total = c2 + __popcll(m3);
    int p0 = __popcll(m0 & lt);
    int p1 = c0 + __popcll(m1 & lt);
    int p2 = c1 + __popcll(m2 & lt);
    int p3 = c2 + __popcll(m3 & lt);
    unsigned short* nb = nbr + (size_t)row * NL;
    if (v.x != 0.f) nb[p0] = (unsigned short)(lane * 4 + 0);
    if (v.y != 0.f) nb[p1] = (unsigned short)(lane * 4 + 1);
    if (v.z != 0.f) nb[p2] = (unsigned short)(lane * 4 + 2);
    if (v.w != 0.f) nb[p3] = (unsigned short)(lane * 4 + 3);
    int padTo = (total + 7) & ~7;
    if (lane < padTo - total) nb[total + lane] = 256;   // sentinel -> zero LDS row
    if (lane == 0) {
        rsum[row] = s; dinv[row] = 1.0f / (s + 1.0f);
        cntp[row] = padTo;
    }
    unsigned* cz = colnz + ((row >> 8) << 8);   // batch base
    if (v.x != 0.f) atomicOr(&cz[lane * 4 + 0], 1u);
    if (v.y != 0.f) atomicOr(&cz[lane * 4 + 1], 1u);
    if (v.z != 0.f) atomicOr(&cz[lane * 4 + 2], 1u);
    if (v.w != 0.f) atomicOr(&cz[lane * 4 + 3], 1u);
}

__global__ void mask_kernel(const float* __restrict__ rsum, const unsigned* __restrict__ colnz,
                            float* __restrict__ outm) {
    int r = blockIdx.x * 256 + threadIdx.x;
    outm[r] = (rsum[r] == 0.f && colnz[r] == 0u) ? 1.0f : 0.0f;
}

// ---------------- bf16 MFMA GEMM: out[M][256] f32 = A[M][lda] * Bp[n][k]^T
// tile 128x64, BK=32, 4 waves (2x2), each wave 64x32 = 4x2 frags of 16x16x32
__global__ __launch_bounds__(256) void gemm_kernel(const short* __restrict__ A, int lda, int nkt,
                                                   const short* __restrict__ Bp, int ldb,
                                                   float* __restrict__ out) {
    __shared__ short At[128][32];
    __shared__ short Bt[64][32];
    int mt = blockIdx.x >> 2, nt = blockIdx.x & 3;
    int tid = threadIdx.x;
    int lane = tid & 63, wid = tid >> 6;
    int wr = wid >> 1, wc = wid & 1;
    int lr = lane & 15, lc = lane >> 4;
    f32x4 acc[4][2] = {};
    const short* Ab = A + (size_t)mt * 128 * lda;
    const short* Bb = Bp + (size_t)nt * 64 * ldb;
    for (int kt = 0; kt < nkt; ++kt) {
        int k0 = kt * 32;
        __syncthreads();
        #pragma unroll
        for (int it = 0; it < 2; ++it) {
            int idx = tid + it * 256;
            int row = idx >> 2, c = idx & 3;
            short8 v = *(const short8*)(Ab + (size_t)row * lda + k0 + c * 8);
            int cs = c ^ ((row >> 1) & 3);
            *(short8*)&At[row][cs * 8] = v;
        }
        {
            int n = tid >> 2, c = tid & 3;
            short8 v = *(const short8*)(Bb + (size_t)n * ldb + k0 + c * 8);
            int cs = c ^ ((n >> 1) & 3);
            *(short8*)&Bt[n][cs * 8] = v;
        }
        __syncthreads();
        short8 af[4], bf[2];
        #pragma unroll
        for (int mi = 0; mi < 4; ++mi) {
            int row = wr * 64 + mi * 16 + lr;
            int cs = lc ^ ((row >> 1) & 3);
            af[mi] = *(const short8*)&At[row][cs * 8];
        }
        #pragma unroll
        for (int ni = 0; ni < 2; ++ni) {
            int row = wc * 32 + ni * 16 + lr;
            int cs = lc ^ ((row >> 1) & 3);
            bf[ni] = *(const short8*)&Bt[row][cs * 8];
        }
        #pragma unroll
        for (int mi = 0; mi < 4; ++mi)
            #pragma unroll
            for (int ni = 0; ni < 2; ++ni)
                acc[mi][ni] = __builtin_amdgcn_mfma_f32_16x16x32_bf16(af[mi], bf[ni], acc[mi][ni], 0, 0, 0);
    }
    int orow0 = mt * 128 + wr * 64;
    int ocol0 = nt * 64 + wc * 32;
    #pragma unroll
    for (int mi = 0; mi < 4; ++mi)
        #pragma unroll
        for (int ni = 0; ni < 2; ++ni)
            #pragma unroll
            for (int r = 0; r < 4; ++r)
                out[(size_t)(orow0 + mi * 16 + lc * 4 + r) * NP + ocol0 + ni * 16 + lr] = acc[mi][ni][r];
}

// ---------------- LDS-staged sparse gather + epilogue, CSR-unrolled, float2/lane.
// block = (batch, 128-col half). Stage Y[batch][:, h*128..+128) in LDS (257 rows, row 256 = zeros),
// 16 waves x 16 rows, dual-row (r, r+8) interleave for ILP; inner chunk = 8 independent ds_read_b64.
// FINAL=0: write x1 bf16 [32768][256]; FINAL=1: f32 out [32768][200]
template <int FINAL>
__global__ __launch_bounds__(1024) void spmm_kernel(
    const float* __restrict__ Y, const unsigned short* __restrict__ nbr,
    const int* __restrict__ cntp, const float* __restrict__ dinv,
    const float* __restrict__ bias, short* __restrict__ x1b, float* __restrict__ outx) {
    extern __shared__ float Ysm[];                 // [257][128]
    int batch = blockIdx.x >> 1, h = blockIdx.x & 1;
    int tid = threadIdx.x;
    const float* Yb = Y + (size_t)batch * NL * NP + h * 128;
    #pragma unroll
    for (int k = 0; k < 8; ++k) {
        int f = tid + k * 1024;                    // float4 index, 8192 total
        int row = f >> 5, c4 = (f & 31) << 2;
        *(float4*)&Ysm[row * 128 + c4] = *(const float4*)(Yb + (size_t)row * NP + c4);
    }
    if (tid < 32) {                                // zero sentinel row 256
        float4 z; z.x = 0.f; z.y = 0.f; z.z = 0.f; z.w = 0.f;
        *(float4*)&Ysm[256 * 128 + tid * 4] = z;
    }
    __syncthreads();
    int wid = tid >> 6, lane = tid & 63;
    int cc = lane * 2;                             // col within half
    int col = h * 128 + cc;                        // global col (even)
    float bv0 = 0.f, bv1 = 0.f;
    if (col < MEM) { bv0 = bias[col]; bv1 = bias[col + 1]; }   // MEM even -> pair valid together
    int r0 = wid * 16;
    for (int rr = 0; rr < 8; ++rr) {
        int rA = r0 + rr, rB = r0 + 8 + rr;
        int gA = batch * NL + rA, gB = batch * NL + rB;
        const unsigned short* nA = nbr + (size_t)gA * NL;
        const unsigned short* nB = nbr + (size_t)gB * NL;
        int npA = cntp[gA], npB = cntp[gB];
        float axA = 0.f, ayA = 0.f, axB = 0.f, ayB = 0.f;
        int nmax = npA > npB ? npA : npB;
        for (int t = 0; t < nmax; t += 8) {
            if (t < npA) {                         // wave-uniform branch
                short8 I = *(const short8*)(nA + t);
                #pragma unroll
                for (int i = 0; i < 8; ++i) {
                    int j = (int)(unsigned short)I[i];
                    float2 v = *(const float2*)&Ysm[j * 128 + cc];
                    axA += v.x; ayA += v.y;
                }
            }
            if (t < npB) {
                short8 I = *(const short8*)(nB + t);
                #pragma unroll
                for (int i = 0; i < 8; ++i) {
                    int j = (int)(unsigned short)I[i];
                    float2 v = *(const float2*)&Ysm[j * 128 + cc];
                    axB += v.x; ayB += v.y;
                }
            }
        }
        float2 sA = *(const float2*)&Ysm[rA * 128 + cc];
        float2 sB = *(const float2*)&Ysm[rB * 128 + cc];
        float dA = dinv[gA], dB = dinv[gB];
        float hA0 = fmaxf((axA + sA.x + 2.f * bv0) * dA, 0.f);
        float hA1 = fmaxf((ayA + sA.y + 2.f * bv1) * dA, 0.f);
        float hB0 = fmaxf((axB + sB.x + 2.f * bv0) * dB, 0.f);
        float hB1 = fmaxf((ayB + sB.y + 2.f * bv1) * dB, 0.f);
        if (FINAL == 0) {
            unsigned pA = (unsigned)f2b(hA0) | ((unsigned)f2b(hA1) << 16);
            unsigned pB = (unsigned)f2b(hB0) | ((unsigned)f2b(hB1) << 16);
            ((unsigned*)x1b)[((size_t)gA * NP + col) >> 1] = pA;
            ((unsigned*)x1b)[((size_t)gB * NP + col) >> 1] = pB;
        } else if (col < MEM) {
            float2 oA; oA.x = hA0; oA.y = hA1;
            float2 oB; oB.x = hB0; oB.y = hB1;
            *(float2*)(outx + (size_t)gA * MEM + col) = oA;
            *(float2*)(outx + (size_t)gB * MEM + col) = oB;
        }
    }
}

extern "C" void kernel_launch(void* const* d_in, const int* in_sizes, int n_in,
                              void* d_out, int out_size, void* d_ws, size_t ws_size,
                              hipStream_t stream) {
    const int*   words = (const int*)d_in[0];
    const int*   pos   = (const int*)d_in[1];
    const int*   ner   = (const int*)d_in[2];
    const float* adj   = (const float*)d_in[3];
    const float* embW  = (const float*)d_in[4];
    const float* posW  = (const float*)d_in[5];
    const float* nerW  = (const float*)d_in[6];
    const float* W0    = (const float*)d_in[7];
    const float* b0    = (const float*)d_in[8];
    const float* W1    = (const float*)d_in[9];
    const float* b1    = (const float*)d_in[10];
    float* out = (float*)d_out;

    char* ws = (char*)d_ws;
    size_t off = 0;
    short* x0b = (short*)(ws + off);        off += (size_t)NROWS * KP1 * 2;       // 25.2 MB
    short* W0p = (short*)(ws + off);        off += (size_t)NP * KP1 * 2;          // 196 KB
    short* W1p = (short*)(ws + off);        off += (size_t)NP * NP * 2;           // 131 KB
    float* Y   = (float*)(ws + off);        off += (size_t)NROWS * NP * 4;        // 33.5 MB
    short* X1b = (short*)(ws + off);        off += (size_t)NROWS * NP * 2;        // 16.8 MB
    float* dinv = (float*)(ws + off);       off += (size_t)NROWS * 4;
    float* rsum = (float*)(ws + off);       off += (size_t)NROWS * 4;
    unsigned* colnz = (unsigned*)(ws + off); off += (size_t)NROWS * 4;
    int* cntp = (int*)(ws + off);           off += (size_t)NROWS * 4;
    unsigned short* nbr = (unsigned short*)(ws + off); off += (size_t)NROWS * NL * 2; // 16.8 MB

    prep_weights<<<(NP * KP1 + NP * NP + 255) / 256, 256, 0, stream>>>(W0, W1, W0p, W1p, colnz);
    embed_kernel<<<NROWS / 8, 384, 0, stream>>>(words, pos, ner, embW, posW, nerW, x0b);
    adjrow_kernel<<<NROWS / 4, 256, 0, stream>>>(adj, dinv, rsum, nbr, cntp, colnz);
    mask_kernel<<<NROWS / 256, 256, 0, stream>>>(rsum, colnz, out + OUT_X);

    const int ldsB = 257 * 128 * 4;   // 131584 B
    // layer 1: y0 = x0 @ W0^T ; x1 = relu((adj@y0 + y0 + 2 b0)/denom)
    gemm_kernel<<<(NROWS / 128) * 4, 256, 0, stream>>>(x0b, KP1, KP1 / 32, W0p, KP1, Y);
    spmm_kernel<0><<<NB * 2, 1024, ldsB, stream>>>(Y, nbr, cntp, dinv, b0, X1b, nullptr);
    // layer 2: y1 = x1 @ W1^T ; out = relu((adj@y1 + y1 + 2 b1)/denom)
    gemm_kernel<<<(NROWS / 128) * 4, 256, 0, stream>>>(X1b, NP, NP / 32, W1p, NP, Y);
    spmm_kernel<1><<<NB * 2, 1024, ldsB, stream>>>(Y, nbr, cntp, dinv, b1, nullptr, out);
}

// Round 7
// 146.224 us; speedup vs baseline: 1.3287x; 1.0300x over previous
//
#include <hip/hip_runtime.h>
#include <hip/hip_bf16.h>
#include <stdint.h>

typedef __attribute__((ext_vector_type(8))) short short8;
typedef __attribute__((ext_vector_type(4))) float f32x4;

#define NB 128
#define NL 256
#define NROWS 32768        // B*L
#define IN_DIM 360
#define KP1 384            // padded K for layer-1 GEMM (permuted layout, see embed_kernel)
#define MEM 200
#define NP 256             // padded N
#define OUT_X (NROWS * MEM)
#define YLD 130            // Ysm leading dim (floats): breaks phase-2 write conflicts

// Permuted K layout for x0/W0p (keeps every 8-col chunk single-table):
//   kp 0..299   : emb k = kp
//   kp 304..333 : pos k = kp-304
//   kp 336..365 : ner k = kp-336
//   else        : zero pad

__device__ __forceinline__ unsigned short f2b(float f) {
    unsigned u = __builtin_bit_cast(unsigned, f);
    unsigned r = (u + 0x7FFFu + ((u >> 16) & 1u)) >> 16;
    return (unsigned short)r;
}

// ---------------- weight prep: W0p[256][384] (permuted K), W1p[256][256] (bf16, [n][k])
// Also zeroes colnz (cheaper than a captured hipMemsetAsync fill kernel).
__global__ void prep_weights(const float* __restrict__ W0, const float* __restrict__ W1,
                             short* __restrict__ W0p, short* __restrict__ W1p,
                             unsigned* __restrict__ colnz) {
    int idx = blockIdx.x * 256 + threadIdx.x;
    if (idx < NROWS) colnz[idx] = 0u;   // runs before adjrow in stream order
    if (idx < NP * KP1) {
        int n = idx / KP1, kp = idx - n * KP1;
        float v = 0.f;
        if (n < MEM) {
            if (kp < 300)                   v = W0[n * IN_DIM + kp];
            else if (kp >= 304 && kp < 334) v = W0[n * IN_DIM + 300 + (kp - 304)];
            else if (kp >= 336 && kp < 366) v = W0[n * IN_DIM + 330 + (kp - 336)];
        }
        W0p[idx] = (short)f2b(v);
    } else {
        int i2 = idx - NP * KP1;
        if (i2 < NP * NP) {
            int n = i2 >> 8, k = i2 & 255;
            float v = (n < MEM && k < MEM) ? W1[n * MEM + k] : 0.f;
            W1p[i2] = (short)f2b(v);
        }
    }
}

// ---------------- embedding concat -> x0 bf16 [32768][384] (permuted K layout)
// block = 384 threads = 8 rows x 48 chunks; each thread writes one short8 (8 cols).
__global__ __launch_bounds__(384) void embed_kernel(
    const int* __restrict__ words, const int* __restrict__ pos, const int* __restrict__ ner,
    const float* __restrict__ embW, const float* __restrict__ posW,
    const float* __restrict__ nerW, short* __restrict__ x0b) {
    int t = threadIdx.x;
    int r = t / 48, c = t - r * 48;
    int row = blockIdx.x * 8 + r;
    float vals[8];
    #pragma unroll
    for (int i = 0; i < 8; ++i) vals[i] = 0.f;
    if (c < 37) {                       // pure emb: cols 8c..8c+7 < 300
        const float* src = embW + (size_t)words[row] * 300 + c * 8;
        float4 a = *(const float4*)src;
        float4 b = *(const float4*)(src + 4);
        vals[0] = a.x; vals[1] = a.y; vals[2] = a.z; vals[3] = a.w;
        vals[4] = b.x; vals[5] = b.y; vals[6] = b.z; vals[7] = b.w;
    } else if (c == 37) {               // emb tail: cols 296..299 + pad
        const float* src = embW + (size_t)words[row] * 300 + 296;
        vals[0] = src[0]; vals[1] = src[1]; vals[2] = src[2]; vals[3] = src[3];
    } else if (c <= 41) {               // pos: kp 304..333
        int k0 = c * 8 - 304;           // 0,8,16,24
        const float* src = posW + (size_t)pos[row] * 30 + k0;
        #pragma unroll
        for (int i = 0; i < 8; ++i) if (k0 + i < 30) vals[i] = src[i];
    } else if (c <= 45) {               // ner: kp 336..365
        int k0 = c * 8 - 336;           // 0,8,16,24
        const float* src = nerW + (size_t)ner[row] * 30 + k0;
        #pragma unroll
        for (int i = 0; i < 8; ++i) if (k0 + i < 30) vals[i] = src[i];
    }                                   // c 46,47: zero pad
    short8 st;
    #pragma unroll
    for (int i = 0; i < 8; ++i) st[i] = (short)f2b(vals[i]);
    *(short8*)((unsigned short*)x0b + (size_t)row * KP1 + c * 8) = st;
}

// ---------------- adj row pass: rowsum, denom_inv, padded u16 CSR lists, col-nonzero flags
// CSR entry = within-batch column index; list padded to x8 with 256 (zeroed Ysm sentinel row).
__global__ void adjrow_kernel(const float* __restrict__ adj, float* __restrict__ dinv,
                              float* __restrict__ rsum, unsigned short* __restrict__ nbr,
                              int* __restrict__ cntp, unsigned* __restrict__ colnz) {
    int row = blockIdx.x * 4 + (threadIdx.x >> 6);
    int lane = threadIdx.x & 63;
    const float4* ar = (const float4*)(adj + (size_t)row * NL);
    float4 v = ar[lane];
    float s = v.x + v.y + v.z + v.w;
    #pragma unroll
    for (int off = 32; off >= 1; off >>= 1) s += __shfl_xor(s, off);
    unsigned long long m0 = __ballot(v.x != 0.f);
    unsigned long long m1 = __ballot(v.y != 0.f);
    unsigned long long m2 = __ballot(v.z != 0.f);
    unsigned long long m3 = __ballot(v.w != 0.f);
    unsigned long long lt = ((unsigned long long)1 << lane) - 1;
    int c0 = __popcll(m0), c1 = c0 + __popcll(m1), c2 = c1 + __popcll(m2);
    int total = c2 + __popcll(m3);
    int p0 = __popcll(m0 & lt);
    int p1 = c0 + __popcll(m1 & lt);
    int p2 = c1 + __popcll(m2 & lt);
    int p3 = c2 + __popcll(m3 & lt);
    unsigned short* nb = nbr + (size_t)row * NL;
    if (v.x != 0.f) nb[p0] = (unsigned short)(lane * 4 + 0);
    if (v.y != 0.f) nb[p1] = (unsigned short)(lane * 4 + 1);
    if (v.z != 0.f) nb[p2] = (unsigned short)(lane * 4 + 2);
    if (v.w != 0.f) nb[p3] = (unsigned short)(lane * 4 + 3);
    int padTo = (total + 7) & ~7;
    if (lane < padTo - total) nb[total + lane] = 256;   // sentinel -> zero Ysm row
    if (lane == 0) {
        rsum[row] = s; dinv[row] = 1.0f / (s + 1.0f);
        cntp[row] = padTo;
    }
    unsigned* cz = colnz + ((row >> 8) << 8);   // batch base
    if (v.x != 0.f) atomicOr(&cz[lane * 4 + 0], 1u);
    if (v.y != 0.f) atomicOr(&cz[lane * 4 + 1], 1u);
    if (v.z != 0.f) atomicOr(&cz[lane * 4 + 2], 1u);
    if (v.w != 0.f) atomicOr(&cz[lane * 4 + 3], 1u);
}

__global__ void mask_kernel(const float* __restrict__ rsum, const unsigned* __restrict__ colnz,
                            float* __restrict__ outm) {
    int r = blockIdx.x * 256 + threadIdx.x;
    outm[r] = (rsum[r] == 0.f && colnz[r] == 0u) ? 1.0f : 0.0f;
}

// ---------------- FUSED per-layer kernel: GEMM (M=256 batch rows, N=128 cols, bf16 MFMA)
// + in-LDS sparse adjacency gather + epilogue. Y never touches HBM.
// Phase 1: K-loop, At[256][32]+Bt[128][32] staging (XOR-swizzled), 8 waves 4x2, acc[4][4].
// Phase 2: acc -> Ysm[257][130] f32 (aliases At/Bt; row 256 = zeros), CSR gather, epilogue.
// FINAL=0: write x1 bf16 [32768][256]; FINAL=1: f32 out [32768][200]
template <int FINAL>
__global__ __launch_bounds__(512) void fused_kernel(
    const short* __restrict__ A, int lda, int nkt,
    const short* __restrict__ Bp, int ldb,
    const unsigned short* __restrict__ nbr, const int* __restrict__ cntp,
    const float* __restrict__ dinv, const float* __restrict__ bias,
    short* __restrict__ x1b, float* __restrict__ outx) {
    extern __shared__ char smem[];
    short (*At)[32] = (short (*)[32])smem;              // [256][32] bf16, 16 KB
    short (*Bt)[32] = (short (*)[32])(smem + 16384);    // [128][32] bf16,  8 KB
    float* Ysm = (float*)smem;                          // [257][130] f32, 130.5 KB (aliases)

    int batch = blockIdx.x >> 1, nh = blockIdx.x & 1;
    int tid = threadIdx.x;
    int lane = tid & 63, wid = tid >> 6;
    int wr = wid >> 1, wc = wid & 1;                    // 4 x 2 wave grid
    int lr = lane & 15, lc = lane >> 4;
    f32x4 acc[4][4] = {};
    const short* Ab = A + (size_t)batch * NL * lda;
    const short* Bb = Bp + (size_t)nh * 128 * ldb;
    for (int kt = 0; kt < nkt; ++kt) {
        int k0 = kt * 32;
        __syncthreads();
        #pragma unroll
        for (int it = 0; it < 2; ++it) {                // At: 1024 short8 over 512 thr
            int idx = tid + it * 512;
            int row = idx >> 2, c = idx & 3;
            short8 v = *(const short8*)(Ab + (size_t)row * lda + k0 + c * 8);
            int cs = c ^ ((row >> 1) & 3);
            *(short8*)&At[row][cs * 8] = v;
        }
        {                                               // Bt: 512 short8
            int n = tid >> 2, c = tid & 3;
            short8 v = *(const short8*)(Bb + (size_t)n * ldb + k0 + c * 8);
            int cs = c ^ ((n >> 1) & 3);
            *(short8*)&Bt[n][cs * 8] = v;
        }
        __syncthreads();
        short8 af[4], bf[4];
        #pragma unroll
        for (int mi = 0; mi < 4; ++mi) {
            int row = wr * 64 + mi * 16 + lr;
            int cs = lc ^ ((row >> 1) & 3);
            af[mi] = *(const short8*)&At[row][cs * 8];
        }
        #pragma unroll
        for (int ni = 0; ni < 4; ++ni) {
            int row = wc * 64 + ni * 16 + lr;
            int cs = lc ^ ((row >> 1) & 3);
            bf[ni] = *(const short8*)&Bt[row][cs * 8];
        }
        #pragma unroll
        for (int mi = 0; mi < 4; ++mi)
            #pragma unroll
            for (int ni = 0; ni < 4; ++ni)
                acc[mi][ni] = __builtin_amdgcn_mfma_f32_16x16x32_bf16(af[mi], bf[ni], acc[mi][ni], 0, 0, 0);
    }
    __syncthreads();                                    // all ds_reads done; safe to alias
    // Phase 2a: acc -> Ysm. bank = (2*row + col) % 32 -> <=2-way (free).
    {
        int orow0 = wr * 64, ocol0 = wc * 64;
        #pragma unroll
        for (int mi = 0; mi < 4; ++mi)
            #pragma unroll
            for (int ni = 0; ni < 4; ++ni)
                #pragma unroll
                for (int r = 0; r < 4; ++r)
                    Ysm[(orow0 + mi * 16 + lc * 4 + r) * YLD + ocol0 + ni * 16 + lr] = acc[mi][ni][r];
    }
    if (tid < 65) {                                     // sentinel row 256 = zeros
        Ysm[256 * YLD + tid] = 0.f;
        Ysm[256 * YLD + 65 + tid] = 0.f;
    }
    __syncthreads();
    // Phase 2b: CSR gather + epilogue. lane covers 2 cols; wave covers 32 rows (dual-row ILP).
    int cc = lane * 2;                                  // col within half (even)
    int col = nh * 128 + cc;                            // global col
    float bv0 = 0.f, bv1 = 0.f;
    if (col < MEM) { bv0 = bias[col]; bv1 = bias[col + 1]; }   // MEM even
    int r0 = wid * 32;
    for (int rr = 0; rr < 16; ++rr) {
        int rA = r0 + rr, rB = r0 + 16 + rr;
        int gA = batch * NL + rA, gB = batch * NL + rB;
        const unsigned short* nA = nbr + (size_t)gA * NL;
        const unsigned short* nB = nbr + (size_t)gB * NL;
        int npA = cntp[gA], npB = cntp[gB];
        float axA = 0.f, ayA = 0.f, axB = 0.f, ayB = 0.f;
        int nmax = npA > npB ? npA : npB;
        for (int t = 0; t < nmax; t += 8) {
            if (t < npA) {                              // wave-uniform branch
                short8 I = *(const short8*)(nA + t);
                #pragma unroll
                for (int i = 0; i < 8; ++i) {
                    int j = (int)(unsigned short)I[i];
                    float2 v = *(const float2*)&Ysm[j * YLD + cc];
                    axA += v.x; ayA += v.y;
                }
            }
            if (t < npB) {
                short8 I = *(const short8*)(nB + t);
                #pragma unroll
                for (int i = 0; i < 8; ++i) {
                    int j = (int)(unsigned short)I[i];
                    float2 v = *(const float2*)&Ysm[j * YLD + cc];
                    axB += v.x; ayB += v.y;
                }
            }
        }
        float2 sA = *(const float2*)&Ysm[rA * YLD + cc];
        float2 sB = *(const float2*)&Ysm[rB * YLD + cc];
        float dA = dinv[gA], dB = dinv[gB];
        float hA0 = fmaxf((axA + sA.x + 2.f * bv0) * dA, 0.f);
        float hA1 = fmaxf((ayA + sA.y + 2.f * bv1) * dA, 0.f);
        float hB0 = fmaxf((axB + sB.x + 2.f * bv0) * dB, 0.f);
        float hB1 = fmaxf((ayB + sB.y + 2.f * bv1) * dB, 0.f);
        if (FINAL == 0) {
            unsigned pA = (unsigned)f2b(hA0) | ((unsigned)f2b(hA1) << 16);
            unsigned pB = (unsigned)f2b(hB0) | ((unsigned)f2b(hB1) << 16);
            ((unsigned*)x1b)[((size_t)gA * NP + col) >> 1] = pA;
            ((unsigned*)x1b)[((size_t)gB * NP + col) >> 1] = pB;
        } else if (col < MEM) {
            float2 oA; oA.x = hA0; oA.y = hA1;
            float2 oB; oB.x = hB0; oB.y = hB1;
            *(float2*)(outx + (size_t)gA * MEM + col) = oA;
            *(float2*)(outx + (size_t)gB * MEM + col) = oB;
        }
    }
}

extern "C" void kernel_launch(void* const* d_in, const int* in_sizes, int n_in,
                              void* d_out, int out_size, void* d_ws, size_t ws_size,
                              hipStream_t stream) {
    const int*   words = (const int*)d_in[0];
    const int*   pos   = (const int*)d_in[1];
    const int*   ner   = (const int*)d_in[2];
    const float* adj   = (const float*)d_in[3];
    const float* embW  = (const float*)d_in[4];
    const float* posW  = (const float*)d_in[5];
    const float* nerW  = (const float*)d_in[6];
    const float* W0    = (const float*)d_in[7];
    const float* b0    = (const float*)d_in[8];
    const float* W1    = (const float*)d_in[9];
    const float* b1    = (const float*)d_in[10];
    float* out = (float*)d_out;

    char* ws = (char*)d_ws;
    size_t off = 0;
    short* x0b = (short*)(ws + off);        off += (size_t)NROWS * KP1 * 2;       // 25.2 MB
    short* W0p = (short*)(ws + off);        off += (size_t)NP * KP1 * 2;          // 196 KB
    short* W1p = (short*)(ws + off);        off += (size_t)NP * NP * 2;           // 131 KB
    short* X1b = (short*)(ws + off);        off += (size_t)NROWS * NP * 2;        // 16.8 MB
    float* dinv = (float*)(ws + off);       off += (size_t)NROWS * 4;
    float* rsum = (float*)(ws + off);       off += (size_t)NROWS * 4;
    unsigned* colnz = (unsigned*)(ws + off); off += (size_t)NROWS * 4;
    int* cntp = (int*)(ws + off);           off += (size_t)NROWS * 4;
    unsigned short* nbr = (unsigned short*)(ws + off); off += (size_t)NROWS * NL * 2; // 16.8 MB

    prep_weights<<<(NP * KP1 + NP * NP + 255) / 256, 256, 0, stream>>>(W0, W1, W0p, W1p, colnz);
    embed_kernel<<<NROWS / 8, 384, 0, stream>>>(words, pos, ner, embW, posW, nerW, x0b);
    adjrow_kernel<<<NROWS / 4, 256, 0, stream>>>(adj, dinv, rsum, nbr, cntp, colnz);
    mask_kernel<<<NROWS / 256, 256, 0, stream>>>(rsum, colnz, out + OUT_X);

    const int ldsB = 257 * YLD * 4;   // 133,640 B (At/Bt alias inside)
    // layer 1: x1 = relu((adj@y0 + y0 + 2 b0)/denom), y0 = x0 @ W0^T  (fused, Y stays in LDS)
    fused_kernel<0><<<NB * 2, 512, ldsB, stream>>>(x0b, KP1, KP1 / 32, W0p, KP1,
                                                   nbr, cntp, dinv, b0, X1b, nullptr);
    // layer 2: out = relu((adj@y1 + y1 + 2 b1)/denom), y1 = x1 @ W1^T
    fused_kernel<1><<<NB * 2, 512, ldsB, stream>>>(X1b, NP, NP / 32, W1p, NP,
                                                   nbr, cntp, dinv, b1, nullptr, out);
}

// Round 8
// 122.959 us; speedup vs baseline: 1.5801x; 1.1892x over previous
//
#include <hip/hip_runtime.h>
#include <hip/hip_bf16.h>
#include <stdint.h>

typedef __attribute__((ext_vector_type(8))) short short8;
typedef __attribute__((ext_vector_type(4))) float f32x4;

#define NB 128
#define NL 256
#define NROWS 32768        // B*L
#define IN_DIM 360
#define KP1 384            // padded K for layer-1 GEMM (permuted layout, see embed_kernel)
#define MEM 200
#define NP 256             // padded N
#define OUT_X (NROWS * MEM)
#define YW 65              // Ysm row pitch in u32 words (130 bf16)

// Permuted K layout for x0/W0p (keeps every 8-col chunk single-table):
//   kp 0..299 emb | kp 304..333 pos | kp 336..365 ner | else zero

__device__ __forceinline__ unsigned short f2b(float f) {
    unsigned u = __builtin_bit_cast(unsigned, f);
    unsigned r = (u + 0x7FFFu + ((u >> 16) & 1u)) >> 16;
    return (unsigned short)r;
}

// ---------------- weight prep + colnz zero
__global__ void prep_weights(const float* __restrict__ W0, const float* __restrict__ W1,
                             short* __restrict__ W0p, short* __restrict__ W1p,
                             unsigned* __restrict__ colnz) {
    int idx = blockIdx.x * 256 + threadIdx.x;
    if (idx < NROWS) colnz[idx] = 0u;
    if (idx < NP * KP1) {
        int n = idx / KP1, kp = idx - n * KP1;
        float v = 0.f;
        if (n < MEM) {
            if (kp < 300)                   v = W0[n * IN_DIM + kp];
            else if (kp >= 304 && kp < 334) v = W0[n * IN_DIM + 300 + (kp - 304)];
            else if (kp >= 336 && kp < 366) v = W0[n * IN_DIM + 330 + (kp - 336)];
        }
        W0p[idx] = (short)f2b(v);
    } else {
        int i2 = idx - NP * KP1;
        if (i2 < NP * NP) {
            int n = i2 >> 8, k = i2 & 255;
            float v = (n < MEM && k < MEM) ? W1[n * MEM + k] : 0.f;
            W1p[i2] = (short)f2b(v);
        }
    }
}

// ---------------- embedding concat -> x0 bf16 [32768][384] (permuted K layout)
__global__ __launch_bounds__(384) void embed_kernel(
    const int* __restrict__ words, const int* __restrict__ pos, const int* __restrict__ ner,
    const float* __restrict__ embW, const float* __restrict__ posW,
    const float* __restrict__ nerW, short* __restrict__ x0b) {
    int t = threadIdx.x;
    int r = t / 48, c = t - r * 48;
    int row = blockIdx.x * 8 + r;
    float vals[8];
    #pragma unroll
    for (int i = 0; i < 8; ++i) vals[i] = 0.f;
    if (c < 37) {
        const float* src = embW + (size_t)words[row] * 300 + c * 8;
        float4 a = *(const float4*)src;
        float4 b = *(const float4*)(src + 4);
        vals[0] = a.x; vals[1] = a.y; vals[2] = a.z; vals[3] = a.w;
        vals[4] = b.x; vals[5] = b.y; vals[6] = b.z; vals[7] = b.w;
    } else if (c == 37) {
        const float* src = embW + (size_t)words[row] * 300 + 296;
        vals[0] = src[0]; vals[1] = src[1]; vals[2] = src[2]; vals[3] = src[3];
    } else if (c <= 41) {
        int k0 = c * 8 - 304;
        const float* src = posW + (size_t)pos[row] * 30 + k0;
        #pragma unroll
        for (int i = 0; i < 8; ++i) if (k0 + i < 30) vals[i] = src[i];
    } else if (c <= 45) {
        int k0 = c * 8 - 336;
        const float* src = nerW + (size_t)ner[row] * 30 + k0;
        #pragma unroll
        for (int i = 0; i < 8; ++i) if (k0 + i < 30) vals[i] = src[i];
    }
    short8 st;
    #pragma unroll
    for (int i = 0; i < 8; ++i) st[i] = (short)f2b(vals[i]);
    *(short8*)((unsigned short*)x0b + (size_t)row * KP1 + c * 8) = st;
}

// ---------------- adj row pass: rowsum, denom_inv, padded u16 CSR, col-nonzero flags
__global__ void adjrow_kernel(const float* __restrict__ adj, float* __restrict__ dinv,
                              float* __restrict__ rsum, unsigned short* __restrict__ nbr,
                              int* __restrict__ cntp, unsigned* __restrict__ colnz) {
    int row = blockIdx.x * 4 + (threadIdx.x >> 6);
    int lane = threadIdx.x & 63;
    const float4* ar = (const float4*)(adj + (size_t)row * NL);
    float4 v = ar[lane];
    float s = v.x + v.y + v.z + v.w;
    #pragma unroll
    for (int off = 32; off >= 1; off >>= 1) s += __shfl_xor(s, off);
    unsigned long long m0 = __ballot(v.x != 0.f);
    unsigned long long m1 = __ballot(v.y != 0.f);
    unsigned long long m2 = __ballot(v.z != 0.f);
    unsigned long long m3 = __ballot(v.w != 0.f);
    unsigned long long lt = ((unsigned long long)1 << lane) - 1;
    int c0 = __popcll(m0), c1 = c0 + __popcll(m1), c2 = c1 + __popcll(m2);
    int total = c2 + __popcll(m3);
    int p0 = __popcll(m0 & lt);
    int p1 = c0 + __popcll(m1 & lt);
    int p2 = c1 + __popcll(m2 & lt);
    int p3 = c2 + __popcll(m3 & lt);
    unsigned short* nb = nbr + (size_t)row * NL;
    if (v.x != 0.f) nb[p0] = (unsigned short)(lane * 4 + 0);
    if (v.y != 0.f) nb[p1] = (unsigned short)(lane * 4 + 1);
    if (v.z != 0.f) nb[p2] = (unsigned short)(lane * 4 + 2);
    if (v.w != 0.f) nb[p3] = (unsigned short)(lane * 4 + 3);
    int padTo = (total + 7) & ~7;
    if (lane < padTo - total) nb[total + lane] = 256;   // sentinel -> zero Ysm row
    if (lane == 0) {
        rsum[row] = s; dinv[row] = 1.0f / (s + 1.0f);
        cntp[row] = padTo;
    }
    unsigned* cz = colnz + ((row >> 8) << 8);
    if (v.x != 0.f) atomicOr(&cz[lane * 4 + 0], 1u);
    if (v.y != 0.f) atomicOr(&cz[lane * 4 + 1], 1u);
    if (v.z != 0.f) atomicOr(&cz[lane * 4 + 2], 1u);
    if (v.w != 0.f) atomicOr(&cz[lane * 4 + 3], 1u);
}

__global__ void mask_kernel(const float* __restrict__ rsum, const unsigned* __restrict__ colnz,
                            float* __restrict__ outm) {
    int r = blockIdx.x * 256 + threadIdx.x;
    outm[r] = (rsum[r] == 0.f && colnz[r] == 0u) ? 1.0f : 0.0f;
}

// ---------------- FUSED per-layer: GEMM (M=256, N=128) + in-LDS gather + epilogue.
// 1024 thr / 16 waves (4x4), wave tile 64x32, reg-prefetch staging, bf16 Ysm (66.8 KB).
// Phase 1: K-loop; each thread owns 1 short8 of At (tid<512 also 1 of Bt).
// Phase 2a: acc -> bf16-pair pack via shfl_xor(1) -> Ysm[257][130]bf16 (row 256 zeros).
// Phase 2b: CSR gather, 16 rows/wave, 1 ds_read_b32 per neighbor (2 cols).
template <int FINAL>
__global__ __launch_bounds__(1024) void fused_kernel(
    const short* __restrict__ A, int lda, int nkt,
    const short* __restrict__ Bp, int ldb,
    const unsigned short* __restrict__ nbr, const int* __restrict__ cntp,
    const float* __restrict__ dinv, const float* __restrict__ bias,
    short* __restrict__ x1b, float* __restrict__ outx) {
    extern __shared__ char smem[];
    short (*At)[32] = (short (*)[32])smem;              // [256][32] bf16, 16 KB
    short (*Bt)[32] = (short (*)[32])(smem + 16384);    // [128][32] bf16,  8 KB
    unsigned* Ysm32 = (unsigned*)smem;                  // [257][65] u32 = bf16 pairs (aliases)

    int batch = blockIdx.x >> 1, nh = blockIdx.x & 1;
    int tid = threadIdx.x;
    int lane = tid & 63, wid = tid >> 6;
    int wr = wid >> 2, wc = wid & 3;                    // 4 x 4 wave grid
    int lr = lane & 15, lc = lane >> 4;
    f32x4 acc[4][2] = {};
    const short* Ab = A + (size_t)batch * NL * lda;
    const short* Bb = Bp + (size_t)nh * 128 * ldb;

    // per-thread staging slots
    int arow = tid >> 2, ac = tid & 3;
    int acs = ac ^ ((arow >> 1) & 3);
    const short* Ap = Ab + (size_t)arow * lda + ac * 8;
    short* Asl = &At[arow][acs * 8];
    const short* Bpp = nullptr; short* Bsl = nullptr;
    if (tid < 512) {
        int brow = tid >> 2, bc = tid & 3;
        int bcs = bc ^ ((brow >> 1) & 3);
        Bpp = Bb + (size_t)brow * ldb + bc * 8;
        Bsl = &Bt[brow][bcs * 8];
    }
    short8 aR = *(const short8*)Ap;
    short8 bR; if (tid < 512) bR = *(const short8*)Bpp;

    for (int kt = 0; kt < nkt; ++kt) {
        __syncthreads();                                // prev frags consumed
        *(short8*)Asl = aR;
        if (tid < 512) *(short8*)Bsl = bR;
        __syncthreads();
        if (kt + 1 < nkt) {                             // prefetch next K-tile (hides under MFMA)
            aR = *(const short8*)(Ap + (kt + 1) * 32);
            if (tid < 512) bR = *(const short8*)(Bpp + (kt + 1) * 32);
        }
        short8 af[4], bf[2];
        #pragma unroll
        for (int mi = 0; mi < 4; ++mi) {
            int row = wr * 64 + mi * 16 + lr;
            int cs = lc ^ ((row >> 1) & 3);
            af[mi] = *(const short8*)&At[row][cs * 8];
        }
        #pragma unroll
        for (int ni = 0; ni < 2; ++ni) {
            int row = wc * 32 + ni * 16 + lr;
            int cs = lc ^ ((row >> 1) & 3);
            bf[ni] = *(const short8*)&Bt[row][cs * 8];
        }
        #pragma unroll
        for (int mi = 0; mi < 4; ++mi)
            #pragma unroll
            for (int ni = 0; ni < 2; ++ni)
                acc[mi][ni] = __builtin_amdgcn_mfma_f32_16x16x32_bf16(af[mi], bf[ni], acc[mi][ni], 0, 0, 0);
    }
    __syncthreads();                                    // all ds_reads done; safe to alias
    // Phase 2a: pack bf16 pairs across (lr, lr^1), even-lr lanes write u32.
    {
        int orow0 = wr * 64, ocol0 = wc * 32;
        bool wlane = ((lr & 1) == 0);
        #pragma unroll
        for (int mi = 0; mi < 4; ++mi)
            #pragma unroll
            for (int ni = 0; ni < 2; ++ni) {
                f32x4 v = acc[mi][ni];
                float w0 = __shfl_xor(v[0], 1);
                float w1 = __shfl_xor(v[1], 1);
                float w2 = __shfl_xor(v[2], 1);
                float w3 = __shfl_xor(v[3], 1);
                if (wlane) {
                    int colw = (ocol0 + ni * 16 + lr) >> 1;
                    int rb = orow0 + mi * 16 + lc * 4;
                    Ysm32[(rb + 0) * YW + colw] = (unsigned)f2b(v[0]) | ((unsigned)f2b(w0) << 16);
                    Ysm32[(rb + 1) * YW + colw] = (unsigned)f2b(v[1]) | ((unsigned)f2b(w1) << 16);
                    Ysm32[(rb + 2) * YW + colw] = (unsigned)f2b(v[2]) | ((unsigned)f2b(w2) << 16);
                    Ysm32[(rb + 3) * YW + colw] = (unsigned)f2b(v[3]) | ((unsigned)f2b(w3) << 16);
                }
            }
    }
    if (tid < YW) Ysm32[256 * YW + tid] = 0u;           // sentinel row 256 = zeros
    __syncthreads();
    // Phase 2b: CSR gather + epilogue. lane covers cols (2*lane, 2*lane+1); wave covers 16 rows.
    int col = nh * 128 + lane * 2;
    float bv0 = 0.f, bv1 = 0.f;
    if (col < MEM) { bv0 = bias[col]; bv1 = bias[col + 1]; }
    int r0 = wid * 16;
    for (int rr = 0; rr < 8; ++rr) {
        int rA = r0 + rr, rB = r0 + 8 + rr;
        int gA = batch * NL + rA, gB = batch * NL + rB;
        const unsigned short* nA = nbr + (size_t)gA * NL;
        const unsigned short* nB = nbr + (size_t)gB * NL;
        int npA = cntp[gA], npB = cntp[gB];
        float axA = 0.f, ayA = 0.f, axB = 0.f, ayB = 0.f;
        int nmax = npA > npB ? npA : npB;
        for (int t = 0; t < nmax; t += 8) {
            if (t < npA) {                              // wave-uniform branch
                short8 I = *(const short8*)(nA + t);
                #pragma unroll
                for (int i = 0; i < 8; ++i) {
                    int j = (int)(unsigned short)I[i];
                    unsigned u = Ysm32[j * YW + lane];
                    axA += __builtin_bit_cast(float, u << 16);
                    ayA += __builtin_bit_cast(float, u & 0xffff0000u);
                }
            }
            if (t < npB) {
                short8 I = *(const short8*)(nB + t);
                #pragma unroll
                for (int i = 0; i < 8; ++i) {
                    int j = (int)(unsigned short)I[i];
                    unsigned u = Ysm32[j * YW + lane];
                    axB += __builtin_bit_cast(float, u << 16);
                    ayB += __builtin_bit_cast(float, u & 0xffff0000u);
                }
            }
        }
        unsigned uA = Ysm32[rA * YW + lane];
        unsigned uB = Ysm32[rB * YW + lane];
        float dA = dinv[gA], dB = dinv[gB];
        float hA0 = fmaxf((axA + __builtin_bit_cast(float, uA << 16) + 2.f * bv0) * dA, 0.f);
        float hA1 = fmaxf((ayA + __builtin_bit_cast(float, uA & 0xffff0000u) + 2.f * bv1) * dA, 0.f);
        float hB0 = fmaxf((axB + __builtin_bit_cast(float, uB << 16) + 2.f * bv0) * dB, 0.f);
        float hB1 = fmaxf((ayB + __builtin_bit_cast(float, uB & 0xffff0000u) + 2.f * bv1) * dB, 0.f);
        if (FINAL == 0) {
            unsigned pA = (unsigned)f2b(hA0) | ((unsigned)f2b(hA1) << 16);
            unsigned pB = (unsigned)f2b(hB0) | ((unsigned)f2b(hB1) << 16);
            ((unsigned*)x1b)[(size_t)gA * 128 + nh * 64 + lane] = pA;
            ((unsigned*)x1b)[(size_t)gB * 128 + nh * 64 + lane] = pB;
        } else if (col < MEM) {
            float2 oA; oA.x = hA0; oA.y = hA1;
            float2 oB; oB.x = hB0; oB.y = hB1;
            *(float2*)(outx + (size_t)gA * MEM + col) = oA;
            *(float2*)(outx + (size_t)gB * MEM + col) = oB;
        }
    }
}

extern "C" void kernel_launch(void* const* d_in, const int* in_sizes, int n_in,
                              void* d_out, int out_size, void* d_ws, size_t ws_size,
                              hipStream_t stream) {
    const int*   words = (const int*)d_in[0];
    const int*   pos   = (const int*)d_in[1];
    const int*   ner   = (const int*)d_in[2];
    const float* adj   = (const float*)d_in[3];
    const float* embW  = (const float*)d_in[4];
    const float* posW  = (const float*)d_in[5];
    const float* nerW  = (const float*)d_in[6];
    const float* W0    = (const float*)d_in[7];
    const float* b0    = (const float*)d_in[8];
    const float* W1    = (const float*)d_in[9];
    const float* b1    = (const float*)d_in[10];
    float* out = (float*)d_out;

    char* ws = (char*)d_ws;
    size_t off = 0;
    short* x0b = (short*)(ws + off);        off += (size_t)NROWS * KP1 * 2;       // 25.2 MB
    short* W0p = (short*)(ws + off);        off += (size_t)NP * KP1 * 2;
    short* W1p = (short*)(ws + off);        off += (size_t)NP * NP * 2;
    short* X1b = (short*)(ws + off);        off += (size_t)NROWS * NP * 2;        // 16.8 MB
    float* dinv = (float*)(ws + off);       off += (size_t)NROWS * 4;
    float* rsum = (float*)(ws + off);       off += (size_t)NROWS * 4;
    unsigned* colnz = (unsigned*)(ws + off); off += (size_t)NROWS * 4;
    int* cntp = (int*)(ws + off);           off += (size_t)NROWS * 4;
    unsigned short* nbr = (unsigned short*)(ws + off); off += (size_t)NROWS * NL * 2; // 16.8 MB

    prep_weights<<<(NP * KP1 + NP * NP + 255) / 256, 256, 0, stream>>>(W0, W1, W0p, W1p, colnz);
    embed_kernel<<<NROWS / 8, 384, 0, stream>>>(words, pos, ner, embW, posW, nerW, x0b);
    adjrow_kernel<<<NROWS / 4, 256, 0, stream>>>(adj, dinv, rsum, nbr, cntp, colnz);
    mask_kernel<<<NROWS / 256, 256, 0, stream>>>(rsum, colnz, out + OUT_X);

    const int ldsB = 257 * YW * 4;   // 66,820 B (At/Bt alias inside)
    fused_kernel<0><<<NB * 2, 1024, ldsB, stream>>>(x0b, KP1, KP1 / 32, W0p, KP1,
                                                    nbr, cntp, dinv, b0, X1b, nullptr);
    fused_kernel<1><<<NB * 2, 1024, ldsB, stream>>>(X1b, NP, NP / 32, W1p, NP,
                                                    nbr, cntp, dinv, b1, nullptr, out);
}

// Round 9
// 121.192 us; speedup vs baseline: 1.6031x; 1.0146x over previous
//
#include <hip/hip_runtime.h>
#include <hip/hip_bf16.h>
#include <stdint.h>

typedef __attribute__((ext_vector_type(8))) short short8;
typedef __attribute__((ext_vector_type(4))) float f32x4;

#define NB 128
#define NL 256
#define NROWS 32768        // B*L
#define IN_DIM 360
#define KP1 384            // padded K for layer-1 GEMM (permuted layout, see embed_kernel)
#define MEM 200
#define NP 256             // padded N
#define OUT_X (NROWS * MEM)
#define YW 33              // Ysm row pitch in u32 words (66 bf16; odd -> bank spread)

// Permuted K layout for x0/W0p (keeps every 8-col chunk single-table):
//   kp 0..299 emb | kp 304..333 pos | kp 336..365 ner | else zero

__device__ __forceinline__ unsigned short f2b(float f) {
    unsigned u = __builtin_bit_cast(unsigned, f);
    unsigned r = (u + 0x7FFFu + ((u >> 16) & 1u)) >> 16;
    return (unsigned short)r;
}

// ---------------- weight prep + colnz zero
__global__ void prep_weights(const float* __restrict__ W0, const float* __restrict__ W1,
                             short* __restrict__ W0p, short* __restrict__ W1p,
                             unsigned* __restrict__ colnz) {
    int idx = blockIdx.x * 256 + threadIdx.x;
    if (idx < NROWS) colnz[idx] = 0u;
    if (idx < NP * KP1) {
        int n = idx / KP1, kp = idx - n * KP1;
        float v = 0.f;
        if (n < MEM) {
            if (kp < 300)                   v = W0[n * IN_DIM + kp];
            else if (kp >= 304 && kp < 334) v = W0[n * IN_DIM + 300 + (kp - 304)];
            else if (kp >= 336 && kp < 366) v = W0[n * IN_DIM + 330 + (kp - 336)];
        }
        W0p[idx] = (short)f2b(v);
    } else {
        int i2 = idx - NP * KP1;
        if (i2 < NP * NP) {
            int n = i2 >> 8, k = i2 & 255;
            float v = (n < MEM && k < MEM) ? W1[n * MEM + k] : 0.f;
            W1p[i2] = (short)f2b(v);
        }
    }
}

// ---------------- embedding concat -> x0 bf16 [32768][384] (permuted K layout)
__global__ __launch_bounds__(384) void embed_kernel(
    const int* __restrict__ words, const int* __restrict__ pos, const int* __restrict__ ner,
    const float* __restrict__ embW, const float* __restrict__ posW,
    const float* __restrict__ nerW, short* __restrict__ x0b) {
    int t = threadIdx.x;
    int r = t / 48, c = t - r * 48;
    int row = blockIdx.x * 8 + r;
    float vals[8];
    #pragma unroll
    for (int i = 0; i < 8; ++i) vals[i] = 0.f;
    if (c < 37) {
        const float* src = embW + (size_t)words[row] * 300 + c * 8;
        float4 a = *(const float4*)src;
        float4 b = *(const float4*)(src + 4);
        vals[0] = a.x; vals[1] = a.y; vals[2] = a.z; vals[3] = a.w;
        vals[4] = b.x; vals[5] = b.y; vals[6] = b.z; vals[7] = b.w;
    } else if (c == 37) {
        const float* src = embW + (size_t)words[row] * 300 + 296;
        vals[0] = src[0]; vals[1] = src[1]; vals[2] = src[2]; vals[3] = src[3];
    } else if (c <= 41) {
        int k0 = c * 8 - 304;
        const float* src = posW + (size_t)pos[row] * 30 + k0;
        #pragma unroll
        for (int i = 0; i < 8; ++i) if (k0 + i < 30) vals[i] = src[i];
    } else if (c <= 45) {
        int k0 = c * 8 - 336;
        const float* src = nerW + (size_t)ner[row] * 30 + k0;
        #pragma unroll
        for (int i = 0; i < 8; ++i) if (k0 + i < 30) vals[i] = src[i];
    }
    short8 st;
    #pragma unroll
    for (int i = 0; i < 8; ++i) st[i] = (short)f2b(vals[i]);
    *(short8*)((unsigned short*)x0b + (size_t)row * KP1 + c * 8) = st;
}

// ---------------- adj row pass: rowsum, denom_inv, padded u16 CSR, col-nonzero flags
__global__ void adjrow_kernel(const float* __restrict__ adj, float* __restrict__ dinv,
                              float* __restrict__ rsum, unsigned short* __restrict__ nbr,
                              int* __restrict__ cntp, unsigned* __restrict__ colnz) {
    int row = blockIdx.x * 4 + (threadIdx.x >> 6);
    int lane = threadIdx.x & 63;
    const float4* ar = (const float4*)(adj + (size_t)row * NL);
    float4 v = ar[lane];
    float s = v.x + v.y + v.z + v.w;
    #pragma unroll
    for (int off = 32; off >= 1; off >>= 1) s += __shfl_xor(s, off);
    unsigned long long m0 = __ballot(v.x != 0.f);
    unsigned long long m1 = __ballot(v.y != 0.f);
    unsigned long long m2 = __ballot(v.z != 0.f);
    unsigned long long m3 = __ballot(v.w != 0.f);
    unsigned long long lt = ((unsigned long long)1 << lane) - 1;
    int c0 = __popcll(m0), c1 = c0 + __popcll(m1), c2 = c1 + __popcll(m2);
    int total = c2 + __popcll(m3);
    int p0 = __popcll(m0 & lt);
    int p1 = c0 + __popcll(m1 & lt);
    int p2 = c1 + __popcll(m2 & lt);
    int p3 = c2 + __popcll(m3 & lt);
    unsigned short* nb = nbr + (size_t)row * NL;
    if (v.x != 0.f) nb[p0] = (unsigned short)(lane * 4 + 0);
    if (v.y != 0.f) nb[p1] = (unsigned short)(lane * 4 + 1);
    if (v.z != 0.f) nb[p2] = (unsigned short)(lane * 4 + 2);
    if (v.w != 0.f) nb[p3] = (unsigned short)(lane * 4 + 3);
    int padTo = (total + 7) & ~7;
    if (lane < padTo - total) nb[total + lane] = 256;   // sentinel -> zero Ysm row
    if (lane == 0) {
        rsum[row] = s; dinv[row] = 1.0f / (s + 1.0f);
        cntp[row] = padTo;
    }
    unsigned* cz = colnz + ((row >> 8) << 8);
    if (v.x != 0.f) atomicOr(&cz[lane * 4 + 0], 1u);
    if (v.y != 0.f) atomicOr(&cz[lane * 4 + 1], 1u);
    if (v.z != 0.f) atomicOr(&cz[lane * 4 + 2], 1u);
    if (v.w != 0.f) atomicOr(&cz[lane * 4 + 3], 1u);
}

__global__ void mask_kernel(const float* __restrict__ rsum, const unsigned* __restrict__ colnz,
                            float* __restrict__ outm) {
    int r = blockIdx.x * 256 + threadIdx.x;
    outm[r] = (rsum[r] == 0.f && colnz[r] == 0u) ? 1.0f : 0.0f;
}

// ---------------- FUSED per-layer: GEMM (M=256, N=64 quarter) + in-LDS gather + epilogue.
// 512 thr / 8 waves (4x2), wave tile 64x32, reg-prefetch staging, bf16 Ysm [257][66] (33.9 KB).
// Grid 512 = 2 blocks/CU: two independent barrier domains per CU overlap phases.
// XCD-affine swizzle: 4 quarters of one batch land on one XCD, adjacent in dispatch ->
// A-panel re-reads hit that XCD's L2.
// Phase 2b: half-wave row split (lanes 0-31 row r, 32-63 row r+16), parity-dual chains.
template <int FINAL>
__global__ __launch_bounds__(512) void fused_kernel(
    const short* __restrict__ A, int lda, int nkt,
    const short* __restrict__ Bp, int ldb,
    const unsigned short* __restrict__ nbr, const int* __restrict__ cntp,
    const float* __restrict__ dinv, const float* __restrict__ bias,
    short* __restrict__ x1b, float* __restrict__ outx) {
    extern __shared__ char smem[];
    short (*At)[32] = (short (*)[32])smem;              // [256][32] bf16, 16 KB
    short (*Bt)[32] = (short (*)[32])(smem + 16384);    // [64][32] bf16,   4 KB
    unsigned* Ysm32 = (unsigned*)smem;                  // [257][33] u32 = bf16 pairs (aliases)

    int bi = blockIdx.x;
    int xcd = bi & 7, s = bi >> 3;
    int batch = xcd * 16 + (s >> 2), q = s & 3;         // bijective: 512 = 8 * 16 * 4

    int tid = threadIdx.x;
    int lane = tid & 63, wid = tid >> 6;
    int wr = wid >> 1, wc = wid & 1;                    // 4 x 2 wave grid
    int lr = lane & 15, lc = lane >> 4;
    f32x4 acc[4][2] = {};
    const short* Ab = A + (size_t)batch * NL * lda;
    const short* Bb = Bp + (size_t)q * 64 * ldb;

    // staging slots: At = 1024 short8 over 512 thr (2 each, rows +0/+128); Bt = 256 (tid<256)
    int arow = tid >> 2, ac = tid & 3;
    int acs0 = ac ^ ((arow >> 1) & 3);
    int acs1 = ac ^ (((arow + 128) >> 1) & 3);
    const short* Ap0 = Ab + (size_t)arow * lda + ac * 8;
    const short* Ap1 = Ap0 + (size_t)128 * lda;
    short* Asl0 = &At[arow][acs0 * 8];
    short* Asl1 = &At[arow + 128][acs1 * 8];
    const short* Bpp = nullptr; short* Bsl = nullptr;
    if (tid < 256) {
        int brow = tid >> 2, bc = tid & 3;
        int bcs = bc ^ ((brow >> 1) & 3);
        Bpp = Bb + (size_t)brow * ldb + bc * 8;
        Bsl = &Bt[brow][bcs * 8];
    }
    short8 aR0 = *(const short8*)Ap0;
    short8 aR1 = *(const short8*)Ap1;
    short8 bR; if (tid < 256) bR = *(const short8*)Bpp;

    for (int kt = 0; kt < nkt; ++kt) {
        __syncthreads();                                // prev frags consumed
        *(short8*)Asl0 = aR0;
        *(short8*)Asl1 = aR1;
        if (tid < 256) *(short8*)Bsl = bR;
        __syncthreads();
        if (kt + 1 < nkt) {                             // prefetch next K-tile under MFMA
            aR0 = *(const short8*)(Ap0 + (kt + 1) * 32);
            aR1 = *(const short8*)(Ap1 + (kt + 1) * 32);
            if (tid < 256) bR = *(const short8*)(Bpp + (kt + 1) * 32);
        }
        short8 af[4], bf[2];
        #pragma unroll
        for (int mi = 0; mi < 4; ++mi) {
            int row = wr * 64 + mi * 16 + lr;
            int cs = lc ^ ((row >> 1) & 3);
            af[mi] = *(const short8*)&At[row][cs * 8];
        }
        #pragma unroll
        for (int ni = 0; ni < 2; ++ni) {
            int row = wc * 32 + ni * 16 + lr;
            int cs = lc ^ ((row >> 1) & 3);
            bf[ni] = *(const short8*)&Bt[row][cs * 8];
        }
        #pragma unroll
        for (int mi = 0; mi < 4; ++mi)
            #pragma unroll
            for (int ni = 0; ni < 2; ++ni)
                acc[mi][ni] = __builtin_amdgcn_mfma_f32_16x16x32_bf16(af[mi], bf[ni], acc[mi][ni], 0, 0, 0);
    }
    __syncthreads();                                    // all ds_reads done; safe to alias
    // Phase 2a: pack bf16 pairs across (lr, lr^1); even-lr lanes write u32.
    {
        int orow0 = wr * 64, ocol0 = wc * 32;
        bool wlane = ((lr & 1) == 0);
        #pragma unroll
        for (int mi = 0; mi < 4; ++mi)
            #pragma unroll
            for (int ni = 0; ni < 2; ++ni) {
                f32x4 v = acc[mi][ni];
                float w0 = __shfl_xor(v[0], 1);
                float w1 = __shfl_xor(v[1], 1);
                float w2 = __shfl_xor(v[2], 1);
                float w3 = __shfl_xor(v[3], 1);
                if (wlane) {
                    int colw = (ocol0 + ni * 16 + lr) >> 1;
                    int rb = orow0 + mi * 16 + lc * 4;
                    Ysm32[(rb + 0) * YW + colw] = (unsigned)f2b(v[0]) | ((unsigned)f2b(w0) << 16);
                    Ysm32[(rb + 1) * YW + colw] = (unsigned)f2b(v[1]) | ((unsigned)f2b(w1) << 16);
                    Ysm32[(rb + 2) * YW + colw] = (unsigned)f2b(v[2]) | ((unsigned)f2b(w2) << 16);
                    Ysm32[(rb + 3) * YW + colw] = (unsigned)f2b(v[3]) | ((unsigned)f2b(w3) << 16);
                }
            }
    }
    if (tid < YW) Ysm32[256 * YW + tid] = 0u;           // sentinel row 256 = zeros
    __syncthreads();
    // Phase 2b: CSR gather + epilogue. Half-wave handles its own row; lane l covers
    // quarter-cols (2l, 2l+1). Wave covers 32 rows in 16 iterations.
    int hl = lane >> 5, l = lane & 31;
    int col = q * 64 + 2 * l;                           // global col (even; MEM even)
    float bv0 = 0.f, bv1 = 0.f;
    if (col < MEM) { bv0 = bias[col]; bv1 = bias[col + 1]; }
    int r0 = wid * 32;
    for (int rr = 0; rr < 16; ++rr) {
        int r = r0 + hl * 16 + rr;
        int g = batch * NL + r;
        const unsigned short* nb = nbr + (size_t)g * NL;
        int np = cntp[g];
        float a0 = 0.f, a1 = 0.f, c0 = 0.f, c1 = 0.f;   // parity-dual chains
        for (int t = 0; t < np; t += 8) {
            short8 I = *(const short8*)(nb + t);
            #pragma unroll
            for (int i = 0; i < 8; i += 2) {
                int j0 = (int)(unsigned short)I[i];
                int j1 = (int)(unsigned short)I[i + 1];
                unsigned u0 = Ysm32[j0 * YW + l];
                unsigned u1 = Ysm32[j1 * YW + l];
                a0 += __builtin_bit_cast(float, u0 << 16);
                c0 += __builtin_bit_cast(float, u0 & 0xffff0000u);
                a1 += __builtin_bit_cast(float, u1 << 16);
                c1 += __builtin_bit_cast(float, u1 & 0xffff0000u);
            }
        }
        float ax = a0 + a1, ay = c0 + c1;
        unsigned uS = Ysm32[r * YW + l];
        float di = dinv[g];
        float h0 = fmaxf((ax + __builtin_bit_cast(float, uS << 16) + 2.f * bv0) * di, 0.f);
        float h1 = fmaxf((ay + __builtin_bit_cast(float, uS & 0xffff0000u) + 2.f * bv1) * di, 0.f);
        if (FINAL == 0) {
            ((unsigned*)x1b)[(size_t)g * 128 + q * 32 + l] =
                (unsigned)f2b(h0) | ((unsigned)f2b(h1) << 16);
        } else if (col < MEM) {
            float2 o; o.x = h0; o.y = h1;
            *(float2*)(outx + (size_t)g * MEM + col) = o;
        }
    }
}

extern "C" void kernel_launch(void* const* d_in, const int* in_sizes, int n_in,
                              void* d_out, int out_size, void* d_ws, size_t ws_size,
                              hipStream_t stream) {
    const int*   words = (const int*)d_in[0];
    const int*   pos   = (const int*)d_in[1];
    const int*   ner   = (const int*)d_in[2];
    const float* adj   = (const float*)d_in[3];
    const float* embW  = (const float*)d_in[4];
    const float* posW  = (const float*)d_in[5];
    const float* nerW  = (const float*)d_in[6];
    const float* W0    = (const float*)d_in[7];
    const float* b0    = (const float*)d_in[8];
    const float* W1    = (const float*)d_in[9];
    const float* b1    = (const float*)d_in[10];
    float* out = (float*)d_out;

    char* ws = (char*)d_ws;
    size_t off = 0;
    short* x0b = (short*)(ws + off);        off += (size_t)NROWS * KP1 * 2;       // 25.2 MB
    short* W0p = (short*)(ws + off);        off += (size_t)NP * KP1 * 2;
    short* W1p = (short*)(ws + off);        off += (size_t)NP * NP * 2;
    short* X1b = (short*)(ws + off);        off += (size_t)NROWS * NP * 2;        // 16.8 MB
    float* dinv = (float*)(ws + off);       off += (size_t)NROWS * 4;
    float* rsum = (float*)(ws + off);       off += (size_t)NROWS * 4;
    unsigned* colnz = (unsigned*)(ws + off); off += (size_t)NROWS * 4;
    int* cntp = (int*)(ws + off);           off += (size_t)NROWS * 4;
    unsigned short* nbr = (unsigned short*)(ws + off); off += (size_t)NROWS * NL * 2; // 16.8 MB

    prep_weights<<<(NP * KP1 + NP * NP + 255) / 256, 256, 0, stream>>>(W0, W1, W0p, W1p, colnz);
    embed_kernel<<<NROWS / 8, 384, 0, stream>>>(words, pos, ner, embW, posW, nerW, x0b);
    adjrow_kernel<<<NROWS / 4, 256, 0, stream>>>(adj, dinv, rsum, nbr, cntp, colnz);
    mask_kernel<<<NROWS / 256, 256, 0, stream>>>(rsum, colnz, out + OUT_X);

    const int ldsB = 257 * YW * 4;   // 33,924 B (At/Bt alias inside)
    fused_kernel<0><<<NB * 4, 512, ldsB, stream>>>(x0b, KP1, KP1 / 32, W0p, KP1,
                                                   nbr, cntp, dinv, b0, X1b, nullptr);
    fused_kernel<1><<<NB * 4, 512, ldsB, stream>>>(X1b, NP, NP / 32, W1p, NP,
                                                   nbr, cntp, dinv, b1, nullptr, out);
}

// Round 10
// 118.033 us; speedup vs baseline: 1.6460x; 1.0268x over previous
//
#include <hip/hip_runtime.h>
#include <hip/hip_bf16.h>
#include <stdint.h>

typedef __attribute__((ext_vector_type(8))) short short8;
typedef __attribute__((ext_vector_type(4))) float f32x4;

#define NB 128
#define NL 256
#define NROWS 32768        // B*L
#define IN_DIM 360
#define KP1 384            // padded K for layer-1 GEMM (permuted layout, see embed_kernel)
#define MEM 200
#define NP 256             // padded N
#define OUT_X (NROWS * MEM)
#define YW 17              // Ysm pitch in u32 (16 used + 1 -> bank spread)
#define NBS 272            // nbr row stride in u16 (max padded 264)
#define BUFB 18432         // staging buffer bytes: At 16K + Bt 2K

// Permuted K layout for x0/W0p (keeps every 8-col chunk single-table):
//   kp 0..299 emb | kp 304..333 pos | kp 336..365 ner | else zero

__device__ __forceinline__ unsigned short f2b(float f) {
    unsigned u = __builtin_bit_cast(unsigned, f);
    unsigned r = (u + 0x7FFFu + ((u >> 16) & 1u)) >> 16;
    return (unsigned short)r;
}

__device__ __forceinline__ void gl16(const void* g, void* l) {
    __builtin_amdgcn_global_load_lds((const __attribute__((address_space(1))) unsigned*)g,
                                     (__attribute__((address_space(3))) unsigned*)l, 16, 0, 0);
}

// ---------------- weight prep + colnz zero
__global__ void prep_weights(const float* __restrict__ W0, const float* __restrict__ W1,
                             short* __restrict__ W0p, short* __restrict__ W1p,
                             unsigned* __restrict__ colnz) {
    int idx = blockIdx.x * 256 + threadIdx.x;
    if (idx < NROWS) colnz[idx] = 0u;
    if (idx < NP * KP1) {
        int n = idx / KP1, kp = idx - n * KP1;
        float v = 0.f;
        if (n < MEM) {
            if (kp < 300)                   v = W0[n * IN_DIM + kp];
            else if (kp >= 304 && kp < 334) v = W0[n * IN_DIM + 300 + (kp - 304)];
            else if (kp >= 336 && kp < 366) v = W0[n * IN_DIM + 330 + (kp - 336)];
        }
        W0p[idx] = (short)f2b(v);
    } else {
        int i2 = idx - NP * KP1;
        if (i2 < NP * NP) {
            int n = i2 >> 8, k = i2 & 255;
            float v = (n < MEM && k < MEM) ? W1[n * MEM + k] : 0.f;
            W1p[i2] = (short)f2b(v);
        }
    }
}

// ---------------- embedding concat -> x0 bf16 [32768][384] (permuted K layout)
__global__ __launch_bounds__(384) void embed_kernel(
    const int* __restrict__ words, const int* __restrict__ pos, const int* __restrict__ ner,
    const float* __restrict__ embW, const float* __restrict__ posW,
    const float* __restrict__ nerW, short* __restrict__ x0b) {
    int t = threadIdx.x;
    int r = t / 48, c = t - r * 48;
    int row = blockIdx.x * 8 + r;
    float vals[8];
    #pragma unroll
    for (int i = 0; i < 8; ++i) vals[i] = 0.f;
    if (c < 37) {
        const float* src = embW + (size_t)words[row] * 300 + c * 8;
        float4 a = *(const float4*)src;
        float4 b = *(const float4*)(src + 4);
        vals[0] = a.x; vals[1] = a.y; vals[2] = a.z; vals[3] = a.w;
        vals[4] = b.x; vals[5] = b.y; vals[6] = b.z; vals[7] = b.w;
    } else if (c == 37) {
        const float* src = embW + (size_t)words[row] * 300 + 296;
        vals[0] = src[0]; vals[1] = src[1]; vals[2] = src[2]; vals[3] = src[3];
    } else if (c <= 41) {
        int k0 = c * 8 - 304;
        const float* src = posW + (size_t)pos[row] * 30 + k0;
        #pragma unroll
        for (int i = 0; i < 8; ++i) if (k0 + i < 30) vals[i] = src[i];
    } else if (c <= 45) {
        int k0 = c * 8 - 336;
        const float* src = nerW + (size_t)ner[row] * 30 + k0;
        #pragma unroll
        for (int i = 0; i < 8; ++i) if (k0 + i < 30) vals[i] = src[i];
    }
    short8 st;
    #pragma unroll
    for (int i = 0; i < 8; ++i) st[i] = (short)f2b(vals[i]);
    *(short8*)((unsigned short*)x0b + (size_t)row * KP1 + c * 8) = st;
}

// ---------------- adj row pass: rowsum, denom_inv, padded u16 CSR (count in slot 0), colnz
// Row layout: nb[0]=padTo (slots incl header, x8), nb[1..total]=entries, rest sentinel 256.
__global__ void adjrow_kernel(const float* __restrict__ adj, float* __restrict__ dinv,
                              float* __restrict__ rsum, unsigned short* __restrict__ nbr,
                              unsigned* __restrict__ colnz) {
    int row = blockIdx.x * 4 + (threadIdx.x >> 6);
    int lane = threadIdx.x & 63;
    const float4* ar = (const float4*)(adj + (size_t)row * NL);
    float4 v = ar[lane];
    float s = v.x + v.y + v.z + v.w;
    #pragma unroll
    for (int off = 32; off >= 1; off >>= 1) s += __shfl_xor(s, off);
    unsigned long long m0 = __ballot(v.x != 0.f);
    unsigned long long m1 = __ballot(v.y != 0.f);
    unsigned long long m2 = __ballot(v.z != 0.f);
    unsigned long long m3 = __ballot(v.w != 0.f);
    unsigned long long lt = ((unsigned long long)1 << lane) - 1;
    int c0 = __popcll(m0), c1 = c0 + __popcll(m1), c2 = c1 + __popcll(m2);
    int total = c2 + __popcll(m3);
    int p0 = __popcll(m0 & lt);
    int p1 = c0 + __popcll(m1 & lt);
    int p2 = c1 + __popcll(m2 & lt);
    int p3 = c2 + __popcll(m3 & lt);
    unsigned short* nb = nbr + (size_t)row * NBS;
    if (v.x != 0.f) nb[p0 + 1] = (unsigned short)(lane * 4 + 0);
    if (v.y != 0.f) nb[p1 + 1] = (unsigned short)(lane * 4 + 1);
    if (v.z != 0.f) nb[p2 + 1] = (unsigned short)(lane * 4 + 2);
    if (v.w != 0.f) nb[p3 + 1] = (unsigned short)(lane * 4 + 3);
    int padTo = (total + 8) & ~7;                       // header + entries, rounded to x8
    if (lane < padTo - 1 - total) nb[total + 1 + lane] = 256;   // sentinel -> zero Ysm row
    if (lane == 0) {
        rsum[row] = s; dinv[row] = 1.0f / (s + 1.0f);
        nb[0] = (unsigned short)padTo;
    }
    unsigned* cz = colnz + ((row >> 8) << 8);
    if (v.x != 0.f) atomicOr(&cz[lane * 4 + 0], 1u);
    if (v.y != 0.f) atomicOr(&cz[lane * 4 + 1], 1u);
    if (v.z != 0.f) atomicOr(&cz[lane * 4 + 2], 1u);
    if (v.w != 0.f) atomicOr(&cz[lane * 4 + 3], 1u);
}

__global__ void mask_kernel(const float* __restrict__ rsum, const unsigned* __restrict__ colnz,
                            float* __restrict__ outm) {
    int r = blockIdx.x * 256 + threadIdx.x;
    outm[r] = (rsum[r] == 0.f && colnz[r] == 0u) ? 1.0f : 0.0f;
}

// ---------------- FUSED per-layer: GEMM (M=256, N=32 slice) + in-LDS gather + epilogue.
// Grid 1024 (batch x 8 slices) x 512 thr -> 4 blocks/CU, 32 waves/CU (100% occupancy).
// Phase 1: double-buffered global_load_lds staging (pre-swizzled source, linear LDS dest),
//          raw s_barrier + counted vmcnt (loads stay in flight across barriers).
// Phase 2a: acc -> bf16-pair Ysm [257][17]u32 (aliases buf0; row 256 zeros).
// Phase 2b: CSR gather, 4 rows/wave-iter via quarter-waves, count embedded in chunk 0.
template <int FINAL>
__global__ __launch_bounds__(512, 8) void fused_kernel(
    const short* __restrict__ A, int lda, int nkt,
    const short* __restrict__ Bp, int ldb,
    const unsigned short* __restrict__ nbr,
    const float* __restrict__ dinv, const float* __restrict__ bias,
    short* __restrict__ x1b, float* __restrict__ outx) {
    extern __shared__ char smem[];
    unsigned* Ysm32 = (unsigned*)smem;                  // [257][17] u32, aliases buf0

    int bi = blockIdx.x;
    int s = bi >> 3;
    int batch = (bi & 7) * 16 + (s >> 3), sl = s & 7;   // bijective: 1024 = 8*16*8

    int tid = threadIdx.x;
    int lane = tid & 63, wid = tid >> 6;
    int lr = lane & 15, lc = lane >> 4;
    f32x4 acc[2][2] = {};
    const short* Ab = A + (size_t)batch * NL * lda;
    const short* Bb = Bp + (size_t)sl * 32 * ldb;

    // staging geometry: linear 16B-chunk index li: At li=row*4+cd (1024 chunks),
    // Bt li2=row*4+cd (128 chunks). Source col chunk = cd ^ ((row>>1)&3) (XOR involution,
    // matched by the swizzled frag reads below).
    int liA0 = wid * 128;                               // wave-uniform chunk bases
    int liA1 = liA0 + 64;
    int liL0 = liA0 + lane;
    int rA0 = liL0 >> 2, cA0 = (liL0 & 3) ^ ((rA0 >> 1) & 3);
    int liL1 = liA1 + lane;
    int rA1 = liL1 >> 2, cA1 = (liL1 & 3) ^ ((rA1 >> 1) & 3);
    const short* srcA0 = Ab + (size_t)rA0 * lda + cA0 * 8;
    const short* srcA1 = Ab + (size_t)rA1 * lda + cA1 * 8;
    int liB = wid * 64 + lane;
    int rB = liB >> 2, cB = (liB & 3) ^ ((rB >> 1) & 3);
    const short* srcB = Bb + (size_t)rB * ldb + cB * 8;

    #define STAGE(b, kt) do {                                            \
        char* base_ = smem + (b) * BUFB;                                 \
        gl16(srcA0 + (kt) * 32, base_ + liA0 * 16);                      \
        gl16(srcA1 + (kt) * 32, base_ + liA1 * 16);                      \
        if (wid < 2) gl16(srcB + (kt) * 32, base_ + 16384 + wid * 1024); \
    } while (0)

    STAGE(0, 0);
    for (int kt = 0; kt < nkt; ++kt) {
        int cur = kt & 1;
        if (kt + 1 < nkt) {
            STAGE(cur ^ 1, kt + 1);
            if (wid < 2) asm volatile("s_waitcnt vmcnt(3)" ::: "memory");
            else         asm volatile("s_waitcnt vmcnt(2)" ::: "memory");
        } else {
            asm volatile("s_waitcnt vmcnt(0)" ::: "memory");
        }
        __builtin_amdgcn_sched_barrier(0);
        __builtin_amdgcn_s_barrier();                   // tile kt fully staged (all waves)
        const short* Atc = (const short*)(smem + cur * BUFB);
        const short* Btc = Atc + 8192;                  // +16384 bytes
        short8 af[2], bf[2];
        #pragma unroll
        for (int mi = 0; mi < 2; ++mi) {
            int row = wid * 32 + mi * 16 + lr;
            int cs = lc ^ ((row >> 1) & 3);
            af[mi] = *(const short8*)(Atc + row * 32 + cs * 8);
        }
        #pragma unroll
        for (int ni = 0; ni < 2; ++ni) {
            int row = ni * 16 + lr;
            int cs = lc ^ ((row >> 1) & 3);
            bf[ni] = *(const short8*)(Btc + row * 32 + cs * 8);
        }
        asm volatile("s_waitcnt lgkmcnt(0)" ::: "memory");
        __builtin_amdgcn_sched_barrier(0);              // rule 18: pin MFMA after the wait
        #pragma unroll
        for (int mi = 0; mi < 2; ++mi)
            #pragma unroll
            for (int ni = 0; ni < 2; ++ni)
                acc[mi][ni] = __builtin_amdgcn_mfma_f32_16x16x32_bf16(af[mi], bf[ni], acc[mi][ni], 0, 0, 0);
        __builtin_amdgcn_sched_barrier(0);
        __builtin_amdgcn_s_barrier();                   // all reads done before next overwrite
    }
    // Phase 2a: pack bf16 pairs across (lr, lr^1); even-lr lanes write u32 into Ysm.
    {
        bool wl = ((lr & 1) == 0);
        #pragma unroll
        for (int mi = 0; mi < 2; ++mi)
            #pragma unroll
            for (int ni = 0; ni < 2; ++ni) {
                f32x4 v = acc[mi][ni];
                float w0 = __shfl_xor(v[0], 1);
                float w1 = __shfl_xor(v[1], 1);
                float w2 = __shfl_xor(v[2], 1);
                float w3 = __shfl_xor(v[3], 1);
                if (wl) {
                    int colw = (ni * 16 + lr) >> 1;
                    int rb = wid * 32 + mi * 16 + lc * 4;
                    Ysm32[(rb + 0) * YW + colw] = (unsigned)f2b(v[0]) | ((unsigned)f2b(w0) << 16);
                    Ysm32[(rb + 1) * YW + colw] = (unsigned)f2b(v[1]) | ((unsigned)f2b(w1) << 16);
                    Ysm32[(rb + 2) * YW + colw] = (unsigned)f2b(v[2]) | ((unsigned)f2b(w2) << 16);
                    Ysm32[(rb + 3) * YW + colw] = (unsigned)f2b(v[3]) | ((unsigned)f2b(w3) << 16);
                }
            }
    }
    if (tid < 16) Ysm32[256 * YW + tid] = 0u;           // sentinel row
    __syncthreads();
    // Phase 2b: gather. Quarter-wave q handles row r; lane covers cols (2cw, 2cw+1).
    int q = lane >> 4, cw = lane & 15;
    int col = sl * 32 + 2 * cw;
    float bv0 = 0.f, bv1 = 0.f;
    if (col < MEM) { bv0 = bias[col]; bv1 = bias[col + 1]; }
    for (int rr = 0; rr < 8; ++rr) {
        int r = wid * 32 + q * 8 + rr;
        int g = batch * NL + r;
        const unsigned short* nb = nbr + (size_t)g * NBS;
        short8 I = *(const short8*)nb;                  // [cnt, e0..e6]
        int cnt = (int)(unsigned short)I[0];
        int mx = cnt;
        mx = max(mx, __shfl_xor(mx, 16));
        mx = max(mx, __shfl_xor(mx, 32));
        float a0 = 0.f, a1 = 0.f;
        #pragma unroll
        for (int i = 1; i < 8; ++i) {
            int j = (int)(unsigned short)I[i];
            unsigned u = Ysm32[j * YW + cw];
            a0 += __builtin_bit_cast(float, u << 16);
            a1 += __builtin_bit_cast(float, u & 0xffff0000u);
        }
        for (int t = 8; t < mx; t += 8) {
            if (t < cnt) {                              // quarter-uniform predicate
                short8 I2 = *(const short8*)(nb + t);
                #pragma unroll
                for (int i = 0; i < 8; ++i) {
                    int j = (int)(unsigned short)I2[i];
                    unsigned u = Ysm32[j * YW + cw];
                    a0 += __builtin_bit_cast(float, u << 16);
                    a1 += __builtin_bit_cast(float, u & 0xffff0000u);
                }
            }
        }
        unsigned uS = Ysm32[r * YW + cw];
        float di = dinv[g];
        float h0 = fmaxf((a0 + __builtin_bit_cast(float, uS << 16) + 2.f * bv0) * di, 0.f);
        float h1 = fmaxf((a1 + __builtin_bit_cast(float, uS & 0xffff0000u) + 2.f * bv1) * di, 0.f);
        if (FINAL == 0) {
            ((unsigned*)x1b)[(size_t)g * 128 + sl * 16 + cw] =
                (unsigned)f2b(h0) | ((unsigned)f2b(h1) << 16);
        } else if (col < MEM) {
            float2 o; o.x = h0; o.y = h1;
            *(float2*)(outx + (size_t)g * MEM + col) = o;
        }
    }
    #undef STAGE
}

extern "C" void kernel_launch(void* const* d_in, const int* in_sizes, int n_in,
                              void* d_out, int out_size, void* d_ws, size_t ws_size,
                              hipStream_t stream) {
    const int*   words = (const int*)d_in[0];
    const int*   pos   = (const int*)d_in[1];
    const int*   ner   = (const int*)d_in[2];
    const float* adj   = (const float*)d_in[3];
    const float* embW  = (const float*)d_in[4];
    const float* posW  = (const float*)d_in[5];
    const float* nerW  = (const float*)d_in[6];
    const float* W0    = (const float*)d_in[7];
    const float* b0    = (const float*)d_in[8];
    const float* W1    = (const float*)d_in[9];
    const float* b1    = (const float*)d_in[10];
    float* out = (float*)d_out;

    char* ws = (char*)d_ws;
    size_t off = 0;
    short* x0b = (short*)(ws + off);        off += (size_t)NROWS * KP1 * 2;       // 25.2 MB
    short* W0p = (short*)(ws + off);        off += (size_t)NP * KP1 * 2;
    short* W1p = (short*)(ws + off);        off += (size_t)NP * NP * 2;
    short* X1b = (short*)(ws + off);        off += (size_t)NROWS * NP * 2;        // 16.8 MB
    float* dinv = (float*)(ws + off);       off += (size_t)NROWS * 4;
    float* rsum = (float*)(ws + off);       off += (size_t)NROWS * 4;
    unsigned* colnz = (unsigned*)(ws + off); off += (size_t)NROWS * 4;
    unsigned short* nbr = (unsigned short*)(ws + off); off += (size_t)NROWS * NBS * 2; // 17.8 MB

    prep_weights<<<(NP * KP1 + NP * NP + 255) / 256, 256, 0, stream>>>(W0, W1, W0p, W1p, colnz);
    embed_kernel<<<NROWS / 8, 384, 0, stream>>>(words, pos, ner, embW, posW, nerW, x0b);
    adjrow_kernel<<<NROWS / 4, 256, 0, stream>>>(adj, dinv, rsum, nbr, colnz);
    mask_kernel<<<NROWS / 256, 256, 0, stream>>>(rsum, colnz, out + OUT_X);

    const int ldsB = 2 * BUFB;   // 36,864 B (Ysm aliases buf0)
    fused_kernel<0><<<NB * 8, 512, ldsB, stream>>>(x0b, KP1, KP1 / 32, W0p, KP1,
                                                   nbr, dinv, b0, X1b, nullptr);
    fused_kernel<1><<<NB * 8, 512, ldsB, stream>>>(X1b, NP, NP / 32, W1p, NP,
                                                   nbr, dinv, b1, nullptr, out);
}

// Round 11
// 106.006 us; speedup vs baseline: 1.8328x; 1.1135x over previous
//
#include <hip/hip_runtime.h>
#include <hip/hip_bf16.h>
#include <stdint.h>

typedef __attribute__((ext_vector_type(8))) short short8;
typedef __attribute__((ext_vector_type(4))) float f32x4;

#define NB 128
#define NL 256
#define NROWS 32768        // B*L
#define IN_DIM 360
#define KP1 384            // padded K for layer-1 GEMM (permuted layout, see embed_kernel)
#define MEM 200
#define NP 256             // padded N
#define OUT_X (NROWS * MEM)
#define YTP 272            // Yt pitch in bf16: 544 B rows -> every access 16B-aligned

// Permuted K layout for x0/W0p (keeps every 8-col chunk single-table):
//   kp 0..299 emb | kp 304..333 pos | kp 336..365 ner | else zero

__device__ __forceinline__ unsigned short f2b(float f) {
    unsigned u = __builtin_bit_cast(unsigned, f);
    unsigned r = (u + 0x7FFFu + ((u >> 16) & 1u)) >> 16;
    return (unsigned short)r;
}

// ---------------- weight prep + colnz zero
__global__ void prep_weights(const float* __restrict__ W0, const float* __restrict__ W1,
                             short* __restrict__ W0p, short* __restrict__ W1p,
                             unsigned* __restrict__ colnz) {
    int idx = blockIdx.x * 256 + threadIdx.x;
    if (idx < NROWS) colnz[idx] = 0u;
    if (idx < NP * KP1) {
        int n = idx / KP1, kp = idx - n * KP1;
        float v = 0.f;
        if (n < MEM) {
            if (kp < 300)                   v = W0[n * IN_DIM + kp];
            else if (kp >= 304 && kp < 334) v = W0[n * IN_DIM + 300 + (kp - 304)];
            else if (kp >= 336 && kp < 366) v = W0[n * IN_DIM + 330 + (kp - 336)];
        }
        W0p[idx] = (short)f2b(v);
    } else {
        int i2 = idx - NP * KP1;
        if (i2 < NP * NP) {
            int n = i2 >> 8, k = i2 & 255;
            float v = (n < MEM && k < MEM) ? W1[n * MEM + k] : 0.f;
            W1p[i2] = (short)f2b(v);
        }
    }
}

// ---------------- embedding concat -> x0 bf16 [32768][384] (permuted K layout)
__global__ __launch_bounds__(384) void embed_kernel(
    const int* __restrict__ words, const int* __restrict__ pos, const int* __restrict__ ner,
    const float* __restrict__ embW, const float* __restrict__ posW,
    const float* __restrict__ nerW, short* __restrict__ x0b) {
    int t = threadIdx.x;
    int r = t / 48, c = t - r * 48;
    int row = blockIdx.x * 8 + r;
    float vals[8];
    #pragma unroll
    for (int i = 0; i < 8; ++i) vals[i] = 0.f;
    if (c < 37) {
        const float* src = embW + (size_t)words[row] * 300 + c * 8;
        float4 a = *(const float4*)src;
        float4 b = *(const float4*)(src + 4);
        vals[0] = a.x; vals[1] = a.y; vals[2] = a.z; vals[3] = a.w;
        vals[4] = b.x; vals[5] = b.y; vals[6] = b.z; vals[7] = b.w;
    } else if (c == 37) {
        const float* src = embW + (size_t)words[row] * 300 + 296;
        vals[0] = src[0]; vals[1] = src[1]; vals[2] = src[2]; vals[3] = src[3];
    } else if (c <= 41) {
        int k0 = c * 8 - 304;
        const float* src = posW + (size_t)pos[row] * 30 + k0;
        #pragma unroll
        for (int i = 0; i < 8; ++i) if (k0 + i < 30) vals[i] = src[i];
    } else if (c <= 45) {
        int k0 = c * 8 - 336;
        const float* src = nerW + (size_t)ner[row] * 30 + k0;
        #pragma unroll
        for (int i = 0; i < 8; ++i) if (k0 + i < 30) vals[i] = src[i];
    }
    short8 st;
    #pragma unroll
    for (int i = 0; i < 8; ++i) st[i] = (short)f2b(vals[i]);
    *(short8*)((unsigned short*)x0b + (size_t)row * KP1 + c * 8) = st;
}

// ---------------- adj row pass: rowsum/dinv, S = (A+I) as bf16 [B][256][256], colnz flags
// S values are exactly {0,1,2} -> bf16 exact. Diagonal add makes the fused MFMA compute
// adj@Y + Y in one contraction (no separate self-term).
__global__ void adjrow_kernel(const float* __restrict__ adj, float* __restrict__ dinv,
                              float* __restrict__ rsum, unsigned short* __restrict__ Sbf,
                              unsigned* __restrict__ colnz) {
    int row = blockIdx.x * 4 + (threadIdx.x >> 6);
    int lane = threadIdx.x & 63;
    const float4* ar = (const float4*)(adj + (size_t)row * NL);
    float4 v = ar[lane];
    float s = v.x + v.y + v.z + v.w;
    #pragma unroll
    for (int off = 32; off >= 1; off >>= 1) s += __shfl_xor(s, off);
    int rloc = row & 255;
    float d0 = v.x + ((lane * 4 + 0) == rloc ? 1.f : 0.f);
    float d1 = v.y + ((lane * 4 + 1) == rloc ? 1.f : 0.f);
    float d2 = v.z + ((lane * 4 + 2) == rloc ? 1.f : 0.f);
    float d3 = v.w + ((lane * 4 + 3) == rloc ? 1.f : 0.f);
    ushort4 st; st.x = f2b(d0); st.y = f2b(d1); st.z = f2b(d2); st.w = f2b(d3);
    *(ushort4*)(Sbf + (size_t)row * NL + lane * 4) = st;
    if (lane == 0) { rsum[row] = s; dinv[row] = 1.0f / (s + 1.0f); }
    unsigned* cz = colnz + ((row >> 8) << 8);
    if (v.x != 0.f) atomicOr(&cz[lane * 4 + 0], 1u);
    if (v.y != 0.f) atomicOr(&cz[lane * 4 + 1], 1u);
    if (v.z != 0.f) atomicOr(&cz[lane * 4 + 2], 1u);
    if (v.w != 0.f) atomicOr(&cz[lane * 4 + 3], 1u);
}

__global__ void mask_kernel(const float* __restrict__ rsum, const unsigned* __restrict__ colnz,
                            float* __restrict__ outm) {
    int r = blockIdx.x * 256 + threadIdx.x;
    outm[r] = (rsum[r] == 0.f && colnz[r] == 0u) ? 1.0f : 0.0f;
}

// ---------------- FUSED per-layer, all-MFMA:
// Phase 1: Y = X @ W^T (M=256 batch rows, N=32 col slice, K=lda), reg-staged single-buffer
//          LDS tiles At[256][32]+Bt[32][32] (XOR-swizzled), 8 waves x (32 rows x 32 cols).
// Phase 2a: acc frags -> Yt[32 cols][YTP] bf16 transposed (4 consecutive rows per 8B write).
// Phase 2b: Z^T = mfma(a=Yt rows (y-cols), b=S rows (out-rows)) over K=256 in 8 steps;
//           S tiles staged into the At region (same swizzle). D-frag: lane holds one out-row
//           (lr) x 4 consecutive cols -> coalescedable stores, per-lane scalar dinv.
// FINAL=0: write x1 bf16 [32768][256] (cols>=200 compute to 0); FINAL=1: f32 out [32768][200].
template <int FINAL>
__global__ __launch_bounds__(512) void fused_kernel(
    const short* __restrict__ A, int lda, int nkt,
    const short* __restrict__ Bp, int ldb,
    const unsigned short* __restrict__ Sbf,
    const float* __restrict__ dinv, const float* __restrict__ bias,
    short* __restrict__ x1b, float* __restrict__ outx) {
    extern __shared__ char smem[];
    short (*At)[32] = (short (*)[32])smem;              // [256][32] bf16 16K (phase2b: S tile)
    short (*Bt)[32] = (short (*)[32])(smem + 16384);    // [32][32] bf16 2K
    unsigned short* Yt = (unsigned short*)(smem + 18432); // [32][YTP] bf16, 17 KB

    int bi = blockIdx.x;
    int batch = bi & 127, sl = bi >> 7;                 // all 8 slices of a batch -> same XCD

    int tid = threadIdx.x;
    int lane = tid & 63, wid = tid >> 6;
    int lr = lane & 15, lc = lane >> 4;

    const short* Ab = A + (size_t)batch * NL * lda;
    const short* Bb = Bp + (size_t)sl * 32 * ldb;

    // staging slots: each thread owns chunks (r0s,c0s) and (r0s+128,c0s) of the 256x32 tile
    int r0s = tid >> 2, c0s = tid & 3;
    int r1s = r0s + 128;
    short* Asl0 = &At[r0s][(c0s ^ ((r0s >> 1) & 3)) * 8];
    short* Asl1 = &At[r1s][(c0s ^ ((r1s >> 1) & 3)) * 8];
    const short* Ap0 = Ab + (size_t)r0s * lda + c0s * 8;
    const short* Ap1 = Ab + (size_t)r1s * lda + c0s * 8;
    const short* Bpp = nullptr; short* Bsl = nullptr;
    if (tid < 128) {
        int br = tid >> 2, bc = tid & 3;
        Bsl = &Bt[br][(bc ^ ((br >> 1) & 3)) * 8];
        Bpp = Bb + (size_t)br * ldb + bc * 8;
    }

    f32x4 acc[2][2] = {};
    short8 aR0 = *(const short8*)Ap0;
    short8 aR1 = *(const short8*)Ap1;
    short8 bR; if (tid < 128) bR = *(const short8*)Bpp;

    for (int kt = 0; kt < nkt; ++kt) {
        __syncthreads();                                // prev frag reads done
        *(short8*)Asl0 = aR0;
        *(short8*)Asl1 = aR1;
        if (tid < 128) *(short8*)Bsl = bR;
        __syncthreads();
        if (kt + 1 < nkt) {                             // prefetch next K-tile under MFMA
            aR0 = *(const short8*)(Ap0 + (kt + 1) * 32);
            aR1 = *(const short8*)(Ap1 + (kt + 1) * 32);
            if (tid < 128) bR = *(const short8*)(Bpp + (kt + 1) * 32);
        }
        short8 af[2], bf[2];
        #pragma unroll
        for (int mi = 0; mi < 2; ++mi) {
            int row = wid * 32 + mi * 16 + lr;
            int cs = lc ^ ((row >> 1) & 3);
            af[mi] = *(const short8*)&At[row][cs * 8];
        }
        #pragma unroll
        for (int ni = 0; ni < 2; ++ni) {
            int row = ni * 16 + lr;
            int cs = lc ^ ((row >> 1) & 3);
            bf[ni] = *(const short8*)&Bt[row][cs * 8];
        }
        #pragma unroll
        for (int mi = 0; mi < 2; ++mi)
            #pragma unroll
            for (int ni = 0; ni < 2; ++ni)
                acc[mi][ni] = __builtin_amdgcn_mfma_f32_16x16x32_bf16(af[mi], bf[ni], acc[mi][ni], 0, 0, 0);
    }

    // S prefetch for phase 2b (independent global loads; same slot geometry, 256x32 tiles)
    const short* Sb = (const short*)(Sbf + (size_t)batch * NL * NL);
    const short* Sp0 = Sb + (size_t)r0s * NL + c0s * 8;
    const short* Sp1 = Sb + (size_t)r1s * NL + c0s * 8;
    short8 sR0 = *(const short8*)Sp0;
    short8 sR1 = *(const short8*)Sp1;

    // Phase 2a: acc -> Yt transposed (col-major rows). 4 consecutive batch-rows per 8B write.
    #pragma unroll
    for (int mi = 0; mi < 2; ++mi)
        #pragma unroll
        for (int ni = 0; ni < 2; ++ni) {
            f32x4 v = acc[mi][ni];
            ushort4 st; st.x = f2b(v[0]); st.y = f2b(v[1]); st.z = f2b(v[2]); st.w = f2b(v[3]);
            int col = ni * 16 + lr;                     // y-col within slice (0..31)
            int row0 = wid * 32 + mi * 16 + lc * 4;     // batch row
            *(ushort4*)(Yt + (size_t)col * YTP + row0) = st;
        }

    // Phase 2b: Zt = Yt(a) x S(b): acc2[mi][ni], K=256 over 8 tiles of 32.
    f32x4 acc2[2][2] = {};
    for (int kt = 0; kt < 8; ++kt) {
        __syncthreads();                                // kt0: phase-1 reads done + Yt visible
        *(short8*)Asl0 = sR0;                           // S tile into At region
        *(short8*)Asl1 = sR1;
        __syncthreads();
        if (kt + 1 < 8) {
            sR0 = *(const short8*)(Sp0 + (kt + 1) * 32);
            sR1 = *(const short8*)(Sp1 + (kt + 1) * 32);
        }
        short8 ay[2], bs[2];
        #pragma unroll
        for (int mi = 0; mi < 2; ++mi)                  // a = Y^T: row = y-col, k-contiguous
            ay[mi] = *(const short8*)(Yt + (size_t)(mi * 16 + lr) * YTP + kt * 32 + lc * 8);
        #pragma unroll
        for (int ni = 0; ni < 2; ++ni) {                // b = S rows (out-rows), swizzled tile
            int row = wid * 32 + ni * 16 + lr;
            int cs = lc ^ ((row >> 1) & 3);
            bs[ni] = *(const short8*)&At[row][cs * 8];
        }
        #pragma unroll
        for (int mi = 0; mi < 2; ++mi)
            #pragma unroll
            for (int ni = 0; ni < 2; ++ni)
                acc2[mi][ni] = __builtin_amdgcn_mfma_f32_16x16x32_bf16(ay[mi], bs[ni], acc2[mi][ni], 0, 0, 0);
    }

    // Epilogue: D[ycol][outrow]: lane holds outrow = lr (fixed), ycols = lc*4 + r (4 consec).
    #pragma unroll
    for (int ni = 0; ni < 2; ++ni) {
        int g = batch * NL + wid * 32 + ni * 16 + lr;   // global output row
        float di = dinv[g];
        #pragma unroll
        for (int mi = 0; mi < 2; ++mi) {
            int col0 = sl * 32 + mi * 16 + lc * 4;      // global col (multiple of 4)
            float4 bv;
            if (col0 < MEM) bv = *(const float4*)(bias + col0);
            else { bv.x = 0.f; bv.y = 0.f; bv.z = 0.f; bv.w = 0.f; }
            f32x4 z = acc2[mi][ni];
            float h0 = fmaxf((z[0] + 2.f * bv.x) * di, 0.f);
            float h1 = fmaxf((z[1] + 2.f * bv.y) * di, 0.f);
            float h2 = fmaxf((z[2] + 2.f * bv.z) * di, 0.f);
            float h3 = fmaxf((z[3] + 2.f * bv.w) * di, 0.f);
            if (FINAL == 0) {
                ushort4 st; st.x = f2b(h0); st.y = f2b(h1); st.z = f2b(h2); st.w = f2b(h3);
                *(ushort4*)((unsigned short*)x1b + (size_t)g * NP + col0) = st;
            } else if (col0 < MEM) {
                float4 o; o.x = h0; o.y = h1; o.z = h2; o.w = h3;
                *(float4*)(outx + (size_t)g * MEM + col0) = o;
            }
        }
    }
}

extern "C" void kernel_launch(void* const* d_in, const int* in_sizes, int n_in,
                              void* d_out, int out_size, void* d_ws, size_t ws_size,
                              hipStream_t stream) {
    const int*   words = (const int*)d_in[0];
    const int*   pos   = (const int*)d_in[1];
    const int*   ner   = (const int*)d_in[2];
    const float* adj   = (const float*)d_in[3];
    const float* embW  = (const float*)d_in[4];
    const float* posW  = (const float*)d_in[5];
    const float* nerW  = (const float*)d_in[6];
    const float* W0    = (const float*)d_in[7];
    const float* b0    = (const float*)d_in[8];
    const float* W1    = (const float*)d_in[9];
    const float* b1    = (const float*)d_in[10];
    float* out = (float*)d_out;

    char* ws = (char*)d_ws;
    size_t off = 0;
    short* x0b = (short*)(ws + off);        off += (size_t)NROWS * KP1 * 2;       // 25.2 MB
    short* W0p = (short*)(ws + off);        off += (size_t)NP * KP1 * 2;
    short* W1p = (short*)(ws + off);        off += (size_t)NP * NP * 2;
    short* X1b = (short*)(ws + off);        off += (size_t)NROWS * NP * 2;        // 16.8 MB
    float* dinv = (float*)(ws + off);       off += (size_t)NROWS * 4;
    float* rsum = (float*)(ws + off);       off += (size_t)NROWS * 4;
    unsigned* colnz = (unsigned*)(ws + off); off += (size_t)NROWS * 4;
    unsigned short* Sbf = (unsigned short*)(ws + off); off += (size_t)NROWS * NL * 2; // 16.8 MB

    prep_weights<<<(NP * KP1 + NP * NP + 255) / 256, 256, 0, stream>>>(W0, W1, W0p, W1p, colnz);
    embed_kernel<<<NROWS / 8, 384, 0, stream>>>(words, pos, ner, embW, posW, nerW, x0b);
    adjrow_kernel<<<NROWS / 4, 256, 0, stream>>>(adj, dinv, rsum, Sbf, colnz);
    mask_kernel<<<NROWS / 256, 256, 0, stream>>>(rsum, colnz, out + OUT_X);

    const int ldsB = 18432 + 32 * YTP * 2;   // 35,840 B
    fused_kernel<0><<<NB * 8, 512, ldsB, stream>>>(x0b, KP1, KP1 / 32, W0p, KP1,
                                                   Sbf, dinv, b0, X1b, nullptr);
    fused_kernel<1><<<NB * 8, 512, ldsB, stream>>>(X1b, NP, NP / 32, W1p, NP,
                                                   Sbf, dinv, b1, nullptr, out);
}

// Round 12
// 88.681 us; speedup vs baseline: 2.1908x; 1.1954x over previous
//
#include <hip/hip_runtime.h>
#include <hip/hip_bf16.h>
#include <stdint.h>

typedef __attribute__((ext_vector_type(8))) short short8;
typedef __attribute__((ext_vector_type(4))) float f32x4;

#define NB 128
#define NL 256
#define NROWS 32768        // B*L
#define IN_DIM 360
#define KP1 384            // padded K for layer-1 GEMM (permuted layout, see embed_kernel)
#define MEM 200
#define NP 256             // padded N
#define OUT_X (NROWS * MEM)
#define YTP 264            // Yt pitch in bf16 (528 B rows: 16B-aligned, 2-way bank pattern)
#define BUFSZ 20480        // one staging buffer: At 16K + Bt 4K
#define YTOFF 40960        // Yt offset in smem

// Permuted K layout for x0/W0p (keeps every 8-col chunk single-table):
//   kp 0..299 emb | kp 304..333 pos | kp 336..365 ner | else zero

__device__ __forceinline__ unsigned short f2b(float f) {
    unsigned u = __builtin_bit_cast(unsigned, f);
    unsigned r = (u + 0x7FFFu + ((u >> 16) & 1u)) >> 16;
    return (unsigned short)r;
}

// ---------------- weight prep + colnz zero
__global__ void prep_weights(const float* __restrict__ W0, const float* __restrict__ W1,
                             short* __restrict__ W0p, short* __restrict__ W1p,
                             unsigned* __restrict__ colnz) {
    int idx = blockIdx.x * 256 + threadIdx.x;
    if (idx < NROWS) colnz[idx] = 0u;
    if (idx < NP * KP1) {
        int n = idx / KP1, kp = idx - n * KP1;
        float v = 0.f;
        if (n < MEM) {
            if (kp < 300)                   v = W0[n * IN_DIM + kp];
            else if (kp >= 304 && kp < 334) v = W0[n * IN_DIM + 300 + (kp - 304)];
            else if (kp >= 336 && kp < 366) v = W0[n * IN_DIM + 330 + (kp - 336)];
        }
        W0p[idx] = (short)f2b(v);
    } else {
        int i2 = idx - NP * KP1;
        if (i2 < NP * NP) {
            int n = i2 >> 8, k = i2 & 255;
            float v = (n < MEM && k < MEM) ? W1[n * MEM + k] : 0.f;
            W1p[i2] = (short)f2b(v);
        }
    }
}

// ---------------- embedding concat -> x0 bf16 [32768][384] (permuted K layout)
__global__ __launch_bounds__(384) void embed_kernel(
    const int* __restrict__ words, const int* __restrict__ pos, const int* __restrict__ ner,
    const float* __restrict__ embW, const float* __restrict__ posW,
    const float* __restrict__ nerW, short* __restrict__ x0b) {
    int t = threadIdx.x;
    int r = t / 48, c = t - r * 48;
    int row = blockIdx.x * 8 + r;
    float vals[8];
    #pragma unroll
    for (int i = 0; i < 8; ++i) vals[i] = 0.f;
    if (c < 37) {
        const float* src = embW + (size_t)words[row] * 300 + c * 8;
        float4 a = *(const float4*)src;
        float4 b = *(const float4*)(src + 4);
        vals[0] = a.x; vals[1] = a.y; vals[2] = a.z; vals[3] = a.w;
        vals[4] = b.x; vals[5] = b.y; vals[6] = b.z; vals[7] = b.w;
    } else if (c == 37) {
        const float* src = embW + (size_t)words[row] * 300 + 296;
        vals[0] = src[0]; vals[1] = src[1]; vals[2] = src[2]; vals[3] = src[3];
    } else if (c <= 41) {
        int k0 = c * 8 - 304;
        const float* src = posW + (size_t)pos[row] * 30 + k0;
        #pragma unroll
        for (int i = 0; i < 8; ++i) if (k0 + i < 30) vals[i] = src[i];
    } else if (c <= 45) {
        int k0 = c * 8 - 336;
        const float* src = nerW + (size_t)ner[row] * 30 + k0;
        #pragma unroll
        for (int i = 0; i < 8; ++i) if (k0 + i < 30) vals[i] = src[i];
    }
    short8 st;
    #pragma unroll
    for (int i = 0; i < 8; ++i) st[i] = (short)f2b(vals[i]);
    *(short8*)((unsigned short*)x0b + (size_t)row * KP1 + c * 8) = st;
}

// ---------------- adj row pass: rowsum/dinv, S = (A+I) bf16 [B][256][256], colnz flags
__global__ void adjrow_kernel(const float* __restrict__ adj, float* __restrict__ dinv,
                              float* __restrict__ rsum, unsigned short* __restrict__ Sbf,
                              unsigned* __restrict__ colnz) {
    int row = blockIdx.x * 4 + (threadIdx.x >> 6);
    int lane = threadIdx.x & 63;
    const float4* ar = (const float4*)(adj + (size_t)row * NL);
    float4 v = ar[lane];
    float s = v.x + v.y + v.z + v.w;
    #pragma unroll
    for (int off = 32; off >= 1; off >>= 1) s += __shfl_xor(s, off);
    int rloc = row & 255;
    float d0 = v.x + ((lane * 4 + 0) == rloc ? 1.f : 0.f);
    float d1 = v.y + ((lane * 4 + 1) == rloc ? 1.f : 0.f);
    float d2 = v.z + ((lane * 4 + 2) == rloc ? 1.f : 0.f);
    float d3 = v.w + ((lane * 4 + 3) == rloc ? 1.f : 0.f);
    ushort4 st; st.x = f2b(d0); st.y = f2b(d1); st.z = f2b(d2); st.w = f2b(d3);
    *(ushort4*)(Sbf + (size_t)row * NL + lane * 4) = st;
    if (lane == 0) { rsum[row] = s; dinv[row] = 1.0f / (s + 1.0f); }
    unsigned* cz = colnz + ((row >> 8) << 8);
    if (v.x != 0.f) atomicOr(&cz[lane * 4 + 0], 1u);
    if (v.y != 0.f) atomicOr(&cz[lane * 4 + 1], 1u);
    if (v.z != 0.f) atomicOr(&cz[lane * 4 + 2], 1u);
    if (v.w != 0.f) atomicOr(&cz[lane * 4 + 3], 1u);
}

__global__ void mask_kernel(const float* __restrict__ rsum, const unsigned* __restrict__ colnz,
                            float* __restrict__ outm) {
    int r = blockIdx.x * 256 + threadIdx.x;
    outm[r] = (rsum[r] == 0.f && colnz[r] == 0u) ? 1.0f : 0.0f;
}

// ---------------- FUSED per-layer, all-MFMA, double-buffered:
// N-slice 64 (grid 512 = 2 blocks/CU); 8 waves 4x2, wave tile 64x32, acc[4][2].
// Phase 1: Y = X@W^T, LDS dbuf (buf0/buf1 = At[256][32]+Bt[64][32]), 1 barrier/K-tile,
//          reg prefetch 2 tiles deep; S t0/t1 loads issued in the loop tail.
// Phase 2a: acc -> Yt[64][YTP] bf16 transposed.
// Phase 2b: Zt = mfma(a=Yt, b=S) K=256 in 8 tiles, S ping-pong buf0.At/buf1.At,
//           1 barrier/tile, fully unrolled.
template <int FINAL>
__global__ __launch_bounds__(512, 4) void fused_kernel(
    const short* __restrict__ A, int lda, int nkt,
    const short* __restrict__ Bp, int ldb,
    const unsigned short* __restrict__ Sbf,
    const float* __restrict__ dinv, const float* __restrict__ bias,
    short* __restrict__ x1b, float* __restrict__ outx) {
    extern __shared__ char smem[];
    unsigned short* Yt = (unsigned short*)(smem + YTOFF);   // [64][YTP] bf16

    int bi = blockIdx.x;
    int batch = bi & 127, sl = bi >> 7;                 // 4 slices of a batch -> same XCD

    int tid = threadIdx.x;
    int lane = tid & 63, wid = tid >> 6;
    int wr = wid >> 1, wc = wid & 1;                    // 4 x 2 wave grid
    int lr = lane & 15, lc = lane >> 4;

    const short* Ab = A + (size_t)batch * NL * lda;
    const short* Bb = Bp + (size_t)sl * 64 * ldb;
    const short* Sb = (const short*)(Sbf + (size_t)batch * NL * NL);

    // staging slots (byte offsets within a buffer)
    int r0s = tid >> 2, c0s = tid & 3;
    int r1s = r0s + 128;
    int offA0 = r0s * 64 + (c0s ^ ((r0s >> 1) & 3)) * 16;
    int offA1 = r1s * 64 + (c0s ^ ((r1s >> 1) & 3)) * 16;
    const short* Ap0 = Ab + (size_t)r0s * lda + c0s * 8;
    const short* Ap1 = Ab + (size_t)r1s * lda + c0s * 8;
    const short* Sp0 = Sb + (size_t)r0s * NL + c0s * 8;
    const short* Sp1 = Sb + (size_t)r1s * NL + c0s * 8;
    int offB = 0; const short* Bpp = nullptr;
    if (tid < 256) {
        int br = tid >> 2, bc = tid & 3;
        offB = 16384 + br * 64 + (bc ^ ((br >> 1) & 3)) * 16;
        Bpp = Bb + (size_t)br * ldb + bc * 8;
    }

    f32x4 acc[4][2] = {};
    // prologue: tile 0 -> buf0; load tile 1
    short8 aR0 = *(const short8*)Ap0;
    short8 aR1 = *(const short8*)Ap1;
    short8 bR; if (tid < 256) bR = *(const short8*)Bpp;
    *(short8*)(smem + offA0) = aR0;
    *(short8*)(smem + offA1) = aR1;
    if (tid < 256) *(short8*)(smem + offB) = bR;
    aR0 = *(const short8*)(Ap0 + 32);
    aR1 = *(const short8*)(Ap1 + 32);
    if (tid < 256) bR = *(const short8*)(Bpp + 32);
    __syncthreads();

    short8 sA0, sA1, sB0, sB1;                          // S t0/t1 regs
    for (int kt = 0; kt < nkt; ++kt) {
        char* base_ = smem + (kt & 1) * BUFSZ;
        short8 af[4], bf[2];
        #pragma unroll
        for (int mi = 0; mi < 4; ++mi) {
            int row = wr * 64 + mi * 16 + lr;
            int cs = lc ^ ((row >> 1) & 3);
            af[mi] = *(const short8*)(base_ + row * 64 + cs * 16);
        }
        #pragma unroll
        for (int ni = 0; ni < 2; ++ni) {
            int row = wc * 32 + ni * 16 + lr;
            int cs = lc ^ ((row >> 1) & 3);
            bf[ni] = *(const short8*)(base_ + 16384 + row * 64 + cs * 16);
        }
        if (kt + 1 < nkt) {                             // write tile kt+1 to other buffer
            char* nb_ = smem + ((kt + 1) & 1) * BUFSZ;
            *(short8*)(nb_ + offA0) = aR0;
            *(short8*)(nb_ + offA1) = aR1;
            if (tid < 256) *(short8*)(nb_ + offB) = bR;
        }
        if (kt + 2 < nkt) {                             // prefetch tile kt+2
            aR0 = *(const short8*)(Ap0 + (kt + 2) * 32);
            aR1 = *(const short8*)(Ap1 + (kt + 2) * 32);
            if (tid < 256) bR = *(const short8*)(Bpp + (kt + 2) * 32);
        } else if (kt + 2 == nkt) {                     // tail: S t0
            sA0 = *(const short8*)Sp0;
            sA1 = *(const short8*)Sp1;
        } else if (kt + 2 == nkt + 1) {                 // tail: S t1
            sB0 = *(const short8*)(Sp0 + 32);
            sB1 = *(const short8*)(Sp1 + 32);
        }
        #pragma unroll
        for (int mi = 0; mi < 4; ++mi)
            #pragma unroll
            for (int ni = 0; ni < 2; ++ni)
                acc[mi][ni] = __builtin_amdgcn_mfma_f32_16x16x32_bf16(af[mi], bf[ni], acc[mi][ni], 0, 0, 0);
        __syncthreads();
    }

    // Phase 2a: acc -> Yt transposed (col = y-col, 4 consecutive batch rows per 8B write)
    #pragma unroll
    for (int mi = 0; mi < 4; ++mi)
        #pragma unroll
        for (int ni = 0; ni < 2; ++ni) {
            f32x4 v = acc[mi][ni];
            ushort4 st; st.x = f2b(v[0]); st.y = f2b(v[1]); st.z = f2b(v[2]); st.w = f2b(v[3]);
            int col = wc * 32 + ni * 16 + lr;
            int row0 = wr * 64 + mi * 16 + lc * 4;
            *(ushort4*)(Yt + (size_t)col * YTP + row0) = st;
        }
    // stage S t0 -> buf0.At (buf0 free: last read at kt=nkt-2, barrier passed); prefetch t2
    *(short8*)(smem + offA0) = sA0;
    *(short8*)(smem + offA1) = sA1;
    sA0 = *(const short8*)(Sp0 + 64);
    sA1 = *(const short8*)(Sp1 + 64);
    __syncthreads();                                    // Yt + S t0 visible

    // Phase 2b: Zt = Yt x S, 8 K-tiles, ping-pong staging, 1 barrier/tile
    f32x4 acc2[4][2] = {};
    #pragma unroll
    for (int kt = 0; kt < 8; ++kt) {
        char* base_ = smem + (kt & 1) * BUFSZ;
        short8 ay[4], bs[2];
        #pragma unroll
        for (int mi = 0; mi < 4; ++mi)                  // a = Y^T rows (y-cols), k-contig
            ay[mi] = *(const short8*)(Yt + (size_t)(mi * 16 + lr) * YTP + kt * 32 + lc * 8);
        #pragma unroll
        for (int ni = 0; ni < 2; ++ni) {                // b = S rows (out-rows), swizzled
            int row = wid * 32 + ni * 16 + lr;
            int cs = lc ^ ((row >> 1) & 3);
            bs[ni] = *(const short8*)(base_ + row * 64 + cs * 16);
        }
        if (kt + 1 < 8) {                               // write tile kt+1; reload that set
            char* nb_ = smem + ((kt + 1) & 1) * BUFSZ;
            if ((kt & 1) == 0) {
                *(short8*)(nb_ + offA0) = sB0;
                *(short8*)(nb_ + offA1) = sB1;
                if (kt + 3 < 8) {
                    sB0 = *(const short8*)(Sp0 + (kt + 3) * 32);
                    sB1 = *(const short8*)(Sp1 + (kt + 3) * 32);
                }
            } else {
                *(short8*)(nb_ + offA0) = sA0;
                *(short8*)(nb_ + offA1) = sA1;
                if (kt + 3 < 8) {
                    sA0 = *(const short8*)(Sp0 + (kt + 3) * 32);
                    sA1 = *(const short8*)(Sp1 + (kt + 3) * 32);
                }
            }
        }
        #pragma unroll
        for (int mi = 0; mi < 4; ++mi)
            #pragma unroll
            for (int ni = 0; ni < 2; ++ni)
                acc2[mi][ni] = __builtin_amdgcn_mfma_f32_16x16x32_bf16(ay[mi], bs[ni], acc2[mi][ni], 0, 0, 0);
        if (kt + 1 < 8) __syncthreads();
    }

    // Epilogue: lane holds outrow lr (fixed) x 4 consecutive y-cols per frag
    #pragma unroll
    for (int ni = 0; ni < 2; ++ni) {
        int g = batch * NL + wid * 32 + ni * 16 + lr;   // global output row
        float di = dinv[g];
        #pragma unroll
        for (int mi = 0; mi < 4; ++mi) {
            int col0 = sl * 64 + mi * 16 + lc * 4;      // global col (multiple of 4)
            float4 bv;
            if (col0 < MEM) bv = *(const float4*)(bias + col0);
            else { bv.x = 0.f; bv.y = 0.f; bv.z = 0.f; bv.w = 0.f; }
            f32x4 z = acc2[mi][ni];
            float h0 = fmaxf((z[0] + 2.f * bv.x) * di, 0.f);
            float h1 = fmaxf((z[1] + 2.f * bv.y) * di, 0.f);
            float h2 = fmaxf((z[2] + 2.f * bv.z) * di, 0.f);
            float h3 = fmaxf((z[3] + 2.f * bv.w) * di, 0.f);
            if (FINAL == 0) {
                ushort4 st; st.x = f2b(h0); st.y = f2b(h1); st.z = f2b(h2); st.w = f2b(h3);
                *(ushort4*)((unsigned short*)x1b + (size_t)g * NP + col0) = st;
            } else if (col0 < MEM) {
                float4 o; o.x = h0; o.y = h1; o.z = h2; o.w = h3;
                *(float4*)(outx + (size_t)g * MEM + col0) = o;
            }
        }
    }
}

extern "C" void kernel_launch(void* const* d_in, const int* in_sizes, int n_in,
                              void* d_out, int out_size, void* d_ws, size_t ws_size,
                              hipStream_t stream) {
    const int*   words = (const int*)d_in[0];
    const int*   pos   = (const int*)d_in[1];
    const int*   ner   = (const int*)d_in[2];
    const float* adj   = (const float*)d_in[3];
    const float* embW  = (const float*)d_in[4];
    const float* posW  = (const float*)d_in[5];
    const float* nerW  = (const float*)d_in[6];
    const float* W0    = (const float*)d_in[7];
    const float* b0    = (const float*)d_in[8];
    const float* W1    = (const float*)d_in[9];
    const float* b1    = (const float*)d_in[10];
    float* out = (float*)d_out;

    char* ws = (char*)d_ws;
    size_t off = 0;
    short* x0b = (short*)(ws + off);        off += (size_t)NROWS * KP1 * 2;       // 25.2 MB
    short* W0p = (short*)(ws + off);        off += (size_t)NP * KP1 * 2;
    short* W1p = (short*)(ws + off);        off += (size_t)NP * NP * 2;
    short* X1b = (short*)(ws + off);        off += (size_t)NROWS * NP * 2;        // 16.8 MB
    float* dinv = (float*)(ws + off);       off += (size_t)NROWS * 4;
    float* rsum = (float*)(ws + off);       off += (size_t)NROWS * 4;
    unsigned* colnz = (unsigned*)(ws + off); off += (size_t)NROWS * 4;
    unsigned short* Sbf = (unsigned short*)(ws + off); off += (size_t)NROWS * NL * 2; // 16.8 MB

    prep_weights<<<(NP * KP1 + NP * NP + 255) / 256, 256, 0, stream>>>(W0, W1, W0p, W1p, colnz);
    embed_kernel<<<NROWS / 8, 384, 0, stream>>>(words, pos, ner, embW, posW, nerW, x0b);
    adjrow_kernel<<<NROWS / 4, 256, 0, stream>>>(adj, dinv, rsum, Sbf, colnz);
    mask_kernel<<<NROWS / 256, 256, 0, stream>>>(rsum, colnz, out + OUT_X);

    const int ldsB = YTOFF + 64 * YTP * 2;   // 74,752 B
    fused_kernel<0><<<NB * 4, 512, ldsB, stream>>>(x0b, KP1, KP1 / 32, W0p, KP1,
                                                   Sbf, dinv, b0, X1b, nullptr);
    fused_kernel<1><<<NB * 4, 512, ldsB, stream>>>(X1b, NP, NP / 32, W1p, NP,
                                                   Sbf, dinv, b1, nullptr, out);
}

// Round 13
// 82.790 us; speedup vs baseline: 2.3468x; 1.0712x over previous
//
#include <hip/hip_runtime.h>
#include <hip/hip_bf16.h>
#include <stdint.h>

typedef __attribute__((ext_vector_type(8))) short short8;
typedef __attribute__((ext_vector_type(4))) float f32x4;

#define NB 128
#define NL 256
#define NROWS 32768        // B*L
#define IN_DIM 360
#define KP1 384            // padded K for layer-1 GEMM (permuted layout)
#define MEM 200
#define NP 256             // padded N
#define OUT_X (NROWS * MEM)
#define YTP 264            // Yt pitch in bf16 (528 B rows: 16B-aligned, 2-way bank pattern)
#define BUFSZ 20480        // one staging buffer: At 16K + Bt 4K
#define YTOFF 40960        // Yt offset in smem

// Permuted K layout for x/W0p (keeps every 8-col chunk single-table):
//   kp 0..299 emb | kp 304..333 pos | kp 336..365 ner | else zero
// Chunk id c = kp/8: 0..36 emb-full | 37 emb-tail(296-299) | 38..41 pos | 42..45 ner | 46,47 zero

__device__ __forceinline__ unsigned short f2b(float f) {
    unsigned u = __builtin_bit_cast(unsigned, f);
    unsigned r = (u + 0x7FFFu + ((u >> 16) & 1u)) >> 16;
    return (unsigned short)r;
}

// gather one 8-col chunk of the (permuted) embedding row as bf16
__device__ __forceinline__ short8 gather_chunk(int chunk, const float* __restrict__ er,
                                               const float* __restrict__ pr,
                                               const float* __restrict__ nr) {
    float v[8];
    if (chunk < 37) {                                   // emb, 16B-aligned (stride 1200 B)
        const float* s = er + chunk * 8;
        float4 a = *(const float4*)s;
        float4 b = *(const float4*)(s + 4);
        v[0] = a.x; v[1] = a.y; v[2] = a.z; v[3] = a.w;
        v[4] = b.x; v[5] = b.y; v[6] = b.z; v[7] = b.w;
    } else if (chunk == 37) {                           // emb tail 296..299 + pad
        float4 a = *(const float4*)(er + 296);
        v[0] = a.x; v[1] = a.y; v[2] = a.z; v[3] = a.w;
        v[4] = 0.f; v[5] = 0.f; v[6] = 0.f; v[7] = 0.f;
    } else if (chunk <= 41) {                           // pos (stride 120 B: scalar, guarded)
        int k0 = chunk * 8 - 304;
        #pragma unroll
        for (int i = 0; i < 8; ++i) v[i] = (k0 + i < 30) ? pr[k0 + i] : 0.f;
    } else if (chunk <= 45) {                           // ner
        int k0 = chunk * 8 - 336;
        #pragma unroll
        for (int i = 0; i < 8; ++i) v[i] = (k0 + i < 30) ? nr[k0 + i] : 0.f;
    } else {
        #pragma unroll
        for (int i = 0; i < 8; ++i) v[i] = 0.f;
    }
    short8 r;
    #pragma unroll
    for (int i = 0; i < 8; ++i) r[i] = (short)f2b(v[i]);
    return r;
}

// ---------------- weight prep + colnz zero
__global__ void prep_weights(const float* __restrict__ W0, const float* __restrict__ W1,
                             short* __restrict__ W0p, short* __restrict__ W1p,
                             unsigned* __restrict__ colnz) {
    int idx = blockIdx.x * 256 + threadIdx.x;
    if (idx < NROWS) colnz[idx] = 0u;
    if (idx < NP * KP1) {
        int n = idx / KP1, kp = idx - n * KP1;
        float v = 0.f;
        if (n < MEM) {
            if (kp < 300)                   v = W0[n * IN_DIM + kp];
            else if (kp >= 304 && kp < 334) v = W0[n * IN_DIM + 300 + (kp - 304)];
            else if (kp >= 336 && kp < 366) v = W0[n * IN_DIM + 330 + (kp - 336)];
        }
        W0p[idx] = (short)f2b(v);
    } else {
        int i2 = idx - NP * KP1;
        if (i2 < NP * NP) {
            int n = i2 >> 8, k = i2 & 255;
            float v = (n < MEM && k < MEM) ? W1[n * MEM + k] : 0.f;
            W1p[i2] = (short)f2b(v);
        }
    }
}

// ---------------- adj row pass: rowsum/dinv, S = (A+I) bf16 [B][256][256], colnz flags
__global__ void adjrow_kernel(const float* __restrict__ adj, float* __restrict__ dinv,
                              float* __restrict__ rsum, unsigned short* __restrict__ Sbf,
                              unsigned* __restrict__ colnz) {
    int row = blockIdx.x * 4 + (threadIdx.x >> 6);
    int lane = threadIdx.x & 63;
    const float4* ar = (const float4*)(adj + (size_t)row * NL);
    float4 v = ar[lane];
    float s = v.x + v.y + v.z + v.w;
    #pragma unroll
    for (int off = 32; off >= 1; off >>= 1) s += __shfl_xor(s, off);
    int rloc = row & 255;
    float d0 = v.x + ((lane * 4 + 0) == rloc ? 1.f : 0.f);
    float d1 = v.y + ((lane * 4 + 1) == rloc ? 1.f : 0.f);
    float d2 = v.z + ((lane * 4 + 2) == rloc ? 1.f : 0.f);
    float d3 = v.w + ((lane * 4 + 3) == rloc ? 1.f : 0.f);
    ushort4 st; st.x = f2b(d0); st.y = f2b(d1); st.z = f2b(d2); st.w = f2b(d3);
    *(ushort4*)(Sbf + (size_t)row * NL + lane * 4) = st;
    if (lane == 0) { rsum[row] = s; dinv[row] = 1.0f / (s + 1.0f); }
    unsigned* cz = colnz + ((row >> 8) << 8);
    if (v.x != 0.f) atomicOr(&cz[lane * 4 + 0], 1u);
    if (v.y != 0.f) atomicOr(&cz[lane * 4 + 1], 1u);
    if (v.z != 0.f) atomicOr(&cz[lane * 4 + 2], 1u);
    if (v.w != 0.f) atomicOr(&cz[lane * 4 + 3], 1u);
}

__global__ void mask_kernel(const float* __restrict__ rsum, const unsigned* __restrict__ colnz,
                            float* __restrict__ outm) {
    int r = blockIdx.x * 256 + threadIdx.x;
    outm[r] = (rsum[r] == 0.f && colnz[r] == 0u) ? 1.0f : 0.0f;
}

// ---------------- FUSED per-layer, all-MFMA, double-buffered.
// FINAL=0: A-tile staging IS the embedding gather (no x0 buffer exists at all).
// FINAL=1: A-tile staged from X1b.
// N-slice 64 (grid 512 = 2 blocks/CU); 8 waves 4x2, wave tile 64x32, acc[4][2].
// Phase 1: Y = X@W^T, LDS dbuf, 1 barrier/K-tile, reg prefetch 2 tiles deep; S t0/t1 in tail.
// Phase 2a: acc -> Yt[64][YTP] bf16 transposed.
// Phase 2b: Zt = mfma(a=Yt, b=S) K=256 in 8 tiles, S ping-pong, 1 barrier/tile, unrolled.
template <int FINAL>
__global__ __launch_bounds__(512, 4) void fused_kernel(
    const short* __restrict__ A, int lda, int nkt,
    const short* __restrict__ Bp, int ldb,
    const unsigned short* __restrict__ Sbf,
    const float* __restrict__ dinv, const float* __restrict__ bias,
    const int* __restrict__ words, const int* __restrict__ pos, const int* __restrict__ ner,
    const float* __restrict__ embW, const float* __restrict__ posW,
    const float* __restrict__ nerW,
    short* __restrict__ x1b, float* __restrict__ outx) {
    extern __shared__ char smem[];
    unsigned short* Yt = (unsigned short*)(smem + YTOFF);   // [64][YTP] bf16

    int bi = blockIdx.x;
    int batch = bi & 127, sl = bi >> 7;                 // 4 slices of a batch -> same XCD

    int tid = threadIdx.x;
    int lane = tid & 63, wid = tid >> 6;
    int wr = wid >> 1, wc = wid & 1;                    // 4 x 2 wave grid
    int lr = lane & 15, lc = lane >> 4;

    const short* Bb = Bp + (size_t)sl * 64 * ldb;
    const short* Sb = (const short*)(Sbf + (size_t)batch * NL * NL);

    // staging slots (byte offsets within a buffer)
    int r0s = tid >> 2, c0s = tid & 3;
    int r1s = r0s + 128;
    int offA0 = r0s * 64 + (c0s ^ ((r0s >> 1) & 3)) * 16;
    int offA1 = r1s * 64 + (c0s ^ ((r1s >> 1) & 3)) * 16;
    const short* Sp0 = Sb + (size_t)r0s * NL + c0s * 8;
    const short* Sp1 = Sb + (size_t)r1s * NL + c0s * 8;
    int offB = 0; const short* Bpp = nullptr;
    if (tid < 256) {
        int br = tid >> 2, bc = tid & 3;
        offB = 16384 + br * 64 + (bc ^ ((br >> 1) & 3)) * 16;
        Bpp = Bb + (size_t)br * ldb + bc * 8;
    }

    // A source: FINAL=0 -> per-row table pointers; FINAL=1 -> X1b pointers
    const short* Ap0 = nullptr; const short* Ap1 = nullptr;
    const float *er0 = nullptr, *pr0 = nullptr, *nr0 = nullptr;
    const float *er1 = nullptr, *pr1 = nullptr, *nr1 = nullptr;
    if (FINAL == 0) {
        int g0 = batch * NL + r0s, g1 = g0 + 128;
        er0 = embW + (size_t)words[g0] * 300;
        pr0 = posW + (size_t)pos[g0] * 30;
        nr0 = nerW + (size_t)ner[g0] * 30;
        er1 = embW + (size_t)words[g1] * 300;
        pr1 = posW + (size_t)pos[g1] * 30;
        nr1 = nerW + (size_t)ner[g1] * 30;
    } else {
        const short* Ab = A + (size_t)batch * NL * lda;
        Ap0 = Ab + (size_t)r0s * lda + c0s * 8;
        Ap1 = Ab + (size_t)r1s * lda + c0s * 8;
    }
    #define LOADA(kt, o0, o1) do {                                  \
        if (FINAL == 0) {                                           \
            int ch_ = (kt) * 4 + c0s;                               \
            (o0) = gather_chunk(ch_, er0, pr0, nr0);                \
            (o1) = gather_chunk(ch_, er1, pr1, nr1);                \
        } else {                                                    \
            (o0) = *(const short8*)(Ap0 + (kt) * 32);               \
            (o1) = *(const short8*)(Ap1 + (kt) * 32);               \
        }                                                           \
    } while (0)

    f32x4 acc[4][2] = {};
    // prologue: tile 0 -> buf0; load tile 1
    short8 aR0, aR1, bR;
    LOADA(0, aR0, aR1);
    if (tid < 256) bR = *(const short8*)Bpp;
    *(short8*)(smem + offA0) = aR0;
    *(short8*)(smem + offA1) = aR1;
    if (tid < 256) *(short8*)(smem + offB) = bR;
    LOADA(1, aR0, aR1);
    if (tid < 256) bR = *(const short8*)(Bpp + 32);
    __syncthreads();

    short8 sA0, sA1, sB0, sB1;                          // S t0/t1 regs
    for (int kt = 0; kt < nkt; ++kt) {
        char* base_ = smem + (kt & 1) * BUFSZ;
        short8 af[4], bf[2];
        #pragma unroll
        for (int mi = 0; mi < 4; ++mi) {
            int row = wr * 64 + mi * 16 + lr;
            int cs = lc ^ ((row >> 1) & 3);
            af[mi] = *(const short8*)(base_ + row * 64 + cs * 16);
        }
        #pragma unroll
        for (int ni = 0; ni < 2; ++ni) {
            int row = wc * 32 + ni * 16 + lr;
            int cs = lc ^ ((row >> 1) & 3);
            bf[ni] = *(const short8*)(base_ + 16384 + row * 64 + cs * 16);
        }
        if (kt + 1 < nkt) {                             // write tile kt+1 to other buffer
            char* nb_ = smem + ((kt + 1) & 1) * BUFSZ;
            *(short8*)(nb_ + offA0) = aR0;
            *(short8*)(nb_ + offA1) = aR1;
            if (tid < 256) *(short8*)(nb_ + offB) = bR;
        }
        if (kt + 2 < nkt) {                             // prefetch tile kt+2
            LOADA(kt + 2, aR0, aR1);
            if (tid < 256) bR = *(const short8*)(Bpp + (kt + 2) * 32);
        } else if (kt + 2 == nkt) {                     // tail: S t0
            sA0 = *(const short8*)Sp0;
            sA1 = *(const short8*)Sp1;
        } else if (kt + 2 == nkt + 1) {                 // tail: S t1
            sB0 = *(const short8*)(Sp0 + 32);
            sB1 = *(const short8*)(Sp1 + 32);
        }
        #pragma unroll
        for (int mi = 0; mi < 4; ++mi)
            #pragma unroll
            for (int ni = 0; ni < 2; ++ni)
                acc[mi][ni] = __builtin_amdgcn_mfma_f32_16x16x32_bf16(af[mi], bf[ni], acc[mi][ni], 0, 0, 0);
        __syncthreads();
    }
    #undef LOADA

    // Phase 2a: acc -> Yt transposed (col = y-col, 4 consecutive batch rows per 8B write)
    #pragma unroll
    for (int mi = 0; mi < 4; ++mi)
        #pragma unroll
        for (int ni = 0; ni < 2; ++ni) {
            f32x4 v = acc[mi][ni];
            ushort4 st; st.x = f2b(v[0]); st.y = f2b(v[1]); st.z = f2b(v[2]); st.w = f2b(v[3]);
            int col = wc * 32 + ni * 16 + lr;
            int row0 = wr * 64 + mi * 16 + lc * 4;
            *(ushort4*)(Yt + (size_t)col * YTP + row0) = st;
        }
    // stage S t0 -> buf0.At (buf0 free); prefetch t2
    *(short8*)(smem + offA0) = sA0;
    *(short8*)(smem + offA1) = sA1;
    sA0 = *(const short8*)(Sp0 + 64);
    sA1 = *(const short8*)(Sp1 + 64);
    __syncthreads();                                    // Yt + S t0 visible

    // Phase 2b: Zt = Yt x S, 8 K-tiles, ping-pong staging, 1 barrier/tile
    f32x4 acc2[4][2] = {};
    #pragma unroll
    for (int kt = 0; kt < 8; ++kt) {
        char* base_ = smem + (kt & 1) * BUFSZ;
        short8 ay[4], bs[2];
        #pragma unroll
        for (int mi = 0; mi < 4; ++mi)                  // a = Y^T rows (y-cols), k-contig
            ay[mi] = *(const short8*)(Yt + (size_t)(mi * 16 + lr) * YTP + kt * 32 + lc * 8);
        #pragma unroll
        for (int ni = 0; ni < 2; ++ni) {                // b = S rows (out-rows), swizzled
            int row = wid * 32 + ni * 16 + lr;
            int cs = lc ^ ((row >> 1) & 3);
            bs[ni] = *(const short8*)(base_ + row * 64 + cs * 16);
        }
        if (kt + 1 < 8) {                               // write tile kt+1; reload that set
            char* nb_ = smem + ((kt + 1) & 1) * BUFSZ;
            if ((kt & 1) == 0) {
                *(short8*)(nb_ + offA0) = sB0;
                *(short8*)(nb_ + offA1) = sB1;
                if (kt + 3 < 8) {
                    sB0 = *(const short8*)(Sp0 + (kt + 3) * 32);
                    sB1 = *(const short8*)(Sp1 + (kt + 3) * 32);
                }
            } else {
                *(short8*)(nb_ + offA0) = sA0;
                *(short8*)(nb_ + offA1) = sA1;
                if (kt + 3 < 8) {
                    sA0 = *(const short8*)(Sp0 + (kt + 3) * 32);
                    sA1 = *(const short8*)(Sp1 + (kt + 3) * 32);
                }
            }
        }
        #pragma unroll
        for (int mi = 0; mi < 4; ++mi)
            #pragma unroll
            for (int ni = 0; ni < 2; ++ni)
                acc2[mi][ni] = __builtin_amdgcn_mfma_f32_16x16x32_bf16(ay[mi], bs[ni], acc2[mi][ni], 0, 0, 0);
        if (kt + 1 < 8) __syncthreads();
    }

    // Epilogue: lane holds outrow lr (fixed) x 4 consecutive y-cols per frag
    #pragma unroll
    for (int ni = 0; ni < 2; ++ni) {
        int g = batch * NL + wid * 32 + ni * 16 + lr;   // global output row
        float di = dinv[g];
        #pragma unroll
        for (int mi = 0; mi < 4; ++mi) {
            int col0 = sl * 64 + mi * 16 + lc * 4;      // global col (multiple of 4)
            float4 bv;
            if (col0 < MEM) bv = *(const float4*)(bias + col0);
            else { bv.x = 0.f; bv.y = 0.f; bv.z = 0.f; bv.w = 0.f; }
            f32x4 z = acc2[mi][ni];
            float h0 = fmaxf((z[0] + 2.f * bv.x) * di, 0.f);
            float h1 = fmaxf((z[1] + 2.f * bv.y) * di, 0.f);
            float h2 = fmaxf((z[2] + 2.f * bv.z) * di, 0.f);
            float h3 = fmaxf((z[3] + 2.f * bv.w) * di, 0.f);
            if (FINAL == 0) {
                ushort4 st; st.x = f2b(h0); st.y = f2b(h1); st.z = f2b(h2); st.w = f2b(h3);
                *(ushort4*)((unsigned short*)x1b + (size_t)g * NP + col0) = st;
            } else if (col0 < MEM) {
                float4 o; o.x = h0; o.y = h1; o.z = h2; o.w = h3;
                *(float4*)(outx + (size_t)g * MEM + col0) = o;
            }
        }
    }
}

extern "C" void kernel_launch(void* const* d_in, const int* in_sizes, int n_in,
                              void* d_out, int out_size, void* d_ws, size_t ws_size,
                              hipStream_t stream) {
    const int*   words = (const int*)d_in[0];
    const int*   pos   = (const int*)d_in[1];
    const int*   ner   = (const int*)d_in[2];
    const float* adj   = (const float*)d_in[3];
    const float* embW  = (const float*)d_in[4];
    const float* posW  = (const float*)d_in[5];
    const float* nerW  = (const float*)d_in[6];
    const float* W0    = (const float*)d_in[7];
    const float* b0    = (const float*)d_in[8];
    const float* W1    = (const float*)d_in[9];
    const float* b1    = (const float*)d_in[10];
    float* out = (float*)d_out;

    char* ws = (char*)d_ws;
    size_t off = 0;
    short* W0p = (short*)(ws + off);        off += (size_t)NP * KP1 * 2;
    short* W1p = (short*)(ws + off);        off += (size_t)NP * NP * 2;
    short* X1b = (short*)(ws + off);        off += (size_t)NROWS * NP * 2;        // 16.8 MB
    float* dinv = (float*)(ws + off);       off += (size_t)NROWS * 4;
    float* rsum = (float*)(ws + off);       off += (size_t)NROWS * 4;
    unsigned* colnz = (unsigned*)(ws + off); off += (size_t)NROWS * 4;
    unsigned short* Sbf = (unsigned short*)(ws + off); off += (size_t)NROWS * NL * 2; // 16.8 MB

    prep_weights<<<(NP * KP1 + NP * NP + 255) / 256, 256, 0, stream>>>(W0, W1, W0p, W1p, colnz);
    adjrow_kernel<<<NROWS / 4, 256, 0, stream>>>(adj, dinv, rsum, Sbf, colnz);
    mask_kernel<<<NROWS / 256, 256, 0, stream>>>(rsum, colnz, out + OUT_X);

    const int ldsB = YTOFF + 64 * YTP * 2;   // 74,752 B
    fused_kernel<0><<<NB * 4, 512, ldsB, stream>>>(nullptr, KP1, KP1 / 32, W0p, KP1,
                                                   Sbf, dinv, b0,
                                                   words, pos, ner, embW, posW, nerW,
                                                   X1b, nullptr);
    fused_kernel<1><<<NB * 4, 512, ldsB, stream>>>(X1b, NP, NP / 32, W1p, NP,
                                                   Sbf, dinv, b1,
                                                   nullptr, nullptr, nullptr, nullptr, nullptr, nullptr,
                                                   nullptr, out);
}